// Round 1
// baseline (887.432 us; speedup 1.0000x reference)
//
#include <hip/hip_runtime.h>
#include <math.h>

#define NN 50000
#define NE 800000
#define DD 64
#define LL 4
#define GG 128
#define TT 10
#define NEG_SLOPE 0.2f
#define EPSF 1e-16f

__device__ __forceinline__ float wave_reduce_sum(float v) {
  #pragma unroll
  for (int off = 32; off > 0; off >>= 1) v += __shfl_xor(v, off, 64);
  return v;
}
__device__ __forceinline__ float wave_reduce_max(float v) {
  #pragma unroll
  for (int off = 32; off > 0; off >>= 1) v = fmaxf(v, __shfl_xor(v, off, 64));
  return v;
}

// h[v][d] = node_emb[x[v]][d]
__global__ void embed_kernel(const int* __restrict__ x, const float* __restrict__ node_emb,
                             float* __restrict__ h) {
  int i = blockIdx.x * blockDim.x + threadIdx.x;
  if (i < NN * DD) {
    int v = i >> 6, d = i & 63;
    h[i] = node_emb[x[v] * DD + d];
  }
}

__global__ void hist_kernel(const int* __restrict__ dst, int* __restrict__ cnt) {
  int e = blockIdx.x * blockDim.x + threadIdx.x;
  if (e < NE) atomicAdd(&cnt[dst[e]], 1);
}

// Single-block exclusive scan; data: in=counts, out=cursor(=excl). rowptr gets excl + total at [NN].
__global__ void scan_kernel(int* __restrict__ data, int* __restrict__ rowptr) {
  __shared__ int smem[256];
  __shared__ int carry;
  int tid = threadIdx.x;
  if (tid == 0) carry = 0;
  __syncthreads();
  for (int base = 0; base < NN; base += 256) {
    int i = base + tid;
    int v = (i < NN) ? data[i] : 0;
    smem[tid] = v;
    __syncthreads();
    for (int off = 1; off < 256; off <<= 1) {
      int t = (tid >= off) ? smem[tid - off] : 0;
      __syncthreads();
      smem[tid] += t;
      __syncthreads();
    }
    int incl = smem[tid];
    int total = smem[255];
    int excl = incl - v + carry;
    if (i < NN) { rowptr[i] = excl; data[i] = excl; }
    __syncthreads();
    if (tid == 0) carry += total;
    __syncthreads();
  }
  if (tid == 0) rowptr[NN] = carry;
}

// col[pos] = src | attr<<20, grouped by dst
__global__ void scatter_kernel(const int* __restrict__ src, const int* __restrict__ dst,
                               const int* __restrict__ attr, int* __restrict__ cursor,
                               int* __restrict__ col) {
  int e = blockIdx.x * blockDim.x + threadIdx.x;
  if (e < NE) {
    int d = dst[e];
    int pos = atomicAdd(&cursor[d], 1);
    col[pos] = src[e] | (attr[e] << 20);
  }
}

// ae_tab[l*4+k] = e_tab[l][k] . (W_edges[l]^T att_edge[l])
__global__ void prep_ae_kernel(const float* __restrict__ edge_embs, const float* __restrict__ W_edges,
                               const float* __restrict__ att_edge, float* __restrict__ ae_tab) {
  int t = threadIdx.x;
  if (t >= LL * 4) return;
  int l = t >> 2, k = t & 3;
  const float* We = W_edges + l * DD * DD;
  const float* aE = att_edge + l * DD;
  const float* et = edge_embs + (l * 4 + k) * DD;
  float acc = 0.f;
  for (int j = 0; j < DD; ++j) {
    float tj = 0.f;
    for (int d = 0; d < DD; ++d) tj += We[d * DD + j] * aE[d];
    acc += et[j] * tj;
  }
  ae_tab[t] = acc;
}

// g = h @ W^T ; asrc = g . a_src ; adst = g . a_dst   (one wave per node, 4 nodes/block)
__global__ __launch_bounds__(256) void gemm_attn_kernel(
    const float* __restrict__ h, const float* __restrict__ W,
    const float* __restrict__ a_src, const float* __restrict__ a_dst,
    float* __restrict__ g, float* __restrict__ asrc, float* __restrict__ adst) {
  __shared__ float Wsm[DD][DD + 1];   // +1 pad: 2-way bank alias only (free)
  __shared__ float hs[4][DD];
  int tid = threadIdx.x, wave = tid >> 6, lane = tid & 63;
  for (int idx = tid; idx < DD * DD; idx += 256) Wsm[idx >> 6][idx & 63] = W[idx];
  int v = blockIdx.x * 4 + wave;     // NN % 4 == 0, always valid
  hs[wave][lane] = h[v * DD + lane];
  __syncthreads();
  float acc = 0.f;
  #pragma unroll
  for (int j = 0; j < DD; ++j) acc += hs[wave][j] * Wsm[lane][j];
  g[v * DD + lane] = acc;
  float ps = wave_reduce_sum(acc * a_src[lane]);
  float pd = wave_reduce_sum(acc * a_dst[lane]);
  if (lane == 0) { asrc[v] = ps; adst[v] = pd; }
}

// per-node softmax attention + aggregation, fused bias+relu. One wave per node.
__global__ __launch_bounds__(256) void aggregate_kernel(
    const float* __restrict__ g, const float* __restrict__ asrc, const float* __restrict__ adst,
    const int* __restrict__ rowptr, const int* __restrict__ col,
    const float* __restrict__ ae4, const float* __restrict__ bias, float* __restrict__ hout) {
  int tid = threadIdx.x, wave = tid >> 6, lane = tid & 63;
  int v = blockIdx.x * 4 + wave;     // NN % 4 == 0
  int start = rowptr[v], end = rowptr[v + 1];
  float adstv = adst[v];
  // pass 1: segment max of leaky_relu(alpha)
  float mx = -INFINITY;
  for (int e = start + lane; e < end; e += 64) {
    int p = col[e]; int s = p & 0xFFFFF; int a = p >> 20;
    float al = asrc[s] + adstv + ae4[a];
    al = (al > 0.f) ? al : NEG_SLOPE * al;
    mx = fmaxf(mx, al);
  }
  mx = wave_reduce_max(mx);
  // pass 2: exp + denom + weighted aggregation (division deferred)
  float accum = 0.f, den = 0.f;
  for (int base = start; base < end; base += 64) {
    int e = base + lane;
    float ex = 0.f; int s = 0;
    if (e < end) {
      int p = col[e]; s = p & 0xFFFFF; int a = p >> 20;
      float al = asrc[s] + adstv + ae4[a];
      al = (al > 0.f) ? al : NEG_SLOPE * al;
      ex = __expf(al - mx);
    }
    den += ex;
    int cnt = end - base; if (cnt > 64) cnt = 64;
    for (int j = 0; j < cnt; ++j) {
      float exj = __shfl(ex, j, 64);
      int   sj  = __shfl(s, j, 64);
      accum += exj * g[sj * DD + lane];
    }
  }
  den = wave_reduce_sum(den);
  float o = accum / (den + EPSF) + bias[lane];
  hout[v * DD + lane] = fmaxf(o, 0.f);
}

// pooled[g] = sum of h rows in [lo,hi) where batch==g (batch sorted)
__global__ __launch_bounds__(256) void pool_kernel(const float* __restrict__ h,
                                                   const int* __restrict__ batch,
                                                   float* __restrict__ pooled) {
  __shared__ int s_lo, s_hi;
  __shared__ float red[4][DD];
  int gI = blockIdx.x;
  int tid = threadIdx.x, wave = tid >> 6, lane = tid & 63;
  if (tid == 0) {
    int lo = 0, hi = NN;
    while (lo < hi) { int mid = (lo + hi) >> 1; if (batch[mid] < gI) lo = mid + 1; else hi = mid; }
    s_lo = lo;
    lo = 0; hi = NN;
    while (lo < hi) { int mid = (lo + hi) >> 1; if (batch[mid] < gI + 1) lo = mid + 1; else hi = mid; }
    s_hi = lo;
  }
  __syncthreads();
  float acc = 0.f;
  for (int v = s_lo + wave; v < s_hi; v += 4) acc += h[v * DD + lane];
  red[wave][lane] = acc;
  __syncthreads();
  if (wave == 0)
    pooled[gI * DD + lane] = red[0][lane] + red[1][lane] + red[2][lane] + red[3][lane];
}

// hidden = relu(pooled @ W1^T + b1); out = hidden @ W2^T + b2
__global__ __launch_bounds__(128) void mlp_kernel(const float* __restrict__ pooled,
                                                  const float* __restrict__ W1, const float* __restrict__ b1,
                                                  const float* __restrict__ W2, const float* __restrict__ b2,
                                                  float* __restrict__ out) {
  __shared__ float sp[DD];
  __shared__ float sh[2 * DD];
  int gI = blockIdx.x, t = threadIdx.x;
  if (t < DD) sp[t] = pooled[gI * DD + t];
  __syncthreads();
  float acc = b1[t];
  for (int d = 0; d < DD; ++d) acc += sp[d] * W1[t * DD + d];
  sh[t] = fmaxf(acc, 0.f);
  __syncthreads();
  if (t < TT) {
    float o = b2[t];
    for (int k = 0; k < 2 * DD; ++k) o += sh[k] * W2[t * 2 * DD + k];
    out[gI * TT + t] = o;
  }
}

extern "C" void kernel_launch(void* const* d_in, const int* in_sizes, int n_in,
                              void* d_out, int out_size, void* d_ws, size_t ws_size,
                              hipStream_t stream) {
  const int* x          = (const int*)d_in[0];
  const int* edge_index = (const int*)d_in[1];
  const int* edge_attr  = (const int*)d_in[2];
  const int* batch      = (const int*)d_in[3];
  const float* node_emb = (const float*)d_in[4];
  const float* edge_embs= (const float*)d_in[5];
  const float* Ws_      = (const float*)d_in[6];
  const float* W_edges  = (const float*)d_in[7];
  const float* att_src  = (const float*)d_in[8];
  const float* att_dst  = (const float*)d_in[9];
  const float* att_edge = (const float*)d_in[10];
  const float* biases   = (const float*)d_in[11];
  const float* W1       = (const float*)d_in[12];
  const float* b1       = (const float*)d_in[13];
  const float* W2       = (const float*)d_in[14];
  const float* b2       = (const float*)d_in[15];
  float* out = (float*)d_out;

  char* wsp = (char*)d_ws;
  float* h      = (float*)wsp; wsp += (size_t)NN * DD * 4;
  float* g      = (float*)wsp; wsp += (size_t)NN * DD * 4;
  float* asrc   = (float*)wsp; wsp += (size_t)NN * 4;
  float* adst   = (float*)wsp; wsp += (size_t)NN * 4;
  float* ae_tab = (float*)wsp; wsp += 16 * 4;
  float* pooled = (float*)wsp; wsp += (size_t)GG * DD * 4;
  int* rowptr   = (int*)wsp;   wsp += (size_t)(NN + 1) * 4;
  int* cursor   = (int*)wsp;   wsp += (size_t)NN * 4;
  int* col      = (int*)wsp;   wsp += (size_t)NE * 4;

  const int* src = edge_index;
  const int* dst = edge_index + NE;

  hipMemsetAsync(cursor, 0, NN * sizeof(int), stream);
  embed_kernel<<<(NN * DD + 255) / 256, 256, 0, stream>>>(x, node_emb, h);
  hist_kernel<<<(NE + 255) / 256, 256, 0, stream>>>(dst, cursor);
  scan_kernel<<<1, 256, 0, stream>>>(cursor, rowptr);
  scatter_kernel<<<(NE + 255) / 256, 256, 0, stream>>>(src, dst, edge_attr, cursor, col);
  prep_ae_kernel<<<1, 64, 0, stream>>>(edge_embs, W_edges, att_edge, ae_tab);

  for (int l = 0; l < LL; ++l) {
    gemm_attn_kernel<<<NN / 4, 256, 0, stream>>>(h, Ws_ + l * DD * DD,
                                                 att_src + l * DD, att_dst + l * DD,
                                                 g, asrc, adst);
    aggregate_kernel<<<NN / 4, 256, 0, stream>>>(g, asrc, adst, rowptr, col,
                                                 ae_tab + l * 4, biases + l * DD, h);
  }

  pool_kernel<<<GG, 256, 0, stream>>>(h, batch, pooled);
  mlp_kernel<<<GG, 128, 0, stream>>>(pooled, W1, b1, W2, b2, out);
}

// Round 2
// 679.432 us; speedup vs baseline: 1.3061x; 1.3061x over previous
//
#include <hip/hip_runtime.h>
#include <math.h>

#define NN 50000
#define NE 800000
#define DD 64
#define LL 4
#define GG 128
#define TT 10
#define NEG_SLOPE 0.2f
#define EPSF 1e-16f

#define SCAN_BLK 256
#define NBLK ((NN + SCAN_BLK - 1) / SCAN_BLK)   // 196

__device__ __forceinline__ float wave_reduce_sum(float v) {
  #pragma unroll
  for (int off = 32; off > 0; off >>= 1) v += __shfl_xor(v, off, 64);
  return v;
}
__device__ __forceinline__ float wave_reduce_max(float v) {
  #pragma unroll
  for (int off = 32; off > 0; off >>= 1) v = fmaxf(v, __shfl_xor(v, off, 64));
  return v;
}
__device__ __forceinline__ int wave_incl_scan(int v) {
  int lane = threadIdx.x & 63;
  #pragma unroll
  for (int off = 1; off < 64; off <<= 1) {
    int t = __shfl_up(v, off, 64);
    if (lane >= off) v += t;
  }
  return v;
}

// h[v][d] = node_emb[x[v]][d]
__global__ void embed_kernel(const int* __restrict__ x, const float* __restrict__ node_emb,
                             float* __restrict__ h) {
  int i = blockIdx.x * blockDim.x + threadIdx.x;
  if (i < NN * DD) {
    int v = i >> 6, d = i & 63;
    h[i] = node_emb[x[v] * DD + d];
  }
}

__global__ void hist_kernel(const int* __restrict__ dst, int* __restrict__ cnt) {
  int e = blockIdx.x * blockDim.x + threadIdx.x;
  if (e < NE) atomicAdd(&cnt[dst[e]], 1);
}

// partials[b] = sum of cnt over block b's 256-chunk
__global__ __launch_bounds__(256) void scan_partial_kernel(const int* __restrict__ cnt,
                                                           int* __restrict__ partials) {
  __shared__ int wsum[4];
  int b = blockIdx.x, tid = threadIdx.x, wave = tid >> 6, lane = tid & 63;
  int i = b * SCAN_BLK + tid;
  int v = (i < NN) ? cnt[i] : 0;
  #pragma unroll
  for (int off = 32; off > 0; off >>= 1) v += __shfl_xor(v, off, 64);
  if (lane == 0) wsum[wave] = v;
  __syncthreads();
  if (tid == 0) partials[b] = wsum[0] + wsum[1] + wsum[2] + wsum[3];
}

// exclusive-scan the NBLK partials in place (NBLK <= 256); rowptr[NN] = total
__global__ __launch_bounds__(256) void scan_base_kernel(int* __restrict__ partials,
                                                        int* __restrict__ rowptr) {
  __shared__ int wsum[4];
  int tid = threadIdx.x, wave = tid >> 6, lane = tid & 63;
  int v = (tid < NBLK) ? partials[tid] : 0;
  int incl = wave_incl_scan(v);
  if (lane == 63) wsum[wave] = incl;
  __syncthreads();
  int wbase = 0;
  for (int w = 0; w < wave; ++w) wbase += wsum[w];
  if (tid < NBLK) partials[tid] = incl - v + wbase;
  if (tid == 0) rowptr[NN] = wsum[0] + wsum[1] + wsum[2] + wsum[3];
}

// per-chunk exclusive scan + block base -> rowptr[i], cursor[i]
__global__ __launch_bounds__(256) void scan_apply_kernel(const int* __restrict__ partials,
                                                         int* __restrict__ cnt_cursor,
                                                         int* __restrict__ rowptr) {
  __shared__ int wsum[4];
  int b = blockIdx.x, tid = threadIdx.x, wave = tid >> 6, lane = tid & 63;
  int i = b * SCAN_BLK + tid;
  int v = (i < NN) ? cnt_cursor[i] : 0;
  int incl = wave_incl_scan(v);
  if (lane == 63) wsum[wave] = incl;
  __syncthreads();
  int wbase = 0;
  for (int w = 0; w < wave; ++w) wbase += wsum[w];
  int excl = incl - v + wbase + partials[b];
  if (i < NN) { rowptr[i] = excl; cnt_cursor[i] = excl; }
}

// col[pos] = src | attr<<20, grouped by dst
__global__ void scatter_kernel(const int* __restrict__ src, const int* __restrict__ dst,
                               const int* __restrict__ attr, int* __restrict__ cursor,
                               int* __restrict__ col) {
  int e = blockIdx.x * blockDim.x + threadIdx.x;
  if (e < NE) {
    int d = dst[e];
    int pos = atomicAdd(&cursor[d], 1);
    col[pos] = src[e] | (attr[e] << 20);
  }
}

// ae_tab[l*4+k] = e_tab[l][k] . (W_edges[l]^T att_edge[l])
__global__ void prep_ae_kernel(const float* __restrict__ edge_embs, const float* __restrict__ W_edges,
                               const float* __restrict__ att_edge, float* __restrict__ ae_tab) {
  int t = threadIdx.x;
  if (t >= LL * 4) return;
  int l = t >> 2, k = t & 3;
  const float* We = W_edges + l * DD * DD;
  const float* aE = att_edge + l * DD;
  const float* et = edge_embs + (l * 4 + k) * DD;
  float acc = 0.f;
  for (int j = 0; j < DD; ++j) {
    float tj = 0.f;
    for (int d = 0; d < DD; ++d) tj += We[d * DD + j] * aE[d];
    acc += et[j] * tj;
  }
  ae_tab[t] = acc;
}

// g = h @ W^T ; asrc = g . a_src ; adst = g . a_dst   (one wave per node, 4 nodes/block)
__global__ __launch_bounds__(256) void gemm_attn_kernel(
    const float* __restrict__ h, const float* __restrict__ W,
    const float* __restrict__ a_src, const float* __restrict__ a_dst,
    float* __restrict__ g, float* __restrict__ asrc, float* __restrict__ adst) {
  __shared__ float Wsm[DD][DD + 1];   // +1 pad: 2-way bank alias only (free)
  __shared__ float hs[4][DD];
  int tid = threadIdx.x, wave = tid >> 6, lane = tid & 63;
  for (int idx = tid; idx < DD * DD; idx += 256) Wsm[idx >> 6][idx & 63] = W[idx];
  int v = blockIdx.x * 4 + wave;     // NN % 4 == 0, always valid
  hs[wave][lane] = h[v * DD + lane];
  __syncthreads();
  float acc = 0.f;
  #pragma unroll
  for (int j = 0; j < DD; ++j) acc += hs[wave][j] * Wsm[lane][j];
  g[v * DD + lane] = acc;
  float ps = wave_reduce_sum(acc * a_src[lane]);
  float pd = wave_reduce_sum(acc * a_dst[lane]);
  if (lane == 0) { asrc[v] = ps; adst[v] = pd; }
}

// per-node softmax attention + aggregation, fused bias+relu. One wave per node.
__global__ __launch_bounds__(256) void aggregate_kernel(
    const float* __restrict__ g, const float* __restrict__ asrc, const float* __restrict__ adst,
    const int* __restrict__ rowptr, const int* __restrict__ col,
    const float* __restrict__ ae4, const float* __restrict__ bias, float* __restrict__ hout) {
  int tid = threadIdx.x, wave = tid >> 6, lane = tid & 63;
  int v = blockIdx.x * 4 + wave;     // NN % 4 == 0
  int start = rowptr[v], end = rowptr[v + 1];
  float adstv = adst[v];
  // pass 1: segment max of leaky_relu(alpha)
  float mx = -INFINITY;
  for (int e = start + lane; e < end; e += 64) {
    int p = col[e]; int s = p & 0xFFFFF; int a = p >> 20;
    float al = asrc[s] + adstv + ae4[a];
    al = (al > 0.f) ? al : NEG_SLOPE * al;
    mx = fmaxf(mx, al);
  }
  mx = wave_reduce_max(mx);
  // pass 2: exp + denom + weighted aggregation (division deferred)
  float accum = 0.f, den = 0.f;
  for (int base = start; base < end; base += 64) {
    int e = base + lane;
    float ex = 0.f; int s = 0;
    if (e < end) {
      int p = col[e]; s = p & 0xFFFFF; int a = p >> 20;
      float al = asrc[s] + adstv + ae4[a];
      al = (al > 0.f) ? al : NEG_SLOPE * al;
      ex = __expf(al - mx);
    }
    den += ex;
    int cnt = end - base; if (cnt > 64) cnt = 64;
    for (int j = 0; j < cnt; ++j) {
      float exj = __shfl(ex, j, 64);
      int   sj  = __shfl(s, j, 64);
      accum += exj * g[sj * DD + lane];
    }
  }
  den = wave_reduce_sum(den);
  float o = accum / (den + EPSF) + bias[lane];
  hout[v * DD + lane] = fmaxf(o, 0.f);
}

// pooled[g] = sum of h rows in [lo,hi) where batch==g (batch sorted)
__global__ __launch_bounds__(256) void pool_kernel(const float* __restrict__ h,
                                                   const int* __restrict__ batch,
                                                   float* __restrict__ pooled) {
  __shared__ int s_lo, s_hi;
  __shared__ float red[4][DD];
  int gI = blockIdx.x;
  int tid = threadIdx.x, wave = tid >> 6, lane = tid & 63;
  if (tid == 0) {
    int lo = 0, hi = NN;
    while (lo < hi) { int mid = (lo + hi) >> 1; if (batch[mid] < gI) lo = mid + 1; else hi = mid; }
    s_lo = lo;
    lo = 0; hi = NN;
    while (lo < hi) { int mid = (lo + hi) >> 1; if (batch[mid] < gI + 1) lo = mid + 1; else hi = mid; }
    s_hi = lo;
  }
  __syncthreads();
  float acc = 0.f;
  for (int v = s_lo + wave; v < s_hi; v += 4) acc += h[v * DD + lane];
  red[wave][lane] = acc;
  __syncthreads();
  if (wave == 0)
    pooled[gI * DD + lane] = red[0][lane] + red[1][lane] + red[2][lane] + red[3][lane];
}

// hidden = relu(pooled @ W1^T + b1); out = hidden @ W2^T + b2
__global__ __launch_bounds__(128) void mlp_kernel(const float* __restrict__ pooled,
                                                  const float* __restrict__ W1, const float* __restrict__ b1,
                                                  const float* __restrict__ W2, const float* __restrict__ b2,
                                                  float* __restrict__ out) {
  __shared__ float sp[DD];
  __shared__ float sh[2 * DD];
  int gI = blockIdx.x, t = threadIdx.x;
  if (t < DD) sp[t] = pooled[gI * DD + t];
  __syncthreads();
  float acc = b1[t];
  for (int d = 0; d < DD; ++d) acc += sp[d] * W1[t * DD + d];
  sh[t] = fmaxf(acc, 0.f);
  __syncthreads();
  if (t < TT) {
    float o = b2[t];
    for (int k = 0; k < 2 * DD; ++k) o += sh[k] * W2[t * 2 * DD + k];
    out[gI * TT + t] = o;
  }
}

extern "C" void kernel_launch(void* const* d_in, const int* in_sizes, int n_in,
                              void* d_out, int out_size, void* d_ws, size_t ws_size,
                              hipStream_t stream) {
  const int* x          = (const int*)d_in[0];
  const int* edge_index = (const int*)d_in[1];
  const int* edge_attr  = (const int*)d_in[2];
  const int* batch      = (const int*)d_in[3];
  const float* node_emb = (const float*)d_in[4];
  const float* edge_embs= (const float*)d_in[5];
  const float* Ws_      = (const float*)d_in[6];
  const float* W_edges  = (const float*)d_in[7];
  const float* att_src  = (const float*)d_in[8];
  const float* att_dst  = (const float*)d_in[9];
  const float* att_edge = (const float*)d_in[10];
  const float* biases   = (const float*)d_in[11];
  const float* W1       = (const float*)d_in[12];
  const float* b1       = (const float*)d_in[13];
  const float* W2       = (const float*)d_in[14];
  const float* b2       = (const float*)d_in[15];
  float* out = (float*)d_out;

  char* wsp = (char*)d_ws;
  float* h      = (float*)wsp; wsp += (size_t)NN * DD * 4;
  float* g      = (float*)wsp; wsp += (size_t)NN * DD * 4;
  float* asrc   = (float*)wsp; wsp += (size_t)NN * 4;
  float* adst   = (float*)wsp; wsp += (size_t)NN * 4;
  float* ae_tab = (float*)wsp; wsp += 16 * 4;
  float* pooled = (float*)wsp; wsp += (size_t)GG * DD * 4;
  int* rowptr   = (int*)wsp;   wsp += (size_t)(NN + 1) * 4;
  int* cursor   = (int*)wsp;   wsp += (size_t)NN * 4;
  int* partials = (int*)wsp;   wsp += (size_t)(NBLK + 1) * 4;
  int* col      = (int*)wsp;   wsp += (size_t)NE * 4;

  const int* src = edge_index;
  const int* dst = edge_index + NE;

  hipMemsetAsync(cursor, 0, NN * sizeof(int), stream);
  embed_kernel<<<(NN * DD + 255) / 256, 256, 0, stream>>>(x, node_emb, h);
  hist_kernel<<<(NE + 255) / 256, 256, 0, stream>>>(dst, cursor);
  scan_partial_kernel<<<NBLK, 256, 0, stream>>>(cursor, partials);
  scan_base_kernel<<<1, 256, 0, stream>>>(partials, rowptr);
  scan_apply_kernel<<<NBLK, 256, 0, stream>>>(partials, cursor, rowptr);
  scatter_kernel<<<(NE + 255) / 256, 256, 0, stream>>>(src, dst, edge_attr, cursor, col);
  prep_ae_kernel<<<1, 64, 0, stream>>>(edge_embs, W_edges, att_edge, ae_tab);

  for (int l = 0; l < LL; ++l) {
    gemm_attn_kernel<<<NN / 4, 256, 0, stream>>>(h, Ws_ + l * DD * DD,
                                                 att_src + l * DD, att_dst + l * DD,
                                                 g, asrc, adst);
    aggregate_kernel<<<NN / 4, 256, 0, stream>>>(g, asrc, adst, rowptr, col,
                                                 ae_tab + l * 4, biases + l * DD, h);
  }

  pool_kernel<<<GG, 256, 0, stream>>>(h, batch, pooled);
  mlp_kernel<<<GG, 128, 0, stream>>>(pooled, W1, b1, W2, b2, out);
}

// Round 3
// 524.144 us; speedup vs baseline: 1.6931x; 1.2963x over previous
//
#include <hip/hip_runtime.h>
#include <math.h>

#define NN 50000
#define NE 800000
#define DD 64
#define LL 4
#define GG 128
#define TT 10
#define NEG_SLOPE 0.2f
#define EPSF 1e-16f

#define SCAN_BLK 256
#define NBLK ((NN + SCAN_BLK - 1) / SCAN_BLK)   // 196

__device__ __forceinline__ float wave_reduce_sum(float v) {
  #pragma unroll
  for (int off = 32; off > 0; off >>= 1) v += __shfl_xor(v, off, 64);
  return v;
}
__device__ __forceinline__ float group16_max(float v) {
  #pragma unroll
  for (int off = 1; off < 16; off <<= 1) v = fmaxf(v, __shfl_xor(v, off, 64));
  return v;
}
__device__ __forceinline__ float group16_sum(float v) {
  #pragma unroll
  for (int off = 1; off < 16; off <<= 1) v += __shfl_xor(v, off, 64);
  return v;
}
__device__ __forceinline__ int wave_incl_scan(int v) {
  int lane = threadIdx.x & 63;
  #pragma unroll
  for (int off = 1; off < 64; off <<= 1) {
    int t = __shfl_up(v, off, 64);
    if (lane >= off) v += t;
  }
  return v;
}

// h[v][d] = node_emb[x[v]][d]
__global__ void embed_kernel(const int* __restrict__ x, const float* __restrict__ node_emb,
                             float* __restrict__ h) {
  int i = blockIdx.x * blockDim.x + threadIdx.x;
  if (i < NN * DD) {
    int v = i >> 6, d = i & 63;
    h[i] = node_emb[x[v] * DD + d];
  }
}

__global__ void hist_kernel(const int* __restrict__ dst, int* __restrict__ cnt) {
  int e = blockIdx.x * blockDim.x + threadIdx.x;
  if (e < NE) atomicAdd(&cnt[dst[e]], 1);
}

// partials[b] = sum of cnt over block b's 256-chunk
__global__ __launch_bounds__(256) void scan_partial_kernel(const int* __restrict__ cnt,
                                                           int* __restrict__ partials) {
  __shared__ int wsum[4];
  int b = blockIdx.x, tid = threadIdx.x, wave = tid >> 6, lane = tid & 63;
  int i = b * SCAN_BLK + tid;
  int v = (i < NN) ? cnt[i] : 0;
  #pragma unroll
  for (int off = 32; off > 0; off >>= 1) v += __shfl_xor(v, off, 64);
  if (lane == 0) wsum[wave] = v;
  __syncthreads();
  if (tid == 0) partials[b] = wsum[0] + wsum[1] + wsum[2] + wsum[3];
}

// exclusive-scan the NBLK partials in place (NBLK <= 256); rowptr[NN] = total
__global__ __launch_bounds__(256) void scan_base_kernel(int* __restrict__ partials,
                                                        int* __restrict__ rowptr) {
  __shared__ int wsum[4];
  int tid = threadIdx.x, wave = tid >> 6, lane = tid & 63;
  int v = (tid < NBLK) ? partials[tid] : 0;
  int incl = wave_incl_scan(v);
  if (lane == 63) wsum[wave] = incl;
  __syncthreads();
  int wbase = 0;
  for (int w = 0; w < wave; ++w) wbase += wsum[w];
  if (tid < NBLK) partials[tid] = incl - v + wbase;
  if (tid == 0) rowptr[NN] = wsum[0] + wsum[1] + wsum[2] + wsum[3];
}

// per-chunk exclusive scan + block base -> rowptr[i], cursor[i]
__global__ __launch_bounds__(256) void scan_apply_kernel(const int* __restrict__ partials,
                                                         int* __restrict__ cnt_cursor,
                                                         int* __restrict__ rowptr) {
  __shared__ int wsum[4];
  int b = blockIdx.x, tid = threadIdx.x, wave = tid >> 6, lane = tid & 63;
  int i = b * SCAN_BLK + tid;
  int v = (i < NN) ? cnt_cursor[i] : 0;
  int incl = wave_incl_scan(v);
  if (lane == 63) wsum[wave] = incl;
  __syncthreads();
  int wbase = 0;
  for (int w = 0; w < wave; ++w) wbase += wsum[w];
  int excl = incl - v + wbase + partials[b];
  if (i < NN) { rowptr[i] = excl; cnt_cursor[i] = excl; }
}

// col[pos] = src | attr<<20, grouped by dst
__global__ void scatter_kernel(const int* __restrict__ src, const int* __restrict__ dst,
                               const int* __restrict__ attr, int* __restrict__ cursor,
                               int* __restrict__ col) {
  int e = blockIdx.x * blockDim.x + threadIdx.x;
  if (e < NE) {
    int d = dst[e];
    int pos = atomicAdd(&cursor[d], 1);
    col[pos] = src[e] | (attr[e] << 20);
  }
}

// ae_tab[l*4+k] = e_tab[l][k] . (W_edges[l]^T att_edge[l])
__global__ void prep_ae_kernel(const float* __restrict__ edge_embs, const float* __restrict__ W_edges,
                               const float* __restrict__ att_edge, float* __restrict__ ae_tab) {
  int t = threadIdx.x;
  if (t >= LL * 4) return;
  int l = t >> 2, k = t & 3;
  const float* We = W_edges + l * DD * DD;
  const float* aE = att_edge + l * DD;
  const float* et = edge_embs + (l * 4 + k) * DD;
  float acc = 0.f;
  for (int j = 0; j < DD; ++j) {
    float tj = 0.f;
    for (int d = 0; d < DD; ++d) tj += We[d * DD + j] * aE[d];
    acc += et[j] * tj;
  }
  ae_tab[t] = acc;
}

// g = h @ W^T ; asrc = g . a_src ; adst = g . a_dst
// 4 waves/block, 4 nodes/wave (16 nodes/block). lane = output feature d.
// 4 independent accumulator chains per lane; W rows read as ds_read_b128.
__global__ __launch_bounds__(256) void gemm_attn_kernel(
    const float* __restrict__ h, const float* __restrict__ W,
    const float* __restrict__ a_src, const float* __restrict__ a_dst,
    float* __restrict__ g, float* __restrict__ asrc, float* __restrict__ adst) {
  __shared__ float Wsm[DD][68];    // 68 floats/row: 272B = 16B-aligned, bank-rotating
  __shared__ float hs[16][DD];
  int tid = threadIdx.x, wave = tid >> 6, lane = tid & 63;
  int vbase = blockIdx.x * 16;
  for (int idx = tid; idx < DD * DD; idx += 256) Wsm[idx >> 6][idx & 63] = W[idx];
  for (int idx = tid; idx < 16 * DD; idx += 256) hs[idx >> 6][idx & 63] = h[vbase * DD + idx];
  __syncthreads();
  float acc0 = 0.f, acc1 = 0.f, acc2 = 0.f, acc3 = 0.f;
  int r = wave * 4;
  #pragma unroll
  for (int j4 = 0; j4 < DD / 4; ++j4) {
    float4 wv = *(const float4*)&Wsm[lane][j4 * 4];
    float4 h0 = *(const float4*)&hs[r + 0][j4 * 4];
    float4 h1 = *(const float4*)&hs[r + 1][j4 * 4];
    float4 h2 = *(const float4*)&hs[r + 2][j4 * 4];
    float4 h3 = *(const float4*)&hs[r + 3][j4 * 4];
    acc0 = fmaf(wv.x, h0.x, acc0); acc0 = fmaf(wv.y, h0.y, acc0);
    acc0 = fmaf(wv.z, h0.z, acc0); acc0 = fmaf(wv.w, h0.w, acc0);
    acc1 = fmaf(wv.x, h1.x, acc1); acc1 = fmaf(wv.y, h1.y, acc1);
    acc1 = fmaf(wv.z, h1.z, acc1); acc1 = fmaf(wv.w, h1.w, acc1);
    acc2 = fmaf(wv.x, h2.x, acc2); acc2 = fmaf(wv.y, h2.y, acc2);
    acc2 = fmaf(wv.z, h2.z, acc2); acc2 = fmaf(wv.w, h2.w, acc2);
    acc3 = fmaf(wv.x, h3.x, acc3); acc3 = fmaf(wv.y, h3.y, acc3);
    acc3 = fmaf(wv.z, h3.z, acc3); acc3 = fmaf(wv.w, h3.w, acc3);
  }
  int v = vbase + r;
  g[(v + 0) * DD + lane] = acc0;
  g[(v + 1) * DD + lane] = acc1;
  g[(v + 2) * DD + lane] = acc2;
  g[(v + 3) * DD + lane] = acc3;
  float asl = a_src[lane], adl = a_dst[lane];
  float p;
  p = wave_reduce_sum(acc0 * asl); if (lane == 0) asrc[v + 0] = p;
  p = wave_reduce_sum(acc1 * asl); if (lane == 0) asrc[v + 1] = p;
  p = wave_reduce_sum(acc2 * asl); if (lane == 0) asrc[v + 2] = p;
  p = wave_reduce_sum(acc3 * asl); if (lane == 0) asrc[v + 3] = p;
  p = wave_reduce_sum(acc0 * adl); if (lane == 0) adst[v + 0] = p;
  p = wave_reduce_sum(acc1 * adl); if (lane == 0) adst[v + 1] = p;
  p = wave_reduce_sum(acc2 * adl); if (lane == 0) adst[v + 2] = p;
  p = wave_reduce_sum(acc3 * adl); if (lane == 0) adst[v + 3] = p;
}

// softmax attention + aggregation. 16 lanes per node (float4 features),
// 4 nodes/wave, 16 nodes/block. Edge state cached in regs for deg<=64.
__global__ __launch_bounds__(256) void aggregate_kernel(
    const float4* __restrict__ g4, const float* __restrict__ asrc, const float* __restrict__ adst,
    const int* __restrict__ rowptr, const int* __restrict__ col,
    const float* __restrict__ ae4, const float* __restrict__ bias, float* __restrict__ hout) {
  int tid = threadIdx.x, wave = tid >> 6, lane = tid & 63;
  int sub = lane & 15;
  int base_lane = lane & 48;              // group base within wave
  int v = blockIdx.x * 16 + wave * 4 + (lane >> 4);   // NN % 16 == 0
  int start = rowptr[v], end = rowptr[v + 1];
  float adstv = adst[v];

  // pass 1: alphas for chunks 0..3 cached in regs; tail recomputed
  float alc[4]; int sc[4];
  float mx = -INFINITY;
  #pragma unroll
  for (int c = 0; c < 4; ++c) {
    alc[c] = -INFINITY; sc[c] = 0;
    int e = start + c * 16 + sub;
    if (e < end) {
      int p = col[e]; sc[c] = p & 0xFFFFF; int a = p >> 20;
      float al = asrc[sc[c]] + adstv + ae4[a];
      al = (al > 0.f) ? al : NEG_SLOPE * al;
      alc[c] = al; mx = fmaxf(mx, al);
    }
  }
  for (int base = start + 64; base < end; base += 16) {
    int e = base + sub;
    if (e < end) {
      int p = col[e]; int s = p & 0xFFFFF; int a = p >> 20;
      float al = asrc[s] + adstv + ae4[a];
      al = (al > 0.f) ? al : NEG_SLOPE * al;
      mx = fmaxf(mx, al);
    }
  }
  mx = group16_max(mx);

  // pass 2: exp + denom + aggregation (4 indep chains via float4)
  float4 acc = {0.f, 0.f, 0.f, 0.f};
  float den = 0.f;
  float exc[4];
  #pragma unroll
  for (int c = 0; c < 4; ++c) {
    int e = start + c * 16 + sub;
    exc[c] = (e < end) ? __expf(alc[c] - mx) : 0.f;
    den += exc[c];
  }
  #pragma unroll
  for (int c = 0; c < 4; ++c) {
    int cnt = end - (start + c * 16);
    if (cnt > 0) {
      if (cnt > 16) cnt = 16;
      for (int j = 0; j < cnt; ++j) {
        float exj = __shfl(exc[c], base_lane + j, 64);
        int sj = __shfl(sc[c], base_lane + j, 64);
        float4 gr = g4[(size_t)sj * 16 + sub];
        acc.x = fmaf(exj, gr.x, acc.x);
        acc.y = fmaf(exj, gr.y, acc.y);
        acc.z = fmaf(exj, gr.z, acc.z);
        acc.w = fmaf(exj, gr.w, acc.w);
      }
    }
  }
  for (int base = start + 64; base < end; base += 16) {
    int e = base + sub;
    float ex = 0.f; int s = 0;
    if (e < end) {
      int p = col[e]; s = p & 0xFFFFF; int a = p >> 20;
      float al = asrc[s] + adstv + ae4[a];
      al = (al > 0.f) ? al : NEG_SLOPE * al;
      ex = __expf(al - mx);
    }
    den += ex;
    int cnt = end - base; if (cnt > 16) cnt = 16;
    for (int j = 0; j < cnt; ++j) {
      float exj = __shfl(ex, base_lane + j, 64);
      int sj = __shfl(s, base_lane + j, 64);
      float4 gr = g4[(size_t)sj * 16 + sub];
      acc.x = fmaf(exj, gr.x, acc.x);
      acc.y = fmaf(exj, gr.y, acc.y);
      acc.z = fmaf(exj, gr.z, acc.z);
      acc.w = fmaf(exj, gr.w, acc.w);
    }
  }
  den = group16_sum(den);
  float inv = 1.f / (den + EPSF);
  float4 b4 = ((const float4*)bias)[sub];
  float4 o;
  o.x = fmaxf(fmaf(acc.x, inv, b4.x), 0.f);
  o.y = fmaxf(fmaf(acc.y, inv, b4.y), 0.f);
  o.z = fmaxf(fmaf(acc.z, inv, b4.z), 0.f);
  o.w = fmaxf(fmaf(acc.w, inv, b4.w), 0.f);
  ((float4*)hout)[(size_t)v * 16 + sub] = o;
}

// pooled[g] = sum of h rows in [lo,hi) where batch==g (batch sorted)
__global__ __launch_bounds__(256) void pool_kernel(const float* __restrict__ h,
                                                   const int* __restrict__ batch,
                                                   float* __restrict__ pooled) {
  __shared__ int s_lo, s_hi;
  __shared__ float red[4][DD];
  int gI = blockIdx.x;
  int tid = threadIdx.x, wave = tid >> 6, lane = tid & 63;
  if (tid == 0) {
    int lo = 0, hi = NN;
    while (lo < hi) { int mid = (lo + hi) >> 1; if (batch[mid] < gI) lo = mid + 1; else hi = mid; }
    s_lo = lo;
    lo = 0; hi = NN;
    while (lo < hi) { int mid = (lo + hi) >> 1; if (batch[mid] < gI + 1) lo = mid + 1; else hi = mid; }
    s_hi = lo;
  }
  __syncthreads();
  float acc = 0.f;
  for (int v = s_lo + wave; v < s_hi; v += 4) acc += h[v * DD + lane];
  red[wave][lane] = acc;
  __syncthreads();
  if (wave == 0)
    pooled[gI * DD + lane] = red[0][lane] + red[1][lane] + red[2][lane] + red[3][lane];
}

// hidden = relu(pooled @ W1^T + b1); out = hidden @ W2^T + b2
__global__ __launch_bounds__(128) void mlp_kernel(const float* __restrict__ pooled,
                                                  const float* __restrict__ W1, const float* __restrict__ b1,
                                                  const float* __restrict__ W2, const float* __restrict__ b2,
                                                  float* __restrict__ out) {
  __shared__ float sp[DD];
  __shared__ float sh[2 * DD];
  int gI = blockIdx.x, t = threadIdx.x;
  if (t < DD) sp[t] = pooled[gI * DD + t];
  __syncthreads();
  float acc = b1[t];
  for (int d = 0; d < DD; ++d) acc += sp[d] * W1[t * DD + d];
  sh[t] = fmaxf(acc, 0.f);
  __syncthreads();
  if (t < TT) {
    float o = b2[t];
    for (int k = 0; k < 2 * DD; ++k) o += sh[k] * W2[t * 2 * DD + k];
    out[gI * TT + t] = o;
  }
}

extern "C" void kernel_launch(void* const* d_in, const int* in_sizes, int n_in,
                              void* d_out, int out_size, void* d_ws, size_t ws_size,
                              hipStream_t stream) {
  const int* x          = (const int*)d_in[0];
  const int* edge_index = (const int*)d_in[1];
  const int* edge_attr  = (const int*)d_in[2];
  const int* batch      = (const int*)d_in[3];
  const float* node_emb = (const float*)d_in[4];
  const float* edge_embs= (const float*)d_in[5];
  const float* Ws_      = (const float*)d_in[6];
  const float* W_edges  = (const float*)d_in[7];
  const float* att_src  = (const float*)d_in[8];
  const float* att_dst  = (const float*)d_in[9];
  const float* att_edge = (const float*)d_in[10];
  const float* biases   = (const float*)d_in[11];
  const float* W1       = (const float*)d_in[12];
  const float* b1       = (const float*)d_in[13];
  const float* W2       = (const float*)d_in[14];
  const float* b2       = (const float*)d_in[15];
  float* out = (float*)d_out;

  char* wsp = (char*)d_ws;
  float* h      = (float*)wsp; wsp += (size_t)NN * DD * 4;
  float* g      = (float*)wsp; wsp += (size_t)NN * DD * 4;
  float* asrc   = (float*)wsp; wsp += (size_t)NN * 4;
  float* adst   = (float*)wsp; wsp += (size_t)NN * 4;
  float* ae_tab = (float*)wsp; wsp += 16 * 4;
  float* pooled = (float*)wsp; wsp += (size_t)GG * DD * 4;
  int* rowptr   = (int*)wsp;   wsp += (size_t)(NN + 1) * 4;
  int* cursor   = (int*)wsp;   wsp += (size_t)NN * 4;
  int* partials = (int*)wsp;   wsp += (size_t)(NBLK + 1) * 4;
  int* col      = (int*)wsp;   wsp += (size_t)NE * 4;

  const int* src = edge_index;
  const int* dst = edge_index + NE;

  hipMemsetAsync(cursor, 0, NN * sizeof(int), stream);
  embed_kernel<<<(NN * DD + 255) / 256, 256, 0, stream>>>(x, node_emb, h);
  hist_kernel<<<(NE + 255) / 256, 256, 0, stream>>>(dst, cursor);
  scan_partial_kernel<<<NBLK, 256, 0, stream>>>(cursor, partials);
  scan_base_kernel<<<1, 256, 0, stream>>>(partials, rowptr);
  scan_apply_kernel<<<NBLK, 256, 0, stream>>>(partials, cursor, rowptr);
  scatter_kernel<<<(NE + 255) / 256, 256, 0, stream>>>(src, dst, edge_attr, cursor, col);
  prep_ae_kernel<<<1, 64, 0, stream>>>(edge_embs, W_edges, att_edge, ae_tab);

  for (int l = 0; l < LL; ++l) {
    gemm_attn_kernel<<<NN / 16, 256, 0, stream>>>(h, Ws_ + l * DD * DD,
                                                  att_src + l * DD, att_dst + l * DD,
                                                  g, asrc, adst);
    aggregate_kernel<<<NN / 16, 256, 0, stream>>>((const float4*)g, asrc, adst, rowptr, col,
                                                  ae_tab + l * 4, biases + l * DD, h);
  }

  pool_kernel<<<GG, 256, 0, stream>>>(h, batch, pooled);
  mlp_kernel<<<GG, 128, 0, stream>>>(pooled, W1, b1, W2, b2, out);
}

// Round 5
// 468.421 us; speedup vs baseline: 1.8945x; 1.1190x over previous
//
#include <hip/hip_runtime.h>
#include <math.h>

#define NN 50000
#define NE 800000
#define DD 64
#define LL 4
#define GG 128
#define TT 10
#define NEG_SLOPE 0.2f
#define EPSF 1e-16f

#define SCAN_BLK 256
#define NBLK ((NN + SCAN_BLK - 1) / SCAN_BLK)   // 196

__device__ __forceinline__ float wave_reduce_sum(float v) {
  #pragma unroll
  for (int off = 32; off > 0; off >>= 1) v += __shfl_xor(v, off, 64);
  return v;
}
__device__ __forceinline__ float group16_max(float v) {
  #pragma unroll
  for (int off = 1; off < 16; off <<= 1) v = fmaxf(v, __shfl_xor(v, off, 64));
  return v;
}
__device__ __forceinline__ float group16_sum(float v) {
  #pragma unroll
  for (int off = 1; off < 16; off <<= 1) v += __shfl_xor(v, off, 64);
  return v;
}
__device__ __forceinline__ int wave_incl_scan(int v) {
  int lane = threadIdx.x & 63;
  #pragma unroll
  for (int off = 1; off < 64; off <<= 1) {
    int t = __shfl_up(v, off, 64);
    if (lane >= off) v += t;
  }
  return v;
}

// h[v][d] = node_emb[x[v]][d]
__global__ void embed_kernel(const int* __restrict__ x, const float* __restrict__ node_emb,
                             float* __restrict__ h) {
  int i = blockIdx.x * blockDim.x + threadIdx.x;
  if (i < NN * DD) {
    int v = i >> 6, d = i & 63;
    h[i] = node_emb[x[v] * DD + d];
  }
}

__global__ void hist_kernel(const int* __restrict__ dst, int* __restrict__ cnt) {
  int e = blockIdx.x * blockDim.x + threadIdx.x;
  if (e < NE) atomicAdd(&cnt[dst[e]], 1);
}

// partials[b] = sum of cnt over block b's 256-chunk
__global__ __launch_bounds__(256) void scan_partial_kernel(const int* __restrict__ cnt,
                                                           int* __restrict__ partials) {
  __shared__ int wsum[4];
  int b = blockIdx.x, tid = threadIdx.x, wave = tid >> 6, lane = tid & 63;
  int i = b * SCAN_BLK + tid;
  int v = (i < NN) ? cnt[i] : 0;
  #pragma unroll
  for (int off = 32; off > 0; off >>= 1) v += __shfl_xor(v, off, 64);
  if (lane == 0) wsum[wave] = v;
  __syncthreads();
  if (tid == 0) partials[b] = wsum[0] + wsum[1] + wsum[2] + wsum[3];
}

// exclusive-scan the NBLK partials in place (NBLK <= 256); rowptr[NN] = total
__global__ __launch_bounds__(256) void scan_base_kernel(int* __restrict__ partials,
                                                        int* __restrict__ rowptr) {
  __shared__ int wsum[4];
  int tid = threadIdx.x, wave = tid >> 6, lane = tid & 63;
  int v = (tid < NBLK) ? partials[tid] : 0;
  int incl = wave_incl_scan(v);
  if (lane == 63) wsum[wave] = incl;
  __syncthreads();
  int wbase = 0;
  for (int w = 0; w < wave; ++w) wbase += wsum[w];
  if (tid < NBLK) partials[tid] = incl - v + wbase;
  if (tid == 0) rowptr[NN] = wsum[0] + wsum[1] + wsum[2] + wsum[3];
}

// per-chunk exclusive scan + block base -> rowptr[i], cursor[i]
__global__ __launch_bounds__(256) void scan_apply_kernel(const int* __restrict__ partials,
                                                         int* __restrict__ cnt_cursor,
                                                         int* __restrict__ rowptr) {
  __shared__ int wsum[4];
  int b = blockIdx.x, tid = threadIdx.x, wave = tid >> 6, lane = tid & 63;
  int i = b * SCAN_BLK + tid;
  int v = (i < NN) ? cnt_cursor[i] : 0;
  int incl = wave_incl_scan(v);
  if (lane == 63) wsum[wave] = incl;
  __syncthreads();
  int wbase = 0;
  for (int w = 0; w < wave; ++w) wbase += wsum[w];
  int excl = incl - v + wbase + partials[b];
  if (i < NN) { rowptr[i] = excl; cnt_cursor[i] = excl; }
}

// col[pos] = src | attr<<20, grouped by dst
__global__ void scatter_kernel(const int* __restrict__ src, const int* __restrict__ dst,
                               const int* __restrict__ attr, int* __restrict__ cursor,
                               int* __restrict__ col) {
  int e = blockIdx.x * blockDim.x + threadIdx.x;
  if (e < NE) {
    int d = dst[e];
    int pos = atomicAdd(&cursor[d], 1);
    col[pos] = src[e] | (attr[e] << 20);
  }
}

// ae_tab[l*4+k] = e_tab[l][k] . (W_edges[l]^T att_edge[l])
// one wave per (l,k): lane j computes t_j = sum_d We[d][j]*aE[d] (coalesced), then reduce et[j]*t_j
__global__ __launch_bounds__(64) void prep_ae_kernel(const float* __restrict__ edge_embs,
                                                     const float* __restrict__ W_edges,
                                                     const float* __restrict__ att_edge,
                                                     float* __restrict__ ae_tab) {
  int t = blockIdx.x;          // 0..15
  int l = t >> 2, k = t & 3;
  int j = threadIdx.x;         // 0..63
  const float* We = W_edges + l * DD * DD;
  const float* aE = att_edge + l * DD;
  const float* et = edge_embs + (l * 4 + k) * DD;
  float tj = 0.f;
  #pragma unroll 8
  for (int d = 0; d < DD; ++d) tj = fmaf(We[d * DD + j], aE[d], tj);
  float acc = wave_reduce_sum(et[j] * tj);
  if (j == 0) ae_tab[t] = acc;
}

// g = h @ W^T ; asrc = g . a_src ; adst = g . a_dst
// 4 waves/block, 4 nodes/wave (16 nodes/block). lane = output feature d.
__global__ __launch_bounds__(256) void gemm_attn_kernel(
    const float* __restrict__ h, const float* __restrict__ W,
    const float* __restrict__ a_src, const float* __restrict__ a_dst,
    float* __restrict__ g, float* __restrict__ asrc, float* __restrict__ adst) {
  __shared__ float Wsm[DD][68];    // 68 floats/row: 272B = 16B-aligned, bank-rotating
  __shared__ float hs[16][DD];
  int tid = threadIdx.x, wave = tid >> 6, lane = tid & 63;
  int vbase = blockIdx.x * 16;
  for (int idx = tid; idx < DD * DD; idx += 256) Wsm[idx >> 6][idx & 63] = W[idx];
  for (int idx = tid; idx < 16 * DD; idx += 256) hs[idx >> 6][idx & 63] = h[vbase * DD + idx];
  __syncthreads();
  float acc0 = 0.f, acc1 = 0.f, acc2 = 0.f, acc3 = 0.f;
  int r = wave * 4;
  #pragma unroll
  for (int j4 = 0; j4 < DD / 4; ++j4) {
    float4 wv = *(const float4*)&Wsm[lane][j4 * 4];
    float4 h0 = *(const float4*)&hs[r + 0][j4 * 4];
    float4 h1 = *(const float4*)&hs[r + 1][j4 * 4];
    float4 h2 = *(const float4*)&hs[r + 2][j4 * 4];
    float4 h3 = *(const float4*)&hs[r + 3][j4 * 4];
    acc0 = fmaf(wv.x, h0.x, acc0); acc0 = fmaf(wv.y, h0.y, acc0);
    acc0 = fmaf(wv.z, h0.z, acc0); acc0 = fmaf(wv.w, h0.w, acc0);
    acc1 = fmaf(wv.x, h1.x, acc1); acc1 = fmaf(wv.y, h1.y, acc1);
    acc1 = fmaf(wv.z, h1.z, acc1); acc1 = fmaf(wv.w, h1.w, acc1);
    acc2 = fmaf(wv.x, h2.x, acc2); acc2 = fmaf(wv.y, h2.y, acc2);
    acc2 = fmaf(wv.z, h2.z, acc2); acc2 = fmaf(wv.w, h2.w, acc2);
    acc3 = fmaf(wv.x, h3.x, acc3); acc3 = fmaf(wv.y, h3.y, acc3);
    acc3 = fmaf(wv.z, h3.z, acc3); acc3 = fmaf(wv.w, h3.w, acc3);
  }
  int v = vbase + r;
  g[(v + 0) * DD + lane] = acc0;
  g[(v + 1) * DD + lane] = acc1;
  g[(v + 2) * DD + lane] = acc2;
  g[(v + 3) * DD + lane] = acc3;
  float asl = a_src[lane], adl = a_dst[lane];
  float p;
  p = wave_reduce_sum(acc0 * asl); if (lane == 0) asrc[v + 0] = p;
  p = wave_reduce_sum(acc1 * asl); if (lane == 0) asrc[v + 1] = p;
  p = wave_reduce_sum(acc2 * asl); if (lane == 0) asrc[v + 2] = p;
  p = wave_reduce_sum(acc3 * asl); if (lane == 0) asrc[v + 3] = p;
  p = wave_reduce_sum(acc0 * adl); if (lane == 0) adst[v + 0] = p;
  p = wave_reduce_sum(acc1 * adl); if (lane == 0) adst[v + 1] = p;
  p = wave_reduce_sum(acc2 * adl); if (lane == 0) adst[v + 2] = p;
  p = wave_reduce_sum(acc3 * adl); if (lane == 0) adst[v + 3] = p;
}

// softmax attention + aggregation. 16 lanes per node (float4 features),
// 4 nodes/wave, 16 nodes/block. Edge state cached in regs for deg<=64.
__global__ __launch_bounds__(256) void aggregate_kernel(
    const float4* __restrict__ g4, const float* __restrict__ asrc, const float* __restrict__ adst,
    const int* __restrict__ rowptr, const int* __restrict__ col,
    const float* __restrict__ ae4, const float* __restrict__ bias, float* __restrict__ hout) {
  int tid = threadIdx.x, wave = tid >> 6, lane = tid & 63;
  int sub = lane & 15;
  int base_lane = lane & 48;              // group base within wave
  int v = blockIdx.x * 16 + wave * 4 + (lane >> 4);   // NN % 16 == 0
  int start = rowptr[v], end = rowptr[v + 1];
  float adstv = adst[v];

  // pass 1: alphas for chunks 0..3 cached in regs; tail recomputed
  float alc[4]; int sc[4];
  float mx = -INFINITY;
  #pragma unroll
  for (int c = 0; c < 4; ++c) {
    alc[c] = -INFINITY; sc[c] = 0;
    int e = start + c * 16 + sub;
    if (e < end) {
      int p = col[e]; sc[c] = p & 0xFFFFF; int a = p >> 20;
      float al = asrc[sc[c]] + adstv + ae4[a];
      al = (al > 0.f) ? al : NEG_SLOPE * al;
      alc[c] = al; mx = fmaxf(mx, al);
    }
  }
  for (int base = start + 64; base < end; base += 16) {
    int e = base + sub;
    if (e < end) {
      int p = col[e]; int s = p & 0xFFFFF; int a = p >> 20;
      float al = asrc[s] + adstv + ae4[a];
      al = (al > 0.f) ? al : NEG_SLOPE * al;
      mx = fmaxf(mx, al);
    }
  }
  mx = group16_max(mx);

  // pass 2: exp + denom + aggregation (4 indep chains via float4)
  float4 acc = {0.f, 0.f, 0.f, 0.f};
  float den = 0.f;
  float exc[4];
  #pragma unroll
  for (int c = 0; c < 4; ++c) {
    int e = start + c * 16 + sub;
    exc[c] = (e < end) ? __expf(alc[c] - mx) : 0.f;
    den += exc[c];
  }
  #pragma unroll
  for (int c = 0; c < 4; ++c) {
    int cnt = end - (start + c * 16);
    if (cnt > 0) {
      if (cnt > 16) cnt = 16;
      for (int j = 0; j < cnt; ++j) {
        float exj = __shfl(exc[c], base_lane + j, 64);
        int sj = __shfl(sc[c], base_lane + j, 64);
        float4 gr = g4[(size_t)sj * 16 + sub];
        acc.x = fmaf(exj, gr.x, acc.x);
        acc.y = fmaf(exj, gr.y, acc.y);
        acc.z = fmaf(exj, gr.z, acc.z);
        acc.w = fmaf(exj, gr.w, acc.w);
      }
    }
  }
  for (int base = start + 64; base < end; base += 16) {
    int e = base + sub;
    float ex = 0.f; int s = 0;
    if (e < end) {
      int p = col[e]; s = p & 0xFFFFF; int a = p >> 20;
      float al = asrc[s] + adstv + ae4[a];
      al = (al > 0.f) ? al : NEG_SLOPE * al;
      ex = __expf(al - mx);
    }
    den += ex;
    int cnt = end - base; if (cnt > 16) cnt = 16;
    for (int j = 0; j < cnt; ++j) {
      float exj = __shfl(ex, base_lane + j, 64);
      int sj = __shfl(s, base_lane + j, 64);
      float4 gr = g4[(size_t)sj * 16 + sub];
      acc.x = fmaf(exj, gr.x, acc.x);
      acc.y = fmaf(exj, gr.y, acc.y);
      acc.z = fmaf(exj, gr.z, acc.z);
      acc.w = fmaf(exj, gr.w, acc.w);
    }
  }
  den = group16_sum(den);
  float inv = 1.f / (den + EPSF);
  float4 b4 = ((const float4*)bias)[sub];
  float4 o;
  o.x = fmaxf(fmaf(acc.x, inv, b4.x), 0.f);
  o.y = fmaxf(fmaf(acc.y, inv, b4.y), 0.f);
  o.z = fmaxf(fmaf(acc.z, inv, b4.z), 0.f);
  o.w = fmaxf(fmaf(acc.w, inv, b4.w), 0.f);
  ((float4*)hout)[(size_t)v * 16 + sub] = o;
}

// pooled[g] = sum of h rows in [lo,hi) where batch==g (batch sorted)
__global__ __launch_bounds__(256) void pool_kernel(const float* __restrict__ h,
                                                   const int* __restrict__ batch,
                                                   float* __restrict__ pooled) {
  __shared__ int s_lo, s_hi;
  __shared__ float red[4][DD];
  int gI = blockIdx.x;
  int tid = threadIdx.x, wave = tid >> 6, lane = tid & 63;
  if (tid == 0) {
    int lo = 0, hi = NN;
    while (lo < hi) { int mid = (lo + hi) >> 1; if (batch[mid] < gI) lo = mid + 1; else hi = mid; }
    s_lo = lo;
    lo = 0; hi = NN;
    while (lo < hi) { int mid = (lo + hi) >> 1; if (batch[mid] < gI + 1) lo = mid + 1; else hi = mid; }
    s_hi = lo;
  }
  __syncthreads();
  float acc = 0.f;
  for (int v = s_lo + wave; v < s_hi; v += 4) acc += h[v * DD + lane];
  red[wave][lane] = acc;
  __syncthreads();
  if (wave == 0)
    pooled[gI * DD + lane] = red[0][lane] + red[1][lane] + red[2][lane] + red[3][lane];
}

// hidden = relu(pooled @ W1^T + b1); out = hidden @ W2^T + b2
__global__ __launch_bounds__(128) void mlp_kernel(const float* __restrict__ pooled,
                                                  const float* __restrict__ W1, const float* __restrict__ b1,
                                                  const float* __restrict__ W2, const float* __restrict__ b2,
                                                  float* __restrict__ out) {
  __shared__ float sp[DD];
  __shared__ float sh[2 * DD];
  int gI = blockIdx.x, t = threadIdx.x;
  if (t < DD) sp[t] = pooled[gI * DD + t];
  __syncthreads();
  float acc = b1[t];
  for (int d = 0; d < DD; ++d) acc += sp[d] * W1[t * DD + d];
  sh[t] = fmaxf(acc, 0.f);
  __syncthreads();
  if (t < TT) {
    float o = b2[t];
    for (int k = 0; k < 2 * DD; ++k) o += sh[k] * W2[t * 2 * DD + k];
    out[gI * TT + t] = o;
  }
}

extern "C" void kernel_launch(void* const* d_in, const int* in_sizes, int n_in,
                              void* d_out, int out_size, void* d_ws, size_t ws_size,
                              hipStream_t stream) {
  const int* x          = (const int*)d_in[0];
  const int* edge_index = (const int*)d_in[1];
  const int* edge_attr  = (const int*)d_in[2];
  const int* batch      = (const int*)d_in[3];
  const float* node_emb = (const float*)d_in[4];
  const float* edge_embs= (const float*)d_in[5];
  const float* Ws_      = (const float*)d_in[6];
  const float* W_edges  = (const float*)d_in[7];
  const float* att_src  = (const float*)d_in[8];
  const float* att_dst  = (const float*)d_in[9];
  const float* att_edge = (const float*)d_in[10];
  const float* biases   = (const float*)d_in[11];
  const float* W1       = (const float*)d_in[12];
  const float* b1       = (const float*)d_in[13];
  const float* W2       = (const float*)d_in[14];
  const float* b2       = (const float*)d_in[15];
  float* out = (float*)d_out;

  char* wsp = (char*)d_ws;
  float* h      = (float*)wsp; wsp += (size_t)NN * DD * 4;
  float* g      = (float*)wsp; wsp += (size_t)NN * DD * 4;
  float* asrc   = (float*)wsp; wsp += (size_t)NN * 4;
  float* adst   = (float*)wsp; wsp += (size_t)NN * 4;
  float* ae_tab = (float*)wsp; wsp += 16 * 4;
  float* pooled = (float*)wsp; wsp += (size_t)GG * DD * 4;
  int* rowptr   = (int*)wsp;   wsp += (size_t)(NN + 1) * 4;
  int* cursor   = (int*)wsp;   wsp += (size_t)NN * 4;
  int* partials = (int*)wsp;   wsp += (size_t)(NBLK + 1) * 4;
  int* col      = (int*)wsp;   wsp += (size_t)NE * 4;

  const int* src = edge_index;
  const int* dst = edge_index + NE;

  hipMemsetAsync(cursor, 0, NN * sizeof(int), stream);
  embed_kernel<<<(NN * DD + 255) / 256, 256, 0, stream>>>(x, node_emb, h);
  hist_kernel<<<(NE + 255) / 256, 256, 0, stream>>>(dst, cursor);
  scan_partial_kernel<<<NBLK, 256, 0, stream>>>(cursor, partials);
  scan_base_kernel<<<1, 256, 0, stream>>>(partials, rowptr);
  scan_apply_kernel<<<NBLK, 256, 0, stream>>>(partials, cursor, rowptr);
  scatter_kernel<<<(NE + 255) / 256, 256, 0, stream>>>(src, dst, edge_attr, cursor, col);
  prep_ae_kernel<<<16, 64, 0, stream>>>(edge_embs, W_edges, att_edge, ae_tab);

  for (int l = 0; l < LL; ++l) {
    gemm_attn_kernel<<<NN / 16, 256, 0, stream>>>(h, Ws_ + l * DD * DD,
                                                  att_src + l * DD, att_dst + l * DD,
                                                  g, asrc, adst);
    aggregate_kernel<<<NN / 16, 256, 0, stream>>>((const float4*)g, asrc, adst, rowptr, col,
                                                  ae_tab + l * 4, biases + l * DD, h);
  }

  pool_kernel<<<GG, 256, 0, stream>>>(h, batch, pooled);
  mlp_kernel<<<GG, 128, 0, stream>>>(pooled, W1, b1, W2, b2, out);
}

// Round 6
// 454.404 us; speedup vs baseline: 1.9530x; 1.0308x over previous
//
#include <hip/hip_runtime.h>
#include <math.h>

#define NN 50000
#define NE 800000
#define DD 64
#define LL 4
#define GG 128
#define TT 10
#define NEG_SLOPE 0.2f
#define EPSF 1e-16f

#define BSHIFT 9
#define BNODES 512                       // nodes per bucket
#define NBUK ((NN + BNODES - 1) / BNODES)  // 98
#define CHUNK 2048
#define CAP 96                           // LDS slots per bucket per chunk (mean 21, +16 sigma)

__device__ __forceinline__ float wave_reduce_sum(float v) {
  #pragma unroll
  for (int off = 32; off > 0; off >>= 1) v += __shfl_xor(v, off, 64);
  return v;
}
__device__ __forceinline__ float group16_max(float v) {
  #pragma unroll
  for (int off = 1; off < 16; off <<= 1) v = fmaxf(v, __shfl_xor(v, off, 64));
  return v;
}
__device__ __forceinline__ float group16_sum(float v) {
  #pragma unroll
  for (int off = 1; off < 16; off <<= 1) v += __shfl_xor(v, off, 64);
  return v;
}
__device__ __forceinline__ int wave_incl_scan(int v) {
  int lane = threadIdx.x & 63;
  #pragma unroll
  for (int off = 1; off < 64; off <<= 1) {
    int t = __shfl_up(v, off, 64);
    if (lane >= off) v += t;
  }
  return v;
}

// h[v][d] = node_emb[x[v]][d]
__global__ void embed_kernel(const int* __restrict__ x, const float* __restrict__ node_emb,
                             float* __restrict__ h) {
  int i = blockIdx.x * blockDim.x + threadIdx.x;
  if (i < NN * DD) {
    int v = i >> 6, d = i & 63;
    h[i] = node_emb[x[v] * DD + d];
  }
}

// per-block LDS histogram of dst>>BSHIFT -> global bucket counts
__global__ __launch_bounds__(256) void bucket_count_kernel(const int* __restrict__ dst,
                                                           int* __restrict__ bcnt) {
  __shared__ int cnt[NBUK];
  int tid = threadIdx.x;
  for (int i = tid; i < NBUK; i += 256) cnt[i] = 0;
  __syncthreads();
  int e0 = blockIdx.x * CHUNK;
  for (int i = tid; i < CHUNK; i += 256) {
    int e = e0 + i;
    if (e < NE) atomicAdd(&cnt[dst[e] >> BSHIFT], 1);
  }
  __syncthreads();
  for (int b = tid; b < NBUK; b += 256)
    if (cnt[b]) atomicAdd(&bcnt[b], cnt[b]);
}

// exclusive scan of NBUK (<=128) bucket counts -> bbase; rowptr[NN] = NE
__global__ __launch_bounds__(128) void bucket_scan_kernel(const int* __restrict__ bcnt,
                                                          int* __restrict__ bbase,
                                                          int* __restrict__ rowptr) {
  __shared__ int w0sum;
  int tid = threadIdx.x, lane = tid & 63, wave = tid >> 6;
  int v = (tid < NBUK) ? bcnt[tid] : 0;
  int incl = wave_incl_scan(v);
  if (wave == 0 && lane == 63) w0sum = incl;
  __syncthreads();
  int excl = incl - v + (wave ? w0sum : 0);
  if (tid < NBUK) bbase[tid] = excl;
  if (tid == 0) rowptr[NN] = NE;
}

// bin CHUNK edges into LDS buckets, reserve contiguous spans, flush coalesced.
// packed record: src[0:17) | attr[17:19) | dstlow[19:28)
__global__ __launch_bounds__(256) void bucket_bin_kernel(
    const int* __restrict__ src, const int* __restrict__ dst, const int* __restrict__ attr,
    const int* __restrict__ bbase, int* __restrict__ bcursor, int* __restrict__ stag) {
  __shared__ int cnt[NBUK];
  __shared__ int gbase[NBUK];
  __shared__ int buf[NBUK][CAP];   // 98*96*4 = 37.6 KB
  int tid = threadIdx.x;
  for (int i = tid; i < NBUK; i += 256) cnt[i] = 0;
  __syncthreads();
  int e0 = blockIdx.x * CHUNK;
  for (int i = tid; i < CHUNK; i += 256) {
    int e = e0 + i;
    if (e < NE) {
      int d = dst[e];
      int b = d >> BSHIFT;
      int p = atomicAdd(&cnt[b], 1);
      buf[b][p] = src[e] | (attr[e] << 17) | ((d & (BNODES - 1)) << 19);
    }
  }
  __syncthreads();
  for (int b = tid; b < NBUK; b += 256)
    gbase[b] = (cnt[b] > 0) ? (bbase[b] + atomicAdd(&bcursor[b], cnt[b])) : 0;
  __syncthreads();
  for (int b = 0; b < NBUK; ++b) {
    int n = cnt[b];
    for (int i = tid; i < n; i += 256)
      stag[gbase[b] + i] = buf[b][i];
  }
}

// per bucket: local hist(512) -> scan -> rowptr; scatter col within 32KB window.
// col entry format: src | attr<<20  (same as before)
__global__ __launch_bounds__(256) void bucket_csr_kernel(
    const int* __restrict__ bbase, const int* __restrict__ stag,
    int* __restrict__ rowptr, int* __restrict__ col) {
  __shared__ int hist[BNODES];
  __shared__ int wsum[4];
  int b = blockIdx.x, tid = threadIdx.x, lane = tid & 63, wave = tid >> 6;
  int base = bbase[b];
  int endb = (b == NBUK - 1) ? NE : bbase[b + 1];
  int n = endb - base;
  int nodes0 = b << BSHIFT;
  int nloc = NN - nodes0; if (nloc > BNODES) nloc = BNODES;
  for (int i = tid; i < BNODES; i += 256) hist[i] = 0;
  __syncthreads();
  for (int i = tid; i < n; i += 256)
    atomicAdd(&hist[(stag[base + i] >> 19) & (BNODES - 1)], 1);
  __syncthreads();
  // scan 512 with 256 threads: 2 elems/thread
  int a0 = hist[2 * tid], a1 = hist[2 * tid + 1];
  int pairsum = a0 + a1;
  int incl = wave_incl_scan(pairsum);
  if (lane == 63) wsum[wave] = incl;
  __syncthreads();
  int wbase = 0;
  for (int w = 0; w < wave; ++w) wbase += wsum[w];
  int excl = incl - pairsum + wbase;      // bucket-relative exclusive over pairs
  if (2 * tid < nloc)     rowptr[nodes0 + 2 * tid]     = base + excl;
  if (2 * tid + 1 < nloc) rowptr[nodes0 + 2 * tid + 1] = base + excl + a0;
  __syncthreads();
  hist[2 * tid] = excl;
  hist[2 * tid + 1] = excl + a0;
  __syncthreads();
  for (int i = tid; i < n; i += 256) {
    int p = stag[base + i];
    int dl = (p >> 19) & (BNODES - 1);
    int pos = atomicAdd(&hist[dl], 1);
    col[base + pos] = (p & 0x1FFFF) | (((p >> 17) & 3) << 20);
  }
}

// ae_tab[l*4+k] = e_tab[l][k] . (W_edges[l]^T att_edge[l])
__global__ __launch_bounds__(64) void prep_ae_kernel(const float* __restrict__ edge_embs,
                                                     const float* __restrict__ W_edges,
                                                     const float* __restrict__ att_edge,
                                                     float* __restrict__ ae_tab) {
  int t = blockIdx.x;          // 0..15
  int l = t >> 2, k = t & 3;
  int j = threadIdx.x;         // 0..63
  const float* We = W_edges + l * DD * DD;
  const float* aE = att_edge + l * DD;
  const float* et = edge_embs + (l * 4 + k) * DD;
  float tj = 0.f;
  #pragma unroll 8
  for (int d = 0; d < DD; ++d) tj = fmaf(We[d * DD + j], aE[d], tj);
  float acc = wave_reduce_sum(et[j] * tj);
  if (j == 0) ae_tab[t] = acc;
}

// g = h @ W^T ; asrc = g . a_src ; adst = g . a_dst
__global__ __launch_bounds__(256) void gemm_attn_kernel(
    const float* __restrict__ h, const float* __restrict__ W,
    const float* __restrict__ a_src, const float* __restrict__ a_dst,
    float* __restrict__ g, float* __restrict__ asrc, float* __restrict__ adst) {
  __shared__ float Wsm[DD][68];
  __shared__ float hs[16][DD];
  int tid = threadIdx.x, wave = tid >> 6, lane = tid & 63;
  int vbase = blockIdx.x * 16;
  for (int idx = tid; idx < DD * DD; idx += 256) Wsm[idx >> 6][idx & 63] = W[idx];
  for (int idx = tid; idx < 16 * DD; idx += 256) hs[idx >> 6][idx & 63] = h[vbase * DD + idx];
  __syncthreads();
  float acc0 = 0.f, acc1 = 0.f, acc2 = 0.f, acc3 = 0.f;
  int r = wave * 4;
  #pragma unroll
  for (int j4 = 0; j4 < DD / 4; ++j4) {
    float4 wv = *(const float4*)&Wsm[lane][j4 * 4];
    float4 h0 = *(const float4*)&hs[r + 0][j4 * 4];
    float4 h1 = *(const float4*)&hs[r + 1][j4 * 4];
    float4 h2 = *(const float4*)&hs[r + 2][j4 * 4];
    float4 h3 = *(const float4*)&hs[r + 3][j4 * 4];
    acc0 = fmaf(wv.x, h0.x, acc0); acc0 = fmaf(wv.y, h0.y, acc0);
    acc0 = fmaf(wv.z, h0.z, acc0); acc0 = fmaf(wv.w, h0.w, acc0);
    acc1 = fmaf(wv.x, h1.x, acc1); acc1 = fmaf(wv.y, h1.y, acc1);
    acc1 = fmaf(wv.z, h1.z, acc1); acc1 = fmaf(wv.w, h1.w, acc1);
    acc2 = fmaf(wv.x, h2.x, acc2); acc2 = fmaf(wv.y, h2.y, acc2);
    acc2 = fmaf(wv.z, h2.z, acc2); acc2 = fmaf(wv.w, h2.w, acc2);
    acc3 = fmaf(wv.x, h3.x, acc3); acc3 = fmaf(wv.y, h3.y, acc3);
    acc3 = fmaf(wv.z, h3.z, acc3); acc3 = fmaf(wv.w, h3.w, acc3);
  }
  int v = vbase + r;
  g[(v + 0) * DD + lane] = acc0;
  g[(v + 1) * DD + lane] = acc1;
  g[(v + 2) * DD + lane] = acc2;
  g[(v + 3) * DD + lane] = acc3;
  float asl = a_src[lane], adl = a_dst[lane];
  float p;
  p = wave_reduce_sum(acc0 * asl); if (lane == 0) asrc[v + 0] = p;
  p = wave_reduce_sum(acc1 * asl); if (lane == 0) asrc[v + 1] = p;
  p = wave_reduce_sum(acc2 * asl); if (lane == 0) asrc[v + 2] = p;
  p = wave_reduce_sum(acc3 * asl); if (lane == 0) asrc[v + 3] = p;
  p = wave_reduce_sum(acc0 * adl); if (lane == 0) adst[v + 0] = p;
  p = wave_reduce_sum(acc1 * adl); if (lane == 0) adst[v + 1] = p;
  p = wave_reduce_sum(acc2 * adl); if (lane == 0) adst[v + 2] = p;
  p = wave_reduce_sum(acc3 * adl); if (lane == 0) adst[v + 3] = p;
}

// softmax attention + aggregation. 16 lanes per node (float4 features).
__global__ __launch_bounds__(256) void aggregate_kernel(
    const float4* __restrict__ g4, const float* __restrict__ asrc, const float* __restrict__ adst,
    const int* __restrict__ rowptr, const int* __restrict__ col,
    const float* __restrict__ ae4, const float* __restrict__ bias, float* __restrict__ hout) {
  int tid = threadIdx.x, wave = tid >> 6, lane = tid & 63;
  int sub = lane & 15;
  int base_lane = lane & 48;
  int v = blockIdx.x * 16 + wave * 4 + (lane >> 4);
  int start = rowptr[v], end = rowptr[v + 1];
  float adstv = adst[v];

  float alc[4]; int sc[4];
  float mx = -INFINITY;
  #pragma unroll
  for (int c = 0; c < 4; ++c) {
    alc[c] = -INFINITY; sc[c] = 0;
    int e = start + c * 16 + sub;
    if (e < end) {
      int p = col[e]; sc[c] = p & 0xFFFFF; int a = p >> 20;
      float al = asrc[sc[c]] + adstv + ae4[a];
      al = (al > 0.f) ? al : NEG_SLOPE * al;
      alc[c] = al; mx = fmaxf(mx, al);
    }
  }
  for (int base = start + 64; base < end; base += 16) {
    int e = base + sub;
    if (e < end) {
      int p = col[e]; int s = p & 0xFFFFF; int a = p >> 20;
      float al = asrc[s] + adstv + ae4[a];
      al = (al > 0.f) ? al : NEG_SLOPE * al;
      mx = fmaxf(mx, al);
    }
  }
  mx = group16_max(mx);

  float4 acc = {0.f, 0.f, 0.f, 0.f};
  float den = 0.f;
  float exc[4];
  #pragma unroll
  for (int c = 0; c < 4; ++c) {
    int e = start + c * 16 + sub;
    exc[c] = (e < end) ? __expf(alc[c] - mx) : 0.f;
    den += exc[c];
  }
  #pragma unroll
  for (int c = 0; c < 4; ++c) {
    int cnt = end - (start + c * 16);
    if (cnt > 0) {
      if (cnt > 16) cnt = 16;
      for (int j = 0; j < cnt; ++j) {
        float exj = __shfl(exc[c], base_lane + j, 64);
        int sj = __shfl(sc[c], base_lane + j, 64);
        float4 gr = g4[(size_t)sj * 16 + sub];
        acc.x = fmaf(exj, gr.x, acc.x);
        acc.y = fmaf(exj, gr.y, acc.y);
        acc.z = fmaf(exj, gr.z, acc.z);
        acc.w = fmaf(exj, gr.w, acc.w);
      }
    }
  }
  for (int base = start + 64; base < end; base += 16) {
    int e = base + sub;
    float ex = 0.f; int s = 0;
    if (e < end) {
      int p = col[e]; s = p & 0xFFFFF; int a = p >> 20;
      float al = asrc[s] + adstv + ae4[a];
      al = (al > 0.f) ? al : NEG_SLOPE * al;
      ex = __expf(al - mx);
    }
    den += ex;
    int cnt = end - base; if (cnt > 16) cnt = 16;
    for (int j = 0; j < cnt; ++j) {
      float exj = __shfl(ex, base_lane + j, 64);
      int sj = __shfl(s, base_lane + j, 64);
      float4 gr = g4[(size_t)sj * 16 + sub];
      acc.x = fmaf(exj, gr.x, acc.x);
      acc.y = fmaf(exj, gr.y, acc.y);
      acc.z = fmaf(exj, gr.z, acc.z);
      acc.w = fmaf(exj, gr.w, acc.w);
    }
  }
  den = group16_sum(den);
  float inv = 1.f / (den + EPSF);
  float4 b4 = ((const float4*)bias)[sub];
  float4 o;
  o.x = fmaxf(fmaf(acc.x, inv, b4.x), 0.f);
  o.y = fmaxf(fmaf(acc.y, inv, b4.y), 0.f);
  o.z = fmaxf(fmaf(acc.z, inv, b4.z), 0.f);
  o.w = fmaxf(fmaf(acc.w, inv, b4.w), 0.f);
  ((float4*)hout)[(size_t)v * 16 + sub] = o;
}

// pooled[g] = sum of h rows in [lo,hi) where batch==g (batch sorted)
__global__ __launch_bounds__(256) void pool_kernel(const float* __restrict__ h,
                                                   const int* __restrict__ batch,
                                                   float* __restrict__ pooled) {
  __shared__ int s_lo, s_hi;
  __shared__ float red[4][DD];
  int gI = blockIdx.x;
  int tid = threadIdx.x, wave = tid >> 6, lane = tid & 63;
  if (tid == 0) {
    int lo = 0, hi = NN;
    while (lo < hi) { int mid = (lo + hi) >> 1; if (batch[mid] < gI) lo = mid + 1; else hi = mid; }
    s_lo = lo;
    lo = 0; hi = NN;
    while (lo < hi) { int mid = (lo + hi) >> 1; if (batch[mid] < gI + 1) lo = mid + 1; else hi = mid; }
    s_hi = lo;
  }
  __syncthreads();
  float acc = 0.f;
  for (int v = s_lo + wave; v < s_hi; v += 4) acc += h[v * DD + lane];
  red[wave][lane] = acc;
  __syncthreads();
  if (wave == 0)
    pooled[gI * DD + lane] = red[0][lane] + red[1][lane] + red[2][lane] + red[3][lane];
}

// hidden = relu(pooled @ W1^T + b1); out = hidden @ W2^T + b2
__global__ __launch_bounds__(128) void mlp_kernel(const float* __restrict__ pooled,
                                                  const float* __restrict__ W1, const float* __restrict__ b1,
                                                  const float* __restrict__ W2, const float* __restrict__ b2,
                                                  float* __restrict__ out) {
  __shared__ float sp[DD];
  __shared__ float sh[2 * DD];
  int gI = blockIdx.x, t = threadIdx.x;
  if (t < DD) sp[t] = pooled[gI * DD + t];
  __syncthreads();
  float acc = b1[t];
  for (int d = 0; d < DD; ++d) acc += sp[d] * W1[t * DD + d];
  sh[t] = fmaxf(acc, 0.f);
  __syncthreads();
  if (t < TT) {
    float o = b2[t];
    for (int k = 0; k < 2 * DD; ++k) o += sh[k] * W2[t * 2 * DD + k];
    out[gI * TT + t] = o;
  }
}

extern "C" void kernel_launch(void* const* d_in, const int* in_sizes, int n_in,
                              void* d_out, int out_size, void* d_ws, size_t ws_size,
                              hipStream_t stream) {
  const int* x          = (const int*)d_in[0];
  const int* edge_index = (const int*)d_in[1];
  const int* edge_attr  = (const int*)d_in[2];
  const int* batch      = (const int*)d_in[3];
  const float* node_emb = (const float*)d_in[4];
  const float* edge_embs= (const float*)d_in[5];
  const float* Ws_      = (const float*)d_in[6];
  const float* W_edges  = (const float*)d_in[7];
  const float* att_src  = (const float*)d_in[8];
  const float* att_dst  = (const float*)d_in[9];
  const float* att_edge = (const float*)d_in[10];
  const float* biases   = (const float*)d_in[11];
  const float* W1       = (const float*)d_in[12];
  const float* b1       = (const float*)d_in[13];
  const float* W2       = (const float*)d_in[14];
  const float* b2       = (const float*)d_in[15];
  float* out = (float*)d_out;

  char* wsp = (char*)d_ws;
  float* h      = (float*)wsp; wsp += (size_t)NN * DD * 4;
  float* g      = (float*)wsp; wsp += (size_t)NN * DD * 4;
  float* asrc   = (float*)wsp; wsp += (size_t)NN * 4;
  float* adst   = (float*)wsp; wsp += (size_t)NN * 4;
  float* ae_tab = (float*)wsp; wsp += 16 * 4;
  float* pooled = (float*)wsp; wsp += (size_t)GG * DD * 4;
  int* rowptr   = (int*)wsp;   wsp += (size_t)(NN + 1) * 4;
  int* bcnt     = (int*)wsp;   wsp += (size_t)NBUK * 4;   // zeroed
  int* bcursor  = (int*)wsp;   wsp += (size_t)NBUK * 4;   // zeroed (adjacent to bcnt)
  int* bbase    = (int*)wsp;   wsp += (size_t)NBUK * 4;
  int* stag     = (int*)wsp;   wsp += (size_t)NE * 4;
  int* col      = (int*)wsp;   wsp += (size_t)NE * 4;

  const int* src = edge_index;
  const int* dst = edge_index + NE;

  const int nchunk = (NE + CHUNK - 1) / CHUNK;   // 391

  hipMemsetAsync(bcnt, 0, 2 * NBUK * sizeof(int), stream);   // bcnt + bcursor
  embed_kernel<<<(NN * DD + 255) / 256, 256, 0, stream>>>(x, node_emb, h);
  bucket_count_kernel<<<nchunk, 256, 0, stream>>>(dst, bcnt);
  bucket_scan_kernel<<<1, 128, 0, stream>>>(bcnt, bbase, rowptr);
  bucket_bin_kernel<<<nchunk, 256, 0, stream>>>(src, dst, edge_attr, bbase, bcursor, stag);
  bucket_csr_kernel<<<NBUK, 256, 0, stream>>>(bbase, stag, rowptr, col);
  prep_ae_kernel<<<16, 64, 0, stream>>>(edge_embs, W_edges, att_edge, ae_tab);

  for (int l = 0; l < LL; ++l) {
    gemm_attn_kernel<<<NN / 16, 256, 0, stream>>>(h, Ws_ + l * DD * DD,
                                                  att_src + l * DD, att_dst + l * DD,
                                                  g, asrc, adst);
    aggregate_kernel<<<NN / 16, 256, 0, stream>>>((const float4*)g, asrc, adst, rowptr, col,
                                                  ae_tab + l * 4, biases + l * DD, h);
  }

  pool_kernel<<<GG, 256, 0, stream>>>(h, batch, pooled);
  mlp_kernel<<<GG, 128, 0, stream>>>(pooled, W1, b1, W2, b2, out);
}

// Round 7
// 437.615 us; speedup vs baseline: 2.0279x; 1.0384x over previous
//
#include <hip/hip_runtime.h>
#include <math.h>

#define NN 50000
#define NE 800000
#define DD 64
#define LL 4
#define GG 128
#define TT 10
#define NEG_SLOPE 0.2f
#define EPSF 1e-16f

#define BSHIFT 9
#define BNODES 512                       // nodes per bucket
#define NBUK ((NN + BNODES - 1) / BNODES)  // 98
#define CHUNK 2048

__device__ __forceinline__ float wave_reduce_sum(float v) {
  #pragma unroll
  for (int off = 32; off > 0; off >>= 1) v += __shfl_xor(v, off, 64);
  return v;
}
__device__ __forceinline__ float group16_max(float v) {
  #pragma unroll
  for (int off = 1; off < 16; off <<= 1) v = fmaxf(v, __shfl_xor(v, off, 64));
  return v;
}
__device__ __forceinline__ float group16_sum(float v) {
  #pragma unroll
  for (int off = 1; off < 16; off <<= 1) v += __shfl_xor(v, off, 64);
  return v;
}
__device__ __forceinline__ int wave_incl_scan(int v) {
  int lane = threadIdx.x & 63;
  #pragma unroll
  for (int off = 1; off < 64; off <<= 1) {
    int t = __shfl_up(v, off, 64);
    if (lane >= off) v += t;
  }
  return v;
}

// h[v][d] = node_emb[x[v]][d]
__global__ void embed_kernel(const int* __restrict__ x, const float* __restrict__ node_emb,
                             float* __restrict__ h) {
  int i = blockIdx.x * blockDim.x + threadIdx.x;
  if (i < NN * DD) {
    int v = i >> 6, d = i & 63;
    h[i] = node_emb[x[v] * DD + d];
  }
}

// per-block LDS histogram of dst>>BSHIFT -> global bucket counts
__global__ __launch_bounds__(256) void bucket_count_kernel(const int* __restrict__ dst,
                                                           int* __restrict__ bcnt) {
  __shared__ int cnt[NBUK];
  int tid = threadIdx.x;
  for (int i = tid; i < NBUK; i += 256) cnt[i] = 0;
  __syncthreads();
  int e0 = blockIdx.x * CHUNK;
  for (int i = tid; i < CHUNK; i += 256) {
    int e = e0 + i;
    if (e < NE) atomicAdd(&cnt[dst[e] >> BSHIFT], 1);
  }
  __syncthreads();
  for (int b = tid; b < NBUK; b += 256)
    if (cnt[b]) atomicAdd(&bcnt[b], cnt[b]);
}

// exclusive scan of NBUK (<=128) bucket counts -> bbase; rowptr[NN] = NE
__global__ __launch_bounds__(128) void bucket_scan_kernel(const int* __restrict__ bcnt,
                                                          int* __restrict__ bbase,
                                                          int* __restrict__ rowptr) {
  __shared__ int w0sum;
  int tid = threadIdx.x, lane = tid & 63, wave = tid >> 6;
  int v = (tid < NBUK) ? bcnt[tid] : 0;
  int incl = wave_incl_scan(v);
  if (wave == 0 && lane == 63) w0sum = incl;
  __syncthreads();
  int excl = incl - v + (wave ? w0sum : 0);
  if (tid < NBUK) bbase[tid] = excl;
  if (tid == 0) rowptr[NN] = NE;
}

// count chunk's bucket histogram in LDS, reserve contiguous spans, then
// scatter DIRECTLY to global (each span is block-private => line locality).
// packed record: src[0:17) | attr[17:19) | dstlow[19:28)
__global__ __launch_bounds__(256) void bucket_bin_kernel(
    const int* __restrict__ src, const int* __restrict__ dst, const int* __restrict__ attr,
    const int* __restrict__ bbase, int* __restrict__ bcursor, int* __restrict__ stag) {
  __shared__ int cnt[NBUK];
  __shared__ int gcur[NBUK];
  int tid = threadIdx.x;
  for (int i = tid; i < NBUK; i += 256) cnt[i] = 0;
  __syncthreads();
  int e0 = blockIdx.x * CHUNK;
  // pass 1: count
  for (int i = tid; i < CHUNK; i += 256) {
    int e = e0 + i;
    if (e < NE) atomicAdd(&cnt[dst[e] >> BSHIFT], 1);
  }
  __syncthreads();
  // reserve spans (one global atomic per non-empty bucket)
  for (int b = tid; b < NBUK; b += 256)
    gcur[b] = (cnt[b] > 0) ? (bbase[b] + atomicAdd(&bcursor[b], cnt[b])) : 0;
  __syncthreads();
  // pass 2: scatter straight to global
  for (int i = tid; i < CHUNK; i += 256) {
    int e = e0 + i;
    if (e < NE) {
      int d = dst[e];
      int b = d >> BSHIFT;
      int pos = atomicAdd(&gcur[b], 1);
      stag[pos] = src[e] | (attr[e] << 17) | ((d & (BNODES - 1)) << 19);
    }
  }
}

// per bucket: local hist(512) -> scan -> rowptr; scatter col within 32KB window.
// col entry format: src | attr<<20  (same as before)
__global__ __launch_bounds__(256) void bucket_csr_kernel(
    const int* __restrict__ bbase, const int* __restrict__ stag,
    int* __restrict__ rowptr, int* __restrict__ col) {
  __shared__ int hist[BNODES];
  __shared__ int wsum[4];
  int b = blockIdx.x, tid = threadIdx.x, lane = tid & 63, wave = tid >> 6;
  int base = bbase[b];
  int endb = (b == NBUK - 1) ? NE : bbase[b + 1];
  int n = endb - base;
  int nodes0 = b << BSHIFT;
  int nloc = NN - nodes0; if (nloc > BNODES) nloc = BNODES;
  for (int i = tid; i < BNODES; i += 256) hist[i] = 0;
  __syncthreads();
  for (int i = tid; i < n; i += 256)
    atomicAdd(&hist[(stag[base + i] >> 19) & (BNODES - 1)], 1);
  __syncthreads();
  // scan 512 with 256 threads: 2 elems/thread
  int a0 = hist[2 * tid], a1 = hist[2 * tid + 1];
  int pairsum = a0 + a1;
  int incl = wave_incl_scan(pairsum);
  if (lane == 63) wsum[wave] = incl;
  __syncthreads();
  int wbase = 0;
  for (int w = 0; w < wave; ++w) wbase += wsum[w];
  int excl = incl - pairsum + wbase;      // bucket-relative exclusive over pairs
  if (2 * tid < nloc)     rowptr[nodes0 + 2 * tid]     = base + excl;
  if (2 * tid + 1 < nloc) rowptr[nodes0 + 2 * tid + 1] = base + excl + a0;
  __syncthreads();
  hist[2 * tid] = excl;
  hist[2 * tid + 1] = excl + a0;
  __syncthreads();
  for (int i = tid; i < n; i += 256) {
    int p = stag[base + i];
    int dl = (p >> 19) & (BNODES - 1);
    int pos = atomicAdd(&hist[dl], 1);
    col[base + pos] = (p & 0x1FFFF) | (((p >> 17) & 3) << 20);
  }
}

// ae_tab[l*4+k] = e_tab[l][k] . (W_edges[l]^T att_edge[l])
__global__ __launch_bounds__(64) void prep_ae_kernel(const float* __restrict__ edge_embs,
                                                     const float* __restrict__ W_edges,
                                                     const float* __restrict__ att_edge,
                                                     float* __restrict__ ae_tab) {
  int t = blockIdx.x;          // 0..15
  int l = t >> 2, k = t & 3;
  int j = threadIdx.x;         // 0..63
  const float* We = W_edges + l * DD * DD;
  const float* aE = att_edge + l * DD;
  const float* et = edge_embs + (l * 4 + k) * DD;
  float tj = 0.f;
  #pragma unroll 8
  for (int d = 0; d < DD; ++d) tj = fmaf(We[d * DD + j], aE[d], tj);
  float acc = wave_reduce_sum(et[j] * tj);
  if (j == 0) ae_tab[t] = acc;
}

// g = h @ W^T ; asrc = g . a_src ; adst = g . a_dst
__global__ __launch_bounds__(256) void gemm_attn_kernel(
    const float* __restrict__ h, const float* __restrict__ W,
    const float* __restrict__ a_src, const float* __restrict__ a_dst,
    float* __restrict__ g, float* __restrict__ asrc, float* __restrict__ adst) {
  __shared__ float Wsm[DD][68];
  __shared__ float hs[16][DD];
  int tid = threadIdx.x, wave = tid >> 6, lane = tid & 63;
  int vbase = blockIdx.x * 16;
  for (int idx = tid; idx < DD * DD; idx += 256) Wsm[idx >> 6][idx & 63] = W[idx];
  for (int idx = tid; idx < 16 * DD; idx += 256) hs[idx >> 6][idx & 63] = h[vbase * DD + idx];
  __syncthreads();
  float acc0 = 0.f, acc1 = 0.f, acc2 = 0.f, acc3 = 0.f;
  int r = wave * 4;
  #pragma unroll
  for (int j4 = 0; j4 < DD / 4; ++j4) {
    float4 wv = *(const float4*)&Wsm[lane][j4 * 4];
    float4 h0 = *(const float4*)&hs[r + 0][j4 * 4];
    float4 h1 = *(const float4*)&hs[r + 1][j4 * 4];
    float4 h2 = *(const float4*)&hs[r + 2][j4 * 4];
    float4 h3 = *(const float4*)&hs[r + 3][j4 * 4];
    acc0 = fmaf(wv.x, h0.x, acc0); acc0 = fmaf(wv.y, h0.y, acc0);
    acc0 = fmaf(wv.z, h0.z, acc0); acc0 = fmaf(wv.w, h0.w, acc0);
    acc1 = fmaf(wv.x, h1.x, acc1); acc1 = fmaf(wv.y, h1.y, acc1);
    acc1 = fmaf(wv.z, h1.z, acc1); acc1 = fmaf(wv.w, h1.w, acc1);
    acc2 = fmaf(wv.x, h2.x, acc2); acc2 = fmaf(wv.y, h2.y, acc2);
    acc2 = fmaf(wv.z, h2.z, acc2); acc2 = fmaf(wv.w, h2.w, acc2);
    acc3 = fmaf(wv.x, h3.x, acc3); acc3 = fmaf(wv.y, h3.y, acc3);
    acc3 = fmaf(wv.z, h3.z, acc3); acc3 = fmaf(wv.w, h3.w, acc3);
  }
  int v = vbase + r;
  g[(v + 0) * DD + lane] = acc0;
  g[(v + 1) * DD + lane] = acc1;
  g[(v + 2) * DD + lane] = acc2;
  g[(v + 3) * DD + lane] = acc3;
  float asl = a_src[lane], adl = a_dst[lane];
  float p;
  p = wave_reduce_sum(acc0 * asl); if (lane == 0) asrc[v + 0] = p;
  p = wave_reduce_sum(acc1 * asl); if (lane == 0) asrc[v + 1] = p;
  p = wave_reduce_sum(acc2 * asl); if (lane == 0) asrc[v + 2] = p;
  p = wave_reduce_sum(acc3 * asl); if (lane == 0) asrc[v + 3] = p;
  p = wave_reduce_sum(acc0 * adl); if (lane == 0) adst[v + 0] = p;
  p = wave_reduce_sum(acc1 * adl); if (lane == 0) adst[v + 1] = p;
  p = wave_reduce_sum(acc2 * adl); if (lane == 0) adst[v + 2] = p;
  p = wave_reduce_sum(acc3 * adl); if (lane == 0) adst[v + 3] = p;
}

// softmax attention + aggregation. 16 lanes per node (float4 features).
__global__ __launch_bounds__(256) void aggregate_kernel(
    const float4* __restrict__ g4, const float* __restrict__ asrc, const float* __restrict__ adst,
    const int* __restrict__ rowptr, const int* __restrict__ col,
    const float* __restrict__ ae4, const float* __restrict__ bias, float* __restrict__ hout) {
  int tid = threadIdx.x, wave = tid >> 6, lane = tid & 63;
  int sub = lane & 15;
  int base_lane = lane & 48;
  int v = blockIdx.x * 16 + wave * 4 + (lane >> 4);
  int start = rowptr[v], end = rowptr[v + 1];
  float adstv = adst[v];

  float alc[4]; int sc[4];
  float mx = -INFINITY;
  #pragma unroll
  for (int c = 0; c < 4; ++c) {
    alc[c] = -INFINITY; sc[c] = 0;
    int e = start + c * 16 + sub;
    if (e < end) {
      int p = col[e]; sc[c] = p & 0xFFFFF; int a = p >> 20;
      float al = asrc[sc[c]] + adstv + ae4[a];
      al = (al > 0.f) ? al : NEG_SLOPE * al;
      alc[c] = al; mx = fmaxf(mx, al);
    }
  }
  for (int base = start + 64; base < end; base += 16) {
    int e = base + sub;
    if (e < end) {
      int p = col[e]; int s = p & 0xFFFFF; int a = p >> 20;
      float al = asrc[s] + adstv + ae4[a];
      al = (al > 0.f) ? al : NEG_SLOPE * al;
      mx = fmaxf(mx, al);
    }
  }
  mx = group16_max(mx);

  float4 acc = {0.f, 0.f, 0.f, 0.f};
  float den = 0.f;
  float exc[4];
  #pragma unroll
  for (int c = 0; c < 4; ++c) {
    int e = start + c * 16 + sub;
    exc[c] = (e < end) ? __expf(alc[c] - mx) : 0.f;
    den += exc[c];
  }
  #pragma unroll
  for (int c = 0; c < 4; ++c) {
    int cnt = end - (start + c * 16);
    if (cnt > 0) {
      if (cnt > 16) cnt = 16;
      for (int j = 0; j < cnt; ++j) {
        float exj = __shfl(exc[c], base_lane + j, 64);
        int sj = __shfl(sc[c], base_lane + j, 64);
        float4 gr = g4[(size_t)sj * 16 + sub];
        acc.x = fmaf(exj, gr.x, acc.x);
        acc.y = fmaf(exj, gr.y, acc.y);
        acc.z = fmaf(exj, gr.z, acc.z);
        acc.w = fmaf(exj, gr.w, acc.w);
      }
    }
  }
  for (int base = start + 64; base < end; base += 16) {
    int e = base + sub;
    float ex = 0.f; int s = 0;
    if (e < end) {
      int p = col[e]; s = p & 0xFFFFF; int a = p >> 20;
      float al = asrc[s] + adstv + ae4[a];
      al = (al > 0.f) ? al : NEG_SLOPE * al;
      ex = __expf(al - mx);
    }
    den += ex;
    int cnt = end - base; if (cnt > 16) cnt = 16;
    for (int j = 0; j < cnt; ++j) {
      float exj = __shfl(ex, base_lane + j, 64);
      int sj = __shfl(s, base_lane + j, 64);
      float4 gr = g4[(size_t)sj * 16 + sub];
      acc.x = fmaf(exj, gr.x, acc.x);
      acc.y = fmaf(exj, gr.y, acc.y);
      acc.z = fmaf(exj, gr.z, acc.z);
      acc.w = fmaf(exj, gr.w, acc.w);
    }
  }
  den = group16_sum(den);
  float inv = 1.f / (den + EPSF);
  float4 b4 = ((const float4*)bias)[sub];
  float4 o;
  o.x = fmaxf(fmaf(acc.x, inv, b4.x), 0.f);
  o.y = fmaxf(fmaf(acc.y, inv, b4.y), 0.f);
  o.z = fmaxf(fmaf(acc.z, inv, b4.z), 0.f);
  o.w = fmaxf(fmaf(acc.w, inv, b4.w), 0.f);
  ((float4*)hout)[(size_t)v * 16 + sub] = o;
}

// pooled[g] = sum of h rows in [lo,hi) where batch==g (batch sorted)
__global__ __launch_bounds__(256) void pool_kernel(const float* __restrict__ h,
                                                   const int* __restrict__ batch,
                                                   float* __restrict__ pooled) {
  __shared__ int s_lo, s_hi;
  __shared__ float red[4][DD];
  int gI = blockIdx.x;
  int tid = threadIdx.x, wave = tid >> 6, lane = tid & 63;
  if (tid == 0) {
    int lo = 0, hi = NN;
    while (lo < hi) { int mid = (lo + hi) >> 1; if (batch[mid] < gI) lo = mid + 1; else hi = mid; }
    s_lo = lo;
    lo = 0; hi = NN;
    while (lo < hi) { int mid = (lo + hi) >> 1; if (batch[mid] < gI + 1) lo = mid + 1; else hi = mid; }
    s_hi = lo;
  }
  __syncthreads();
  float acc = 0.f;
  for (int v = s_lo + wave; v < s_hi; v += 4) acc += h[v * DD + lane];
  red[wave][lane] = acc;
  __syncthreads();
  if (wave == 0)
    pooled[gI * DD + lane] = red[0][lane] + red[1][lane] + red[2][lane] + red[3][lane];
}

// hidden = relu(pooled @ W1^T + b1); out = hidden @ W2^T + b2
__global__ __launch_bounds__(128) void mlp_kernel(const float* __restrict__ pooled,
                                                  const float* __restrict__ W1, const float* __restrict__ b1,
                                                  const float* __restrict__ W2, const float* __restrict__ b2,
                                                  float* __restrict__ out) {
  __shared__ float sp[DD];
  __shared__ float sh[2 * DD];
  int gI = blockIdx.x, t = threadIdx.x;
  if (t < DD) sp[t] = pooled[gI * DD + t];
  __syncthreads();
  float acc = b1[t];
  for (int d = 0; d < DD; ++d) acc += sp[d] * W1[t * DD + d];
  sh[t] = fmaxf(acc, 0.f);
  __syncthreads();
  if (t < TT) {
    float o = b2[t];
    for (int k = 0; k < 2 * DD; ++k) o += sh[k] * W2[t * 2 * DD + k];
    out[gI * TT + t] = o;
  }
}

extern "C" void kernel_launch(void* const* d_in, const int* in_sizes, int n_in,
                              void* d_out, int out_size, void* d_ws, size_t ws_size,
                              hipStream_t stream) {
  const int* x          = (const int*)d_in[0];
  const int* edge_index = (const int*)d_in[1];
  const int* edge_attr  = (const int*)d_in[2];
  const int* batch      = (const int*)d_in[3];
  const float* node_emb = (const float*)d_in[4];
  const float* edge_embs= (const float*)d_in[5];
  const float* Ws_      = (const float*)d_in[6];
  const float* W_edges  = (const float*)d_in[7];
  const float* att_src  = (const float*)d_in[8];
  const float* att_dst  = (const float*)d_in[9];
  const float* att_edge = (const float*)d_in[10];
  const float* biases   = (const float*)d_in[11];
  const float* W1       = (const float*)d_in[12];
  const float* b1       = (const float*)d_in[13];
  const float* W2       = (const float*)d_in[14];
  const float* b2       = (const float*)d_in[15];
  float* out = (float*)d_out;

  char* wsp = (char*)d_ws;
  float* h      = (float*)wsp; wsp += (size_t)NN * DD * 4;
  float* g      = (float*)wsp; wsp += (size_t)NN * DD * 4;
  float* asrc   = (float*)wsp; wsp += (size_t)NN * 4;
  float* adst   = (float*)wsp; wsp += (size_t)NN * 4;
  float* ae_tab = (float*)wsp; wsp += 16 * 4;
  float* pooled = (float*)wsp; wsp += (size_t)GG * DD * 4;
  int* rowptr   = (int*)wsp;   wsp += (size_t)(NN + 1) * 4;
  int* bcnt     = (int*)wsp;   wsp += (size_t)NBUK * 4;   // zeroed
  int* bcursor  = (int*)wsp;   wsp += (size_t)NBUK * 4;   // zeroed (adjacent to bcnt)
  int* bbase    = (int*)wsp;   wsp += (size_t)NBUK * 4;
  int* stag     = (int*)wsp;   wsp += (size_t)NE * 4;
  int* col      = (int*)wsp;   wsp += (size_t)NE * 4;

  const int* src = edge_index;
  const int* dst = edge_index + NE;

  const int nchunk = (NE + CHUNK - 1) / CHUNK;   // 391

  hipMemsetAsync(bcnt, 0, 2 * NBUK * sizeof(int), stream);   // bcnt + bcursor
  embed_kernel<<<(NN * DD + 255) / 256, 256, 0, stream>>>(x, node_emb, h);
  bucket_count_kernel<<<nchunk, 256, 0, stream>>>(dst, bcnt);
  bucket_scan_kernel<<<1, 128, 0, stream>>>(bcnt, bbase, rowptr);
  bucket_bin_kernel<<<nchunk, 256, 0, stream>>>(src, dst, edge_attr, bbase, bcursor, stag);
  bucket_csr_kernel<<<NBUK, 256, 0, stream>>>(bbase, stag, rowptr, col);
  prep_ae_kernel<<<16, 64, 0, stream>>>(edge_embs, W_edges, att_edge, ae_tab);

  for (int l = 0; l < LL; ++l) {
    gemm_attn_kernel<<<NN / 16, 256, 0, stream>>>(h, Ws_ + l * DD * DD,
                                                  att_src + l * DD, att_dst + l * DD,
                                                  g, asrc, adst);
    aggregate_kernel<<<NN / 16, 256, 0, stream>>>((const float4*)g, asrc, adst, rowptr, col,
                                                  ae_tab + l * 4, biases + l * DD, h);
  }

  pool_kernel<<<GG, 256, 0, stream>>>(h, batch, pooled);
  mlp_kernel<<<GG, 128, 0, stream>>>(pooled, W1, b1, W2, b2, out);
}

// Round 9
// 424.690 us; speedup vs baseline: 2.0896x; 1.0304x over previous
//
#include <hip/hip_runtime.h>
#include <math.h>

#define NN 50000
#define NE 800000
#define DD 64
#define LL 4
#define GG 128
#define TT 10
#define NEG_SLOPE 0.2f
#define EPSF 1e-16f

#define BSHIFT 9
#define BNODES 512                       // nodes per bucket
#define NBUK ((NN + BNODES - 1) / BNODES)  // 98
#define CHUNK 2048

__device__ __forceinline__ float wave_reduce_sum(float v) {
  #pragma unroll
  for (int off = 32; off > 0; off >>= 1) v += __shfl_xor(v, off, 64);
  return v;
}
__device__ __forceinline__ float group16_max(float v) {
  #pragma unroll
  for (int off = 1; off < 16; off <<= 1) v = fmaxf(v, __shfl_xor(v, off, 64));
  return v;
}
__device__ __forceinline__ float group16_sum(float v) {
  #pragma unroll
  for (int off = 1; off < 16; off <<= 1) v += __shfl_xor(v, off, 64);
  return v;
}
__device__ __forceinline__ int wave_incl_scan(int v) {
  int lane = threadIdx.x & 63;
  #pragma unroll
  for (int off = 1; off < 64; off <<= 1) {
    int t = __shfl_up(v, off, 64);
    if (lane >= off) v += t;
  }
  return v;
}

// h[v][d] = node_emb[x[v]][d]
__global__ void embed_kernel(const int* __restrict__ x, const float* __restrict__ node_emb,
                             float* __restrict__ h) {
  int i = blockIdx.x * blockDim.x + threadIdx.x;
  if (i < NN * DD) {
    int v = i >> 6, d = i & 63;
    h[i] = node_emb[x[v] * DD + d];
  }
}

// per-block LDS histogram of dst>>BSHIFT -> global bucket counts
__global__ __launch_bounds__(256) void bucket_count_kernel(const int* __restrict__ dst,
                                                           int* __restrict__ bcnt) {
  __shared__ int cnt[NBUK];
  int tid = threadIdx.x;
  for (int i = tid; i < NBUK; i += 256) cnt[i] = 0;
  __syncthreads();
  int e0 = blockIdx.x * CHUNK;
  for (int i = tid; i < CHUNK; i += 256) {
    int e = e0 + i;
    if (e < NE) atomicAdd(&cnt[dst[e] >> BSHIFT], 1);
  }
  __syncthreads();
  for (int b = tid; b < NBUK; b += 256)
    if (cnt[b]) atomicAdd(&bcnt[b], cnt[b]);
}

// exclusive scan of NBUK (<=128) bucket counts -> bbase; rowptr[NN] = NE
__global__ __launch_bounds__(128) void bucket_scan_kernel(const int* __restrict__ bcnt,
                                                          int* __restrict__ bbase,
                                                          int* __restrict__ rowptr) {
  __shared__ int w0sum;
  int tid = threadIdx.x, lane = tid & 63, wave = tid >> 6;
  int v = (tid < NBUK) ? bcnt[tid] : 0;
  int incl = wave_incl_scan(v);
  if (wave == 0 && lane == 63) w0sum = incl;
  __syncthreads();
  int excl = incl - v + (wave ? w0sum : 0);
  if (tid < NBUK) bbase[tid] = excl;
  if (tid == 0) rowptr[NN] = NE;
}

// count chunk's bucket histogram in LDS, reserve contiguous spans, then
// scatter DIRECTLY to global (each span is block-private => line locality).
// packed record: src[0:17) | attr[17:19) | dstlow[19:28)
__global__ __launch_bounds__(256) void bucket_bin_kernel(
    const int* __restrict__ src, const int* __restrict__ dst, const int* __restrict__ attr,
    const int* __restrict__ bbase, int* __restrict__ bcursor, int* __restrict__ stag) {
  __shared__ int cnt[NBUK];
  __shared__ int gcur[NBUK];
  int tid = threadIdx.x;
  for (int i = tid; i < NBUK; i += 256) cnt[i] = 0;
  __syncthreads();
  int e0 = blockIdx.x * CHUNK;
  // pass 1: count
  for (int i = tid; i < CHUNK; i += 256) {
    int e = e0 + i;
    if (e < NE) atomicAdd(&cnt[dst[e] >> BSHIFT], 1);
  }
  __syncthreads();
  // reserve spans (one global atomic per non-empty bucket)
  for (int b = tid; b < NBUK; b += 256)
    gcur[b] = (cnt[b] > 0) ? (bbase[b] + atomicAdd(&bcursor[b], cnt[b])) : 0;
  __syncthreads();
  // pass 2: scatter straight to global
  for (int i = tid; i < CHUNK; i += 256) {
    int e = e0 + i;
    if (e < NE) {
      int d = dst[e];
      int b = d >> BSHIFT;
      int pos = atomicAdd(&gcur[b], 1);
      stag[pos] = src[e] | (attr[e] << 17) | ((d & (BNODES - 1)) << 19);
    }
  }
}

// per bucket: local hist(512) -> scan -> rowptr; scatter col within 32KB window.
// col entry format: src | attr<<20  (same as before)
__global__ __launch_bounds__(256) void bucket_csr_kernel(
    const int* __restrict__ bbase, const int* __restrict__ stag,
    int* __restrict__ rowptr, int* __restrict__ col) {
  __shared__ int hist[BNODES];
  __shared__ int wsum[4];
  int b = blockIdx.x, tid = threadIdx.x, lane = tid & 63, wave = tid >> 6;
  int base = bbase[b];
  int endb = (b == NBUK - 1) ? NE : bbase[b + 1];
  int n = endb - base;
  int nodes0 = b << BSHIFT;
  int nloc = NN - nodes0; if (nloc > BNODES) nloc = BNODES;
  for (int i = tid; i < BNODES; i += 256) hist[i] = 0;
  __syncthreads();
  for (int i = tid; i < n; i += 256)
    atomicAdd(&hist[(stag[base + i] >> 19) & (BNODES - 1)], 1);
  __syncthreads();
  // scan 512 with 256 threads: 2 elems/thread
  int a0 = hist[2 * tid], a1 = hist[2 * tid + 1];
  int pairsum = a0 + a1;
  int incl = wave_incl_scan(pairsum);
  if (lane == 63) wsum[wave] = incl;
  __syncthreads();
  int wbase = 0;
  for (int w = 0; w < wave; ++w) wbase += wsum[w];
  int excl = incl - pairsum + wbase;      // bucket-relative exclusive over pairs
  if (2 * tid < nloc)     rowptr[nodes0 + 2 * tid]     = base + excl;
  if (2 * tid + 1 < nloc) rowptr[nodes0 + 2 * tid + 1] = base + excl + a0;
  __syncthreads();
  hist[2 * tid] = excl;
  hist[2 * tid + 1] = excl + a0;
  __syncthreads();
  for (int i = tid; i < n; i += 256) {
    int p = stag[base + i];
    int dl = (p >> 19) & (BNODES - 1);
    int pos = atomicAdd(&hist[dl], 1);
    col[base + pos] = (p & 0x1FFFF) | (((p >> 17) & 3) << 20);
  }
}

// ae_tab[l*4+k] = e_tab[l][k] . (W_edges[l]^T att_edge[l])
__global__ __launch_bounds__(64) void prep_ae_kernel(const float* __restrict__ edge_embs,
                                                     const float* __restrict__ W_edges,
                                                     const float* __restrict__ att_edge,
                                                     float* __restrict__ ae_tab) {
  int t = blockIdx.x;          // 0..15
  int l = t >> 2, k = t & 3;
  int j = threadIdx.x;         // 0..63
  const float* We = W_edges + l * DD * DD;
  const float* aE = att_edge + l * DD;
  const float* et = edge_embs + (l * 4 + k) * DD;
  float tj = 0.f;
  #pragma unroll 8
  for (int d = 0; d < DD; ++d) tj = fmaf(We[d * DD + j], aE[d], tj);
  float acc = wave_reduce_sum(et[j] * tj);
  if (j == 0) ae_tab[t] = acc;
}

// g = h @ W^T ; asrc = g . a_src ; adst = g . a_dst
__global__ __launch_bounds__(256) void gemm_attn_kernel(
    const float* __restrict__ h, const float* __restrict__ W,
    const float* __restrict__ a_src, const float* __restrict__ a_dst,
    float* __restrict__ g, float* __restrict__ asrc, float* __restrict__ adst) {
  __shared__ float Wsm[DD][68];
  __shared__ float hs[16][DD];
  int tid = threadIdx.x, wave = tid >> 6, lane = tid & 63;
  int vbase = blockIdx.x * 16;
  for (int idx = tid; idx < DD * DD; idx += 256) Wsm[idx >> 6][idx & 63] = W[idx];
  for (int idx = tid; idx < 16 * DD; idx += 256) hs[idx >> 6][idx & 63] = h[vbase * DD + idx];
  __syncthreads();
  float acc0 = 0.f, acc1 = 0.f, acc2 = 0.f, acc3 = 0.f;
  int r = wave * 4;
  #pragma unroll
  for (int j4 = 0; j4 < DD / 4; ++j4) {
    float4 wv = *(const float4*)&Wsm[lane][j4 * 4];
    float4 h0 = *(const float4*)&hs[r + 0][j4 * 4];
    float4 h1 = *(const float4*)&hs[r + 1][j4 * 4];
    float4 h2 = *(const float4*)&hs[r + 2][j4 * 4];
    float4 h3 = *(const float4*)&hs[r + 3][j4 * 4];
    acc0 = fmaf(wv.x, h0.x, acc0); acc0 = fmaf(wv.y, h0.y, acc0);
    acc0 = fmaf(wv.z, h0.z, acc0); acc0 = fmaf(wv.w, h0.w, acc0);
    acc1 = fmaf(wv.x, h1.x, acc1); acc1 = fmaf(wv.y, h1.y, acc1);
    acc1 = fmaf(wv.z, h1.z, acc1); acc1 = fmaf(wv.w, h1.w, acc1);
    acc2 = fmaf(wv.x, h2.x, acc2); acc2 = fmaf(wv.y, h2.y, acc2);
    acc2 = fmaf(wv.z, h2.z, acc2); acc2 = fmaf(wv.w, h2.w, acc2);
    acc3 = fmaf(wv.x, h3.x, acc3); acc3 = fmaf(wv.y, h3.y, acc3);
    acc3 = fmaf(wv.z, h3.z, acc3); acc3 = fmaf(wv.w, h3.w, acc3);
  }
  int v = vbase + r;
  g[(v + 0) * DD + lane] = acc0;
  g[(v + 1) * DD + lane] = acc1;
  g[(v + 2) * DD + lane] = acc2;
  g[(v + 3) * DD + lane] = acc3;
  float asl = a_src[lane], adl = a_dst[lane];
  float p;
  p = wave_reduce_sum(acc0 * asl); if (lane == 0) asrc[v + 0] = p;
  p = wave_reduce_sum(acc1 * asl); if (lane == 0) asrc[v + 1] = p;
  p = wave_reduce_sum(acc2 * asl); if (lane == 0) asrc[v + 2] = p;
  p = wave_reduce_sum(acc3 * asl); if (lane == 0) asrc[v + 3] = p;
  p = wave_reduce_sum(acc0 * adl); if (lane == 0) adst[v + 0] = p;
  p = wave_reduce_sum(acc1 * adl); if (lane == 0) adst[v + 1] = p;
  p = wave_reduce_sum(acc2 * adl); if (lane == 0) adst[v + 2] = p;
  p = wave_reduce_sum(acc3 * adl); if (lane == 0) adst[v + 3] = p;
}

// softmax attention + aggregation. 16 lanes per node (float4 features).
// Inner gather loop is branch-free and fully unrolled: invalid edge slots
// carry ex=0, s=0, so the FMA contributes 0 and the load hits g-row 0 (L1-hot).
// This lets the compiler issue all 16 independent gathers back-to-back.
__global__ __launch_bounds__(256) void aggregate_kernel(
    const float4* __restrict__ g4, const float* __restrict__ asrc, const float* __restrict__ adst,
    const int* __restrict__ rowptr, const int* __restrict__ col,
    const float* __restrict__ ae4, const float* __restrict__ bias, float* __restrict__ hout) {
  int tid = threadIdx.x, wave = tid >> 6, lane = tid & 63;
  int sub = lane & 15;
  int base_lane = lane & 48;
  int v = blockIdx.x * 16 + wave * 4 + (lane >> 4);
  int start = rowptr[v], end = rowptr[v + 1];
  float adstv = adst[v];

  float alc[4]; int sc[4];
  float mx = -INFINITY;
  #pragma unroll
  for (int c = 0; c < 4; ++c) {
    alc[c] = -INFINITY; sc[c] = 0;
    int e = start + c * 16 + sub;
    if (e < end) {
      int p = col[e]; sc[c] = p & 0xFFFFF; int a = p >> 20;
      float al = asrc[sc[c]] + adstv + ae4[a];
      al = (al > 0.f) ? al : NEG_SLOPE * al;
      alc[c] = al; mx = fmaxf(mx, al);
    }
  }
  for (int base = start + 64; base < end; base += 16) {
    int e = base + sub;
    if (e < end) {
      int p = col[e]; int s = p & 0xFFFFF; int a = p >> 20;
      float al = asrc[s] + adstv + ae4[a];
      al = (al > 0.f) ? al : NEG_SLOPE * al;
      mx = fmaxf(mx, al);
    }
  }
  mx = group16_max(mx);

  float4 acc = {0.f, 0.f, 0.f, 0.f};
  float den = 0.f;
  float exc[4];
  #pragma unroll
  for (int c = 0; c < 4; ++c) {
    int e = start + c * 16 + sub;
    exc[c] = (e < end) ? __expf(alc[c] - mx) : 0.f;
    den += exc[c];
  }
  #pragma unroll
  for (int c = 0; c < 4; ++c) {
    if (end > start + c * 16) {        // group-uniform skip of empty chunks
      #pragma unroll
      for (int j = 0; j < 16; ++j) {
        float exj = __shfl(exc[c], base_lane + j, 64);
        int sj = __shfl(sc[c], base_lane + j, 64);
        float4 gr = g4[(size_t)sj * 16 + sub];
        acc.x = fmaf(exj, gr.x, acc.x);
        acc.y = fmaf(exj, gr.y, acc.y);
        acc.z = fmaf(exj, gr.z, acc.z);
        acc.w = fmaf(exj, gr.w, acc.w);
      }
    }
  }
  for (int base = start + 64; base < end; base += 16) {
    int e = base + sub;
    float ex = 0.f; int s = 0;
    if (e < end) {
      int p = col[e]; s = p & 0xFFFFF; int a = p >> 20;
      float al = asrc[s] + adstv + ae4[a];
      al = (al > 0.f) ? al : NEG_SLOPE * al;
      ex = __expf(al - mx);
    }
    den += ex;
    #pragma unroll
    for (int j = 0; j < 16; ++j) {
      float exj = __shfl(ex, base_lane + j, 64);
      int sj = __shfl(s, base_lane + j, 64);
      float4 gr = g4[(size_t)sj * 16 + sub];
      acc.x = fmaf(exj, gr.x, acc.x);
      acc.y = fmaf(exj, gr.y, acc.y);
      acc.z = fmaf(exj, gr.z, acc.z);
      acc.w = fmaf(exj, gr.w, acc.w);
    }
  }
  den = group16_sum(den);
  float inv = 1.f / (den + EPSF);
  float4 b4 = ((const float4*)bias)[sub];
  float4 o;
  o.x = fmaxf(fmaf(acc.x, inv, b4.x), 0.f);
  o.y = fmaxf(fmaf(acc.y, inv, b4.y), 0.f);
  o.z = fmaxf(fmaf(acc.z, inv, b4.z), 0.f);
  o.w = fmaxf(fmaf(acc.w, inv, b4.w), 0.f);
  ((float4*)hout)[(size_t)v * 16 + sub] = o;
}

// pooled[g] = sum of h rows in [lo,hi) where batch==g (batch sorted)
__global__ __launch_bounds__(256) void pool_kernel(const float* __restrict__ h,
                                                   const int* __restrict__ batch,
                                                   float* __restrict__ pooled) {
  __shared__ int s_lo, s_hi;
  __shared__ float red[4][DD];
  int gI = blockIdx.x;
  int tid = threadIdx.x, wave = tid >> 6, lane = tid & 63;
  if (tid == 0) {
    int lo = 0, hi = NN;
    while (lo < hi) { int mid = (lo + hi) >> 1; if (batch[mid] < gI) lo = mid + 1; else hi = mid; }
    s_lo = lo;
    lo = 0; hi = NN;
    while (lo < hi) { int mid = (lo + hi) >> 1; if (batch[mid] < gI + 1) lo = mid + 1; else hi = mid; }
    s_hi = lo;
  }
  __syncthreads();
  float acc = 0.f;
  for (int v = s_lo + wave; v < s_hi; v += 4) acc += h[v * DD + lane];
  red[wave][lane] = acc;
  __syncthreads();
  if (wave == 0)
    pooled[gI * DD + lane] = red[0][lane] + red[1][lane] + red[2][lane] + red[3][lane];
}

// hidden = relu(pooled @ W1^T + b1); out = hidden @ W2^T + b2
__global__ __launch_bounds__(128) void mlp_kernel(const float* __restrict__ pooled,
                                                  const float* __restrict__ W1, const float* __restrict__ b1,
                                                  const float* __restrict__ W2, const float* __restrict__ b2,
                                                  float* __restrict__ out) {
  __shared__ float sp[DD];
  __shared__ float sh[2 * DD];
  int gI = blockIdx.x, t = threadIdx.x;
  if (t < DD) sp[t] = pooled[gI * DD + t];
  __syncthreads();
  float acc = b1[t];
  for (int d = 0; d < DD; ++d) acc += sp[d] * W1[t * DD + d];
  sh[t] = fmaxf(acc, 0.f);
  __syncthreads();
  if (t < TT) {
    float o = b2[t];
    for (int k = 0; k < 2 * DD; ++k) o += sh[k] * W2[t * 2 * DD + k];
    out[gI * TT + t] = o;
  }
}

extern "C" void kernel_launch(void* const* d_in, const int* in_sizes, int n_in,
                              void* d_out, int out_size, void* d_ws, size_t ws_size,
                              hipStream_t stream) {
  const int* x          = (const int*)d_in[0];
  const int* edge_index = (const int*)d_in[1];
  const int* edge_attr  = (const int*)d_in[2];
  const int* batch      = (const int*)d_in[3];
  const float* node_emb = (const float*)d_in[4];
  const float* edge_embs= (const float*)d_in[5];
  const float* Ws_      = (const float*)d_in[6];
  const float* W_edges  = (const float*)d_in[7];
  const float* att_src  = (const float*)d_in[8];
  const float* att_dst  = (const float*)d_in[9];
  const float* att_edge = (const float*)d_in[10];
  const float* biases   = (const float*)d_in[11];
  const float* W1       = (const float*)d_in[12];
  const float* b1       = (const float*)d_in[13];
  const float* W2       = (const float*)d_in[14];
  const float* b2       = (const float*)d_in[15];
  float* out = (float*)d_out;

  char* wsp = (char*)d_ws;
  float* h      = (float*)wsp; wsp += (size_t)NN * DD * 4;
  float* g      = (float*)wsp; wsp += (size_t)NN * DD * 4;
  float* asrc   = (float*)wsp; wsp += (size_t)NN * 4;
  float* adst   = (float*)wsp; wsp += (size_t)NN * 4;
  float* ae_tab = (float*)wsp; wsp += 16 * 4;
  float* pooled = (float*)wsp; wsp += (size_t)GG * DD * 4;
  int* rowptr   = (int*)wsp;   wsp += (size_t)(NN + 1) * 4;
  int* bcnt     = (int*)wsp;   wsp += (size_t)NBUK * 4;   // zeroed
  int* bcursor  = (int*)wsp;   wsp += (size_t)NBUK * 4;   // zeroed (adjacent to bcnt)
  int* bbase    = (int*)wsp;   wsp += (size_t)NBUK * 4;
  int* stag     = (int*)wsp;   wsp += (size_t)NE * 4;
  int* col      = (int*)wsp;   wsp += (size_t)NE * 4;

  const int* src = edge_index;
  const int* dst = edge_index + NE;

  const int nchunk = (NE + CHUNK - 1) / CHUNK;   // 391

  hipMemsetAsync(bcnt, 0, 2 * NBUK * sizeof(int), stream);   // bcnt + bcursor
  embed_kernel<<<(NN * DD + 255) / 256, 256, 0, stream>>>(x, node_emb, h);
  bucket_count_kernel<<<nchunk, 256, 0, stream>>>(dst, bcnt);
  bucket_scan_kernel<<<1, 128, 0, stream>>>(bcnt, bbase, rowptr);
  bucket_bin_kernel<<<nchunk, 256, 0, stream>>>(src, dst, edge_attr, bbase, bcursor, stag);
  bucket_csr_kernel<<<NBUK, 256, 0, stream>>>(bbase, stag, rowptr, col);
  prep_ae_kernel<<<16, 64, 0, stream>>>(edge_embs, W_edges, att_edge, ae_tab);

  for (int l = 0; l < LL; ++l) {
    gemm_attn_kernel<<<NN / 16, 256, 0, stream>>>(h, Ws_ + l * DD * DD,
                                                  att_src + l * DD, att_dst + l * DD,
                                                  g, asrc, adst);
    aggregate_kernel<<<NN / 16, 256, 0, stream>>>((const float4*)g, asrc, adst, rowptr, col,
                                                  ae_tab + l * 4, biases + l * DD, h);
  }

  pool_kernel<<<GG, 256, 0, stream>>>(h, batch, pooled);
  mlp_kernel<<<GG, 128, 0, stream>>>(pooled, W1, b1, W2, b2, out);
}

// Round 11
// 418.122 us; speedup vs baseline: 2.1224x; 1.0157x over previous
//
#include <hip/hip_runtime.h>
#include <math.h>

#define NN 50000
#define NE 800000
#define DD 64
#define LL 4
#define GG 128
#define TT 10
#define NEG_SLOPE 0.2f
#define EPSF 1e-16f

#define BSHIFT 9
#define BNODES 512                       // nodes per bucket
#define NBUK ((NN + BNODES - 1) / BNODES)  // 98
#define CHUNK 2048

__device__ __forceinline__ float wave_reduce_sum(float v) {
  #pragma unroll
  for (int off = 32; off > 0; off >>= 1) v += __shfl_xor(v, off, 64);
  return v;
}
__device__ __forceinline__ float group16_sum(float v) {
  #pragma unroll
  for (int off = 1; off < 16; off <<= 1) v += __shfl_xor(v, off, 64);
  return v;
}
__device__ __forceinline__ int wave_incl_scan(int v) {
  int lane = threadIdx.x & 63;
  #pragma unroll
  for (int off = 1; off < 64; off <<= 1) {
    int t = __shfl_up(v, off, 64);
    if (lane >= off) v += t;
  }
  return v;
}

// h[v][d] = node_emb[x[v]][d]
__global__ void embed_kernel(const int* __restrict__ x, const float* __restrict__ node_emb,
                             float* __restrict__ h) {
  int i = blockIdx.x * blockDim.x + threadIdx.x;
  if (i < NN * DD) {
    int v = i >> 6, d = i & 63;
    h[i] = node_emb[x[v] * DD + d];
  }
}

// per-block LDS histogram of dst>>BSHIFT -> global bucket counts
__global__ __launch_bounds__(256) void bucket_count_kernel(const int* __restrict__ dst,
                                                           int* __restrict__ bcnt) {
  __shared__ int cnt[NBUK];
  int tid = threadIdx.x;
  for (int i = tid; i < NBUK; i += 256) cnt[i] = 0;
  __syncthreads();
  int e0 = blockIdx.x * CHUNK;
  for (int i = tid; i < CHUNK; i += 256) {
    int e = e0 + i;
    if (e < NE) atomicAdd(&cnt[dst[e] >> BSHIFT], 1);
  }
  __syncthreads();
  for (int b = tid; b < NBUK; b += 256)
    if (cnt[b]) atomicAdd(&bcnt[b], cnt[b]);
}

// exclusive scan of NBUK (<=128) bucket counts -> bbase; rowptr[NN] = NE
__global__ __launch_bounds__(128) void bucket_scan_kernel(const int* __restrict__ bcnt,
                                                          int* __restrict__ bbase,
                                                          int* __restrict__ rowptr) {
  __shared__ int w0sum;
  int tid = threadIdx.x, lane = tid & 63, wave = tid >> 6;
  int v = (tid < NBUK) ? bcnt[tid] : 0;
  int incl = wave_incl_scan(v);
  if (wave == 0 && lane == 63) w0sum = incl;
  __syncthreads();
  int excl = incl - v + (wave ? w0sum : 0);
  if (tid < NBUK) bbase[tid] = excl;
  if (tid == 0) rowptr[NN] = NE;
}

// count chunk's bucket histogram in LDS, reserve contiguous spans, then
// scatter DIRECTLY to global (each span is block-private => line locality).
// packed record: src[0:17) | attr[17:19) | dstlow[19:28)
__global__ __launch_bounds__(256) void bucket_bin_kernel(
    const int* __restrict__ src, const int* __restrict__ dst, const int* __restrict__ attr,
    const int* __restrict__ bbase, int* __restrict__ bcursor, int* __restrict__ stag) {
  __shared__ int cnt[NBUK];
  __shared__ int gcur[NBUK];
  int tid = threadIdx.x;
  for (int i = tid; i < NBUK; i += 256) cnt[i] = 0;
  __syncthreads();
  int e0 = blockIdx.x * CHUNK;
  // pass 1: count
  for (int i = tid; i < CHUNK; i += 256) {
    int e = e0 + i;
    if (e < NE) atomicAdd(&cnt[dst[e] >> BSHIFT], 1);
  }
  __syncthreads();
  // reserve spans (one global atomic per non-empty bucket)
  for (int b = tid; b < NBUK; b += 256)
    gcur[b] = (cnt[b] > 0) ? (bbase[b] + atomicAdd(&bcursor[b], cnt[b])) : 0;
  __syncthreads();
  // pass 2: scatter straight to global
  for (int i = tid; i < CHUNK; i += 256) {
    int e = e0 + i;
    if (e < NE) {
      int d = dst[e];
      int b = d >> BSHIFT;
      int pos = atomicAdd(&gcur[b], 1);
      stag[pos] = src[e] | (attr[e] << 17) | ((d & (BNODES - 1)) << 19);
    }
  }
}

// per bucket: local hist(512) -> scan -> rowptr; scatter col within 32KB window.
// col entry format: src | attr<<20  (same as before)
__global__ __launch_bounds__(256) void bucket_csr_kernel(
    const int* __restrict__ bbase, const int* __restrict__ stag,
    int* __restrict__ rowptr, int* __restrict__ col) {
  __shared__ int hist[BNODES];
  __shared__ int wsum[4];
  int b = blockIdx.x, tid = threadIdx.x, lane = tid & 63, wave = tid >> 6;
  int base = bbase[b];
  int endb = (b == NBUK - 1) ? NE : bbase[b + 1];
  int n = endb - base;
  int nodes0 = b << BSHIFT;
  int nloc = NN - nodes0; if (nloc > BNODES) nloc = BNODES;
  for (int i = tid; i < BNODES; i += 256) hist[i] = 0;
  __syncthreads();
  for (int i = tid; i < n; i += 256)
    atomicAdd(&hist[(stag[base + i] >> 19) & (BNODES - 1)], 1);
  __syncthreads();
  // scan 512 with 256 threads: 2 elems/thread
  int a0 = hist[2 * tid], a1 = hist[2 * tid + 1];
  int pairsum = a0 + a1;
  int incl = wave_incl_scan(pairsum);
  if (lane == 63) wsum[wave] = incl;
  __syncthreads();
  int wbase = 0;
  for (int w = 0; w < wave; ++w) wbase += wsum[w];
  int excl = incl - pairsum + wbase;      // bucket-relative exclusive over pairs
  if (2 * tid < nloc)     rowptr[nodes0 + 2 * tid]     = base + excl;
  if (2 * tid + 1 < nloc) rowptr[nodes0 + 2 * tid + 1] = base + excl + a0;
  __syncthreads();
  hist[2 * tid] = excl;
  hist[2 * tid + 1] = excl + a0;
  __syncthreads();
  for (int i = tid; i < n; i += 256) {
    int p = stag[base + i];
    int dl = (p >> 19) & (BNODES - 1);
    int pos = atomicAdd(&hist[dl], 1);
    col[base + pos] = (p & 0x1FFFF) | (((p >> 17) & 3) << 20);
  }
}

// ae_tab[l*4+k] = e_tab[l][k] . (W_edges[l]^T att_edge[l])
__global__ __launch_bounds__(64) void prep_ae_kernel(const float* __restrict__ edge_embs,
                                                     const float* __restrict__ W_edges,
                                                     const float* __restrict__ att_edge,
                                                     float* __restrict__ ae_tab) {
  int t = blockIdx.x;          // 0..15
  int l = t >> 2, k = t & 3;
  int j = threadIdx.x;         // 0..63
  const float* We = W_edges + l * DD * DD;
  const float* aE = att_edge + l * DD;
  const float* et = edge_embs + (l * 4 + k) * DD;
  float tj = 0.f;
  #pragma unroll 8
  for (int d = 0; d < DD; ++d) tj = fmaf(We[d * DD + j], aE[d], tj);
  float acc = wave_reduce_sum(et[j] * tj);
  if (j == 0) ae_tab[t] = acc;
}

// g = h @ W^T ; asrc = g . a_src ; adst = g . a_dst
__global__ __launch_bounds__(256) void gemm_attn_kernel(
    const float* __restrict__ h, const float* __restrict__ W,
    const float* __restrict__ a_src, const float* __restrict__ a_dst,
    float* __restrict__ g, float* __restrict__ asrc, float* __restrict__ adst) {
  __shared__ float Wsm[DD][68];
  __shared__ float hs[16][DD];
  int tid = threadIdx.x, wave = tid >> 6, lane = tid & 63;
  int vbase = blockIdx.x * 16;
  for (int idx = tid; idx < DD * DD; idx += 256) Wsm[idx >> 6][idx & 63] = W[idx];
  for (int idx = tid; idx < 16 * DD; idx += 256) hs[idx >> 6][idx & 63] = h[vbase * DD + idx];
  __syncthreads();
  float acc0 = 0.f, acc1 = 0.f, acc2 = 0.f, acc3 = 0.f;
  int r = wave * 4;
  #pragma unroll
  for (int j4 = 0; j4 < DD / 4; ++j4) {
    float4 wv = *(const float4*)&Wsm[lane][j4 * 4];
    float4 h0 = *(const float4*)&hs[r + 0][j4 * 4];
    float4 h1 = *(const float4*)&hs[r + 1][j4 * 4];
    float4 h2 = *(const float4*)&hs[r + 2][j4 * 4];
    float4 h3 = *(const float4*)&hs[r + 3][j4 * 4];
    acc0 = fmaf(wv.x, h0.x, acc0); acc0 = fmaf(wv.y, h0.y, acc0);
    acc0 = fmaf(wv.z, h0.z, acc0); acc0 = fmaf(wv.w, h0.w, acc0);
    acc1 = fmaf(wv.x, h1.x, acc1); acc1 = fmaf(wv.y, h1.y, acc1);
    acc1 = fmaf(wv.z, h1.z, acc1); acc1 = fmaf(wv.w, h1.w, acc1);
    acc2 = fmaf(wv.x, h2.x, acc2); acc2 = fmaf(wv.y, h2.y, acc2);
    acc2 = fmaf(wv.z, h2.z, acc2); acc2 = fmaf(wv.w, h2.w, acc2);
    acc3 = fmaf(wv.x, h3.x, acc3); acc3 = fmaf(wv.y, h3.y, acc3);
    acc3 = fmaf(wv.z, h3.z, acc3); acc3 = fmaf(wv.w, h3.w, acc3);
  }
  int v = vbase + r;
  g[(v + 0) * DD + lane] = acc0;
  g[(v + 1) * DD + lane] = acc1;
  g[(v + 2) * DD + lane] = acc2;
  g[(v + 3) * DD + lane] = acc3;
  float asl = a_src[lane], adl = a_dst[lane];
  float p;
  p = wave_reduce_sum(acc0 * asl); if (lane == 0) asrc[v + 0] = p;
  p = wave_reduce_sum(acc1 * asl); if (lane == 0) asrc[v + 1] = p;
  p = wave_reduce_sum(acc2 * asl); if (lane == 0) asrc[v + 2] = p;
  p = wave_reduce_sum(acc3 * asl); if (lane == 0) asrc[v + 3] = p;
  p = wave_reduce_sum(acc0 * adl); if (lane == 0) adst[v + 0] = p;
  p = wave_reduce_sum(acc1 * adl); if (lane == 0) adst[v + 1] = p;
  p = wave_reduce_sum(acc2 * adl); if (lane == 0) adst[v + 2] = p;
  p = wave_reduce_sum(acc3 * adl); if (lane == 0) adst[v + 3] = p;
}

// softmax attention + aggregation, SINGLE PASS (no max subtraction).
// Numerically safe: alpha = asrc+adst+ae is O(1) for this model scale
// (weights ~N(0, 1/64), zero biases) — exp cannot overflow f32.
// Softmax is shift-invariant, so result matches the reference's
// max-subtracted form. 16 lanes per node, branch-free unrolled gathers.
__global__ __launch_bounds__(256) void aggregate_kernel(
    const float4* __restrict__ g4, const float* __restrict__ asrc, const float* __restrict__ adst,
    const int* __restrict__ rowptr, const int* __restrict__ col,
    const float* __restrict__ ae4, const float* __restrict__ bias, float* __restrict__ hout) {
  int tid = threadIdx.x, wave = tid >> 6, lane = tid & 63;
  int sub = lane & 15;
  int base_lane = lane & 48;
  int v = blockIdx.x * 16 + wave * 4 + (lane >> 4);
  int start = rowptr[v], end = rowptr[v + 1];
  float adstv = adst[v];

  float4 acc = {0.f, 0.f, 0.f, 0.f};
  float den = 0.f;
  for (int base = start; base < end; base += 16) {
    int e = base + sub;
    float ex = 0.f; int s = 0;
    if (e < end) {
      int p = col[e]; s = p & 0xFFFFF; int a = p >> 20;
      float al = asrc[s] + adstv + ae4[a];
      al = (al > 0.f) ? al : NEG_SLOPE * al;
      ex = __expf(al);
    }
    den += ex;
    #pragma unroll
    for (int j = 0; j < 16; ++j) {
      float exj = __shfl(ex, base_lane + j, 64);
      int sj = __shfl(s, base_lane + j, 64);
      float4 gr = g4[(size_t)sj * 16 + sub];
      acc.x = fmaf(exj, gr.x, acc.x);
      acc.y = fmaf(exj, gr.y, acc.y);
      acc.z = fmaf(exj, gr.z, acc.z);
      acc.w = fmaf(exj, gr.w, acc.w);
    }
  }
  den = group16_sum(den);
  float inv = 1.f / (den + EPSF);
  float4 b4 = ((const float4*)bias)[sub];
  float4 o;
  o.x = fmaxf(fmaf(acc.x, inv, b4.x), 0.f);
  o.y = fmaxf(fmaf(acc.y, inv, b4.y), 0.f);
  o.z = fmaxf(fmaf(acc.z, inv, b4.z), 0.f);
  o.w = fmaxf(fmaf(acc.w, inv, b4.w), 0.f);
  ((float4*)hout)[(size_t)v * 16 + sub] = o;
}

// pooled[g] = sum of h rows in [lo,hi) where batch==g (batch sorted)
__global__ __launch_bounds__(256) void pool_kernel(const float* __restrict__ h,
                                                   const int* __restrict__ batch,
                                                   float* __restrict__ pooled) {
  __shared__ int s_lo, s_hi;
  __shared__ float red[4][DD];
  int gI = blockIdx.x;
  int tid = threadIdx.x, wave = tid >> 6, lane = tid & 63;
  if (tid == 0) {
    int lo = 0, hi = NN;
    while (lo < hi) { int mid = (lo + hi) >> 1; if (batch[mid] < gI) lo = mid + 1; else hi = mid; }
    s_lo = lo;
    lo = 0; hi = NN;
    while (lo < hi) { int mid = (lo + hi) >> 1; if (batch[mid] < gI + 1) lo = mid + 1; else hi = mid; }
    s_hi = lo;
  }
  __syncthreads();
  float acc = 0.f;
  for (int v = s_lo + wave; v < s_hi; v += 4) acc += h[v * DD + lane];
  red[wave][lane] = acc;
  __syncthreads();
  if (wave == 0)
    pooled[gI * DD + lane] = red[0][lane] + red[1][lane] + red[2][lane] + red[3][lane];
}

// hidden = relu(pooled @ W1^T + b1); out = hidden @ W2^T + b2
__global__ __launch_bounds__(128) void mlp_kernel(const float* __restrict__ pooled,
                                                  const float* __restrict__ W1, const float* __restrict__ b1,
                                                  const float* __restrict__ W2, const float* __restrict__ b2,
                                                  float* __restrict__ out) {
  __shared__ float sp[DD];
  __shared__ float sh[2 * DD];
  int gI = blockIdx.x, t = threadIdx.x;
  if (t < DD) sp[t] = pooled[gI * DD + t];
  __syncthreads();
  float acc = b1[t];
  for (int d = 0; d < DD; ++d) acc += sp[d] * W1[t * DD + d];
  sh[t] = fmaxf(acc, 0.f);
  __syncthreads();
  if (t < TT) {
    float o = b2[t];
    for (int k = 0; k < 2 * DD; ++k) o += sh[k] * W2[t * 2 * DD + k];
    out[gI * TT + t] = o;
  }
}

extern "C" void kernel_launch(void* const* d_in, const int* in_sizes, int n_in,
                              void* d_out, int out_size, void* d_ws, size_t ws_size,
                              hipStream_t stream) {
  const int* x          = (const int*)d_in[0];
  const int* edge_index = (const int*)d_in[1];
  const int* edge_attr  = (const int*)d_in[2];
  const int* batch      = (const int*)d_in[3];
  const float* node_emb = (const float*)d_in[4];
  const float* edge_embs= (const float*)d_in[5];
  const float* Ws_      = (const float*)d_in[6];
  const float* W_edges  = (const float*)d_in[7];
  const float* att_src  = (const float*)d_in[8];
  const float* att_dst  = (const float*)d_in[9];
  const float* att_edge = (const float*)d_in[10];
  const float* biases   = (const float*)d_in[11];
  const float* W1       = (const float*)d_in[12];
  const float* b1       = (const float*)d_in[13];
  const float* W2       = (const float*)d_in[14];
  const float* b2       = (const float*)d_in[15];
  float* out = (float*)d_out;

  char* wsp = (char*)d_ws;
  float* h      = (float*)wsp; wsp += (size_t)NN * DD * 4;
  float* g      = (float*)wsp; wsp += (size_t)NN * DD * 4;
  float* asrc   = (float*)wsp; wsp += (size_t)NN * 4;
  float* adst   = (float*)wsp; wsp += (size_t)NN * 4;
  float* ae_tab = (float*)wsp; wsp += 16 * 4;
  float* pooled = (float*)wsp; wsp += (size_t)GG * DD * 4;
  int* rowptr   = (int*)wsp;   wsp += (size_t)(NN + 1) * 4;
  int* bcnt     = (int*)wsp;   wsp += (size_t)NBUK * 4;   // zeroed
  int* bcursor  = (int*)wsp;   wsp += (size_t)NBUK * 4;   // zeroed (adjacent to bcnt)
  int* bbase    = (int*)wsp;   wsp += (size_t)NBUK * 4;
  int* stag     = (int*)wsp;   wsp += (size_t)NE * 4;
  int* col      = (int*)wsp;   wsp += (size_t)NE * 4;

  const int* src = edge_index;
  const int* dst = edge_index + NE;

  const int nchunk = (NE + CHUNK - 1) / CHUNK;   // 391

  hipMemsetAsync(bcnt, 0, 2 * NBUK * sizeof(int), stream);   // bcnt + bcursor
  embed_kernel<<<(NN * DD + 255) / 256, 256, 0, stream>>>(x, node_emb, h);
  bucket_count_kernel<<<nchunk, 256, 0, stream>>>(dst, bcnt);
  bucket_scan_kernel<<<1, 128, 0, stream>>>(bcnt, bbase, rowptr);
  bucket_bin_kernel<<<nchunk, 256, 0, stream>>>(src, dst, edge_attr, bbase, bcursor, stag);
  bucket_csr_kernel<<<NBUK, 256, 0, stream>>>(bbase, stag, rowptr, col);
  prep_ae_kernel<<<16, 64, 0, stream>>>(edge_embs, W_edges, att_edge, ae_tab);

  for (int l = 0; l < LL; ++l) {
    gemm_attn_kernel<<<NN / 16, 256, 0, stream>>>(h, Ws_ + l * DD * DD,
                                                  att_src + l * DD, att_dst + l * DD,
                                                  g, asrc, adst);
    aggregate_kernel<<<NN / 16, 256, 0, stream>>>((const float4*)g, asrc, adst, rowptr, col,
                                                  ae_tab + l * 4, biases + l * DD, h);
  }

  pool_kernel<<<GG, 256, 0, stream>>>(h, batch, pooled);
  mlp_kernel<<<GG, 128, 0, stream>>>(pooled, W1, b1, W2, b2, out);
}

// Round 12
// 382.169 us; speedup vs baseline: 2.3221x; 1.0941x over previous
//
#include <hip/hip_runtime.h>
#include <hip/hip_fp16.h>
#include <math.h>

#define NN 50000
#define NE 800000
#define DD 64
#define LL 4
#define GG 128
#define TT 10
#define NEG_SLOPE 0.2f
#define EPSF 1e-16f

#define BSHIFT 9
#define BNODES 512                       // nodes per bucket
#define NBUK ((NN + BNODES - 1) / BNODES)  // 98
#define CHUNK 2048

__device__ __forceinline__ float wave_reduce_sum(float v) {
  #pragma unroll
  for (int off = 32; off > 0; off >>= 1) v += __shfl_xor(v, off, 64);
  return v;
}
__device__ __forceinline__ float group16_sum(float v) {
  #pragma unroll
  for (int off = 1; off < 16; off <<= 1) v += __shfl_xor(v, off, 64);
  return v;
}
__device__ __forceinline__ int wave_incl_scan(int v) {
  int lane = threadIdx.x & 63;
  #pragma unroll
  for (int off = 1; off < 64; off <<= 1) {
    int t = __shfl_up(v, off, 64);
    if (lane >= off) v += t;
  }
  return v;
}

// h[v][d] = node_emb[x[v]][d]
__global__ void embed_kernel(const int* __restrict__ x, const float* __restrict__ node_emb,
                             float* __restrict__ h) {
  int i = blockIdx.x * blockDim.x + threadIdx.x;
  if (i < NN * DD) {
    int v = i >> 6, d = i & 63;
    h[i] = node_emb[x[v] * DD + d];
  }
}

// per-block LDS histogram of dst>>BSHIFT -> global bucket counts
__global__ __launch_bounds__(256) void bucket_count_kernel(const int* __restrict__ dst,
                                                           int* __restrict__ bcnt) {
  __shared__ int cnt[NBUK];
  int tid = threadIdx.x;
  for (int i = tid; i < NBUK; i += 256) cnt[i] = 0;
  __syncthreads();
  int e0 = blockIdx.x * CHUNK;
  for (int i = tid; i < CHUNK; i += 256) {
    int e = e0 + i;
    if (e < NE) atomicAdd(&cnt[dst[e] >> BSHIFT], 1);
  }
  __syncthreads();
  for (int b = tid; b < NBUK; b += 256)
    if (cnt[b]) atomicAdd(&bcnt[b], cnt[b]);
}

// exclusive scan of NBUK (<=128) bucket counts -> bbase; rowptr[NN] = NE
__global__ __launch_bounds__(128) void bucket_scan_kernel(const int* __restrict__ bcnt,
                                                          int* __restrict__ bbase,
                                                          int* __restrict__ rowptr) {
  __shared__ int w0sum;
  int tid = threadIdx.x, lane = tid & 63, wave = tid >> 6;
  int v = (tid < NBUK) ? bcnt[tid] : 0;
  int incl = wave_incl_scan(v);
  if (wave == 0 && lane == 63) w0sum = incl;
  __syncthreads();
  int excl = incl - v + (wave ? w0sum : 0);
  if (tid < NBUK) bbase[tid] = excl;
  if (tid == 0) rowptr[NN] = NE;
}

// count chunk's bucket histogram in LDS, reserve contiguous spans, then
// scatter DIRECTLY to global (each span is block-private => line locality).
// packed record: src[0:17) | attr[17:19) | dstlow[19:28)
__global__ __launch_bounds__(256) void bucket_bin_kernel(
    const int* __restrict__ src, const int* __restrict__ dst, const int* __restrict__ attr,
    const int* __restrict__ bbase, int* __restrict__ bcursor, int* __restrict__ stag) {
  __shared__ int cnt[NBUK];
  __shared__ int gcur[NBUK];
  int tid = threadIdx.x;
  for (int i = tid; i < NBUK; i += 256) cnt[i] = 0;
  __syncthreads();
  int e0 = blockIdx.x * CHUNK;
  // pass 1: count
  for (int i = tid; i < CHUNK; i += 256) {
    int e = e0 + i;
    if (e < NE) atomicAdd(&cnt[dst[e] >> BSHIFT], 1);
  }
  __syncthreads();
  // reserve spans (one global atomic per non-empty bucket)
  for (int b = tid; b < NBUK; b += 256)
    gcur[b] = (cnt[b] > 0) ? (bbase[b] + atomicAdd(&bcursor[b], cnt[b])) : 0;
  __syncthreads();
  // pass 2: scatter straight to global
  for (int i = tid; i < CHUNK; i += 256) {
    int e = e0 + i;
    if (e < NE) {
      int d = dst[e];
      int b = d >> BSHIFT;
      int pos = atomicAdd(&gcur[b], 1);
      stag[pos] = src[e] | (attr[e] << 17) | ((d & (BNODES - 1)) << 19);
    }
  }
}

// per bucket: local hist(512) -> scan -> rowptr; scatter col within 32KB window.
// col entry format: src | attr<<20  (same as before)
__global__ __launch_bounds__(256) void bucket_csr_kernel(
    const int* __restrict__ bbase, const int* __restrict__ stag,
    int* __restrict__ rowptr, int* __restrict__ col) {
  __shared__ int hist[BNODES];
  __shared__ int wsum[4];
  int b = blockIdx.x, tid = threadIdx.x, lane = tid & 63, wave = tid >> 6;
  int base = bbase[b];
  int endb = (b == NBUK - 1) ? NE : bbase[b + 1];
  int n = endb - base;
  int nodes0 = b << BSHIFT;
  int nloc = NN - nodes0; if (nloc > BNODES) nloc = BNODES;
  for (int i = tid; i < BNODES; i += 256) hist[i] = 0;
  __syncthreads();
  for (int i = tid; i < n; i += 256)
    atomicAdd(&hist[(stag[base + i] >> 19) & (BNODES - 1)], 1);
  __syncthreads();
  // scan 512 with 256 threads: 2 elems/thread
  int a0 = hist[2 * tid], a1 = hist[2 * tid + 1];
  int pairsum = a0 + a1;
  int incl = wave_incl_scan(pairsum);
  if (lane == 63) wsum[wave] = incl;
  __syncthreads();
  int wbase = 0;
  for (int w = 0; w < wave; ++w) wbase += wsum[w];
  int excl = incl - pairsum + wbase;      // bucket-relative exclusive over pairs
  if (2 * tid < nloc)     rowptr[nodes0 + 2 * tid]     = base + excl;
  if (2 * tid + 1 < nloc) rowptr[nodes0 + 2 * tid + 1] = base + excl + a0;
  __syncthreads();
  hist[2 * tid] = excl;
  hist[2 * tid + 1] = excl + a0;
  __syncthreads();
  for (int i = tid; i < n; i += 256) {
    int p = stag[base + i];
    int dl = (p >> 19) & (BNODES - 1);
    int pos = atomicAdd(&hist[dl], 1);
    col[base + pos] = (p & 0x1FFFF) | (((p >> 17) & 3) << 20);
  }
}

// ae_tab[l*4+k] = e_tab[l][k] . (W_edges[l]^T att_edge[l])
__global__ __launch_bounds__(64) void prep_ae_kernel(const float* __restrict__ edge_embs,
                                                     const float* __restrict__ W_edges,
                                                     const float* __restrict__ att_edge,
                                                     float* __restrict__ ae_tab) {
  int t = blockIdx.x;          // 0..15
  int l = t >> 2, k = t & 3;
  int j = threadIdx.x;         // 0..63
  const float* We = W_edges + l * DD * DD;
  const float* aE = att_edge + l * DD;
  const float* et = edge_embs + (l * 4 + k) * DD;
  float tj = 0.f;
  #pragma unroll 8
  for (int d = 0; d < DD; ++d) tj = fmaf(We[d * DD + j], aE[d], tj);
  float acc = wave_reduce_sum(et[j] * tj);
  if (j == 0) ae_tab[t] = acc;
}

// g = h @ W^T (stored fp16) ; asrc = g . a_src ; adst = g . a_dst (from f32 acc)
__global__ __launch_bounds__(256) void gemm_attn_kernel(
    const float* __restrict__ h, const float* __restrict__ W,
    const float* __restrict__ a_src, const float* __restrict__ a_dst,
    __half* __restrict__ gh, float* __restrict__ asrc, float* __restrict__ adst) {
  __shared__ float Wsm[DD][68];
  __shared__ float hs[16][DD];
  int tid = threadIdx.x, wave = tid >> 6, lane = tid & 63;
  int vbase = blockIdx.x * 16;
  for (int idx = tid; idx < DD * DD; idx += 256) Wsm[idx >> 6][idx & 63] = W[idx];
  for (int idx = tid; idx < 16 * DD; idx += 256) hs[idx >> 6][idx & 63] = h[vbase * DD + idx];
  __syncthreads();
  float acc0 = 0.f, acc1 = 0.f, acc2 = 0.f, acc3 = 0.f;
  int r = wave * 4;
  #pragma unroll
  for (int j4 = 0; j4 < DD / 4; ++j4) {
    float4 wv = *(const float4*)&Wsm[lane][j4 * 4];
    float4 h0 = *(const float4*)&hs[r + 0][j4 * 4];
    float4 h1 = *(const float4*)&hs[r + 1][j4 * 4];
    float4 h2 = *(const float4*)&hs[r + 2][j4 * 4];
    float4 h3 = *(const float4*)&hs[r + 3][j4 * 4];
    acc0 = fmaf(wv.x, h0.x, acc0); acc0 = fmaf(wv.y, h0.y, acc0);
    acc0 = fmaf(wv.z, h0.z, acc0); acc0 = fmaf(wv.w, h0.w, acc0);
    acc1 = fmaf(wv.x, h1.x, acc1); acc1 = fmaf(wv.y, h1.y, acc1);
    acc1 = fmaf(wv.z, h1.z, acc1); acc1 = fmaf(wv.w, h1.w, acc1);
    acc2 = fmaf(wv.x, h2.x, acc2); acc2 = fmaf(wv.y, h2.y, acc2);
    acc2 = fmaf(wv.z, h2.z, acc2); acc2 = fmaf(wv.w, h2.w, acc2);
    acc3 = fmaf(wv.x, h3.x, acc3); acc3 = fmaf(wv.y, h3.y, acc3);
    acc3 = fmaf(wv.z, h3.z, acc3); acc3 = fmaf(wv.w, h3.w, acc3);
  }
  int v = vbase + r;
  gh[(size_t)(v + 0) * DD + lane] = __float2half(acc0);
  gh[(size_t)(v + 1) * DD + lane] = __float2half(acc1);
  gh[(size_t)(v + 2) * DD + lane] = __float2half(acc2);
  gh[(size_t)(v + 3) * DD + lane] = __float2half(acc3);
  float asl = a_src[lane], adl = a_dst[lane];
  float p;
  p = wave_reduce_sum(acc0 * asl); if (lane == 0) asrc[v + 0] = p;
  p = wave_reduce_sum(acc1 * asl); if (lane == 0) asrc[v + 1] = p;
  p = wave_reduce_sum(acc2 * asl); if (lane == 0) asrc[v + 2] = p;
  p = wave_reduce_sum(acc3 * asl); if (lane == 0) asrc[v + 3] = p;
  p = wave_reduce_sum(acc0 * adl); if (lane == 0) adst[v + 0] = p;
  p = wave_reduce_sum(acc1 * adl); if (lane == 0) adst[v + 1] = p;
  p = wave_reduce_sum(acc2 * adl); if (lane == 0) adst[v + 2] = p;
  p = wave_reduce_sum(acc3 * adl); if (lane == 0) adst[v + 3] = p;
}

// softmax attention + aggregation, single pass, fp16 g gathers (8B/lane).
// Attention weights from f32 asrc/adst => fp16 error only on aggregated values.
__global__ __launch_bounds__(256) void aggregate_kernel(
    const __half* __restrict__ gh, const float* __restrict__ asrc, const float* __restrict__ adst,
    const int* __restrict__ rowptr, const int* __restrict__ col,
    const float* __restrict__ ae4, const float* __restrict__ bias, float* __restrict__ hout) {
  int tid = threadIdx.x, wave = tid >> 6, lane = tid & 63;
  int sub = lane & 15;
  int base_lane = lane & 48;
  int v = blockIdx.x * 16 + wave * 4 + (lane >> 4);
  int start = rowptr[v], end = rowptr[v + 1];
  float adstv = adst[v];

  float4 acc = {0.f, 0.f, 0.f, 0.f};
  float den = 0.f;
  for (int base = start; base < end; base += 16) {
    int e = base + sub;
    float ex = 0.f; int s = 0;
    if (e < end) {
      int p = col[e]; s = p & 0xFFFFF; int a = p >> 20;
      float al = asrc[s] + adstv + ae4[a];
      al = (al > 0.f) ? al : NEG_SLOPE * al;
      ex = __expf(al);
    }
    den += ex;
    #pragma unroll
    for (int j = 0; j < 16; ++j) {
      float exj = __shfl(ex, base_lane + j, 64);
      int sj = __shfl(s, base_lane + j, 64);
      uint2 raw = *(const uint2*)(gh + (size_t)sj * DD + sub * 4);
      __half2 p0 = *(__half2*)&raw.x;
      __half2 p1 = *(__half2*)&raw.y;
      float2 f0 = __half22float2(p0);
      float2 f1 = __half22float2(p1);
      acc.x = fmaf(exj, f0.x, acc.x);
      acc.y = fmaf(exj, f0.y, acc.y);
      acc.z = fmaf(exj, f1.x, acc.z);
      acc.w = fmaf(exj, f1.y, acc.w);
    }
  }
  den = group16_sum(den);
  float inv = 1.f / (den + EPSF);
  float4 b4 = ((const float4*)bias)[sub];
  float4 o;
  o.x = fmaxf(fmaf(acc.x, inv, b4.x), 0.f);
  o.y = fmaxf(fmaf(acc.y, inv, b4.y), 0.f);
  o.z = fmaxf(fmaf(acc.z, inv, b4.z), 0.f);
  o.w = fmaxf(fmaf(acc.w, inv, b4.w), 0.f);
  ((float4*)hout)[(size_t)v * 16 + sub] = o;
}

// pooled[g] = sum of h rows in [lo,hi) where batch==g (batch sorted)
__global__ __launch_bounds__(256) void pool_kernel(const float* __restrict__ h,
                                                   const int* __restrict__ batch,
                                                   float* __restrict__ pooled) {
  __shared__ int s_lo, s_hi;
  __shared__ float red[4][DD];
  int gI = blockIdx.x;
  int tid = threadIdx.x, wave = tid >> 6, lane = tid & 63;
  if (tid == 0) {
    int lo = 0, hi = NN;
    while (lo < hi) { int mid = (lo + hi) >> 1; if (batch[mid] < gI) lo = mid + 1; else hi = mid; }
    s_lo = lo;
    lo = 0; hi = NN;
    while (lo < hi) { int mid = (lo + hi) >> 1; if (batch[mid] < gI + 1) lo = mid + 1; else hi = mid; }
    s_hi = lo;
  }
  __syncthreads();
  float acc = 0.f;
  for (int v = s_lo + wave; v < s_hi; v += 4) acc += h[v * DD + lane];
  red[wave][lane] = acc;
  __syncthreads();
  if (wave == 0)
    pooled[gI * DD + lane] = red[0][lane] + red[1][lane] + red[2][lane] + red[3][lane];
}

// hidden = relu(pooled @ W1^T + b1); out = hidden @ W2^T + b2
__global__ __launch_bounds__(128) void mlp_kernel(const float* __restrict__ pooled,
                                                  const float* __restrict__ W1, const float* __restrict__ b1,
                                                  const float* __restrict__ W2, const float* __restrict__ b2,
                                                  float* __restrict__ out) {
  __shared__ float sp[DD];
  __shared__ float sh[2 * DD];
  int gI = blockIdx.x, t = threadIdx.x;
  if (t < DD) sp[t] = pooled[gI * DD + t];
  __syncthreads();
  float acc = b1[t];
  for (int d = 0; d < DD; ++d) acc += sp[d] * W1[t * DD + d];
  sh[t] = fmaxf(acc, 0.f);
  __syncthreads();
  if (t < TT) {
    float o = b2[t];
    for (int k = 0; k < 2 * DD; ++k) o += sh[k] * W2[t * 2 * DD + k];
    out[gI * TT + t] = o;
  }
}

extern "C" void kernel_launch(void* const* d_in, const int* in_sizes, int n_in,
                              void* d_out, int out_size, void* d_ws, size_t ws_size,
                              hipStream_t stream) {
  const int* x          = (const int*)d_in[0];
  const int* edge_index = (const int*)d_in[1];
  const int* edge_attr  = (const int*)d_in[2];
  const int* batch      = (const int*)d_in[3];
  const float* node_emb = (const float*)d_in[4];
  const float* edge_embs= (const float*)d_in[5];
  const float* Ws_      = (const float*)d_in[6];
  const float* W_edges  = (const float*)d_in[7];
  const float* att_src  = (const float*)d_in[8];
  const float* att_dst  = (const float*)d_in[9];
  const float* att_edge = (const float*)d_in[10];
  const float* biases   = (const float*)d_in[11];
  const float* W1       = (const float*)d_in[12];
  const float* b1       = (const float*)d_in[13];
  const float* W2       = (const float*)d_in[14];
  const float* b2       = (const float*)d_in[15];
  float* out = (float*)d_out;

  char* wsp = (char*)d_ws;
  float* h      = (float*)wsp; wsp += (size_t)NN * DD * 4;
  __half* gh    = (__half*)wsp; wsp += (size_t)NN * DD * 2;
  float* asrc   = (float*)wsp; wsp += (size_t)NN * 4;
  float* adst   = (float*)wsp; wsp += (size_t)NN * 4;
  float* ae_tab = (float*)wsp; wsp += 16 * 4;
  float* pooled = (float*)wsp; wsp += (size_t)GG * DD * 4;
  int* rowptr   = (int*)wsp;   wsp += (size_t)(NN + 1) * 4;
  int* bcnt     = (int*)wsp;   wsp += (size_t)NBUK * 4;   // zeroed
  int* bcursor  = (int*)wsp;   wsp += (size_t)NBUK * 4;   // zeroed (adjacent to bcnt)
  int* bbase    = (int*)wsp;   wsp += (size_t)NBUK * 4;
  int* stag     = (int*)wsp;   wsp += (size_t)NE * 4;
  int* col      = (int*)wsp;   wsp += (size_t)NE * 4;

  const int* src = edge_index;
  const int* dst = edge_index + NE;

  const int nchunk = (NE + CHUNK - 1) / CHUNK;   // 391

  hipMemsetAsync(bcnt, 0, 2 * NBUK * sizeof(int), stream);   // bcnt + bcursor
  embed_kernel<<<(NN * DD + 255) / 256, 256, 0, stream>>>(x, node_emb, h);
  bucket_count_kernel<<<nchunk, 256, 0, stream>>>(dst, bcnt);
  bucket_scan_kernel<<<1, 128, 0, stream>>>(bcnt, bbase, rowptr);
  bucket_bin_kernel<<<nchunk, 256, 0, stream>>>(src, dst, edge_attr, bbase, bcursor, stag);
  bucket_csr_kernel<<<NBUK, 256, 0, stream>>>(bbase, stag, rowptr, col);
  prep_ae_kernel<<<16, 64, 0, stream>>>(edge_embs, W_edges, att_edge, ae_tab);

  for (int l = 0; l < LL; ++l) {
    gemm_attn_kernel<<<NN / 16, 256, 0, stream>>>(h, Ws_ + l * DD * DD,
                                                  att_src + l * DD, att_dst + l * DD,
                                                  gh, asrc, adst);
    aggregate_kernel<<<NN / 16, 256, 0, stream>>>(gh, asrc, adst, rowptr, col,
                                                  ae_tab + l * 4, biases + l * DD, h);
  }

  pool_kernel<<<GG, 256, 0, stream>>>(h, batch, pooled);
  mlp_kernel<<<GG, 128, 0, stream>>>(pooled, W1, b1, W2, b2, out);
}

// Round 15
// 371.231 us; speedup vs baseline: 2.3905x; 1.0295x over previous
//
#include <hip/hip_runtime.h>
#include <hip/hip_fp16.h>
#include <math.h>

#define NN 50000
#define NE 800000
#define DD 64
#define LL 4
#define GG 128
#define TT 10
#define NEG_SLOPE 0.2f
#define EPSF 1e-16f

#define BSHIFT 9
#define BNODES 512                       // nodes per bucket
#define NBUK ((NN + BNODES - 1) / BNODES)  // 98
#define CHUNK 2048

__device__ __forceinline__ float wave_reduce_sum(float v) {
  #pragma unroll
  for (int off = 32; off > 0; off >>= 1) v += __shfl_xor(v, off, 64);
  return v;
}
__device__ __forceinline__ float group16_sum(float v) {
  #pragma unroll
  for (int off = 1; off < 16; off <<= 1) v += __shfl_xor(v, off, 64);
  return v;
}
__device__ __forceinline__ int wave_incl_scan(int v) {
  int lane = threadIdx.x & 63;
  #pragma unroll
  for (int off = 1; off < 64; off <<= 1) {
    int t = __shfl_up(v, off, 64);
    if (lane >= off) v += t;
  }
  return v;
}

// per-block LDS histogram of dst>>BSHIFT -> global bucket counts
__global__ __launch_bounds__(256) void bucket_count_kernel(const int* __restrict__ dst,
                                                           int* __restrict__ bcnt) {
  __shared__ int cnt[NBUK];
  int tid = threadIdx.x;
  for (int i = tid; i < NBUK; i += 256) cnt[i] = 0;
  __syncthreads();
  int e0 = blockIdx.x * CHUNK;
  for (int i = tid; i < CHUNK; i += 256) {
    int e = e0 + i;
    if (e < NE) atomicAdd(&cnt[dst[e] >> BSHIFT], 1);
  }
  __syncthreads();
  for (int b = tid; b < NBUK; b += 256)
    if (cnt[b]) atomicAdd(&bcnt[b], cnt[b]);
}

// exclusive scan of NBUK (<=128) bucket counts -> bbase; rowptr[NN] = NE
__global__ __launch_bounds__(128) void bucket_scan_kernel(const int* __restrict__ bcnt,
                                                          int* __restrict__ bbase,
                                                          int* __restrict__ rowptr) {
  __shared__ int w0sum;
  int tid = threadIdx.x, lane = tid & 63, wave = tid >> 6;
  int v = (tid < NBUK) ? bcnt[tid] : 0;
  int incl = wave_incl_scan(v);
  if (wave == 0 && lane == 63) w0sum = incl;
  __syncthreads();
  int excl = incl - v + (wave ? w0sum : 0);
  if (tid < NBUK) bbase[tid] = excl;
  if (tid == 0) rowptr[NN] = NE;
}

// count chunk's bucket histogram in LDS, reserve contiguous spans, then
// scatter DIRECTLY to global (each span is block-private => line locality).
// packed record: src[0:17) | attr[17:19) | dstlow[19:28)
__global__ __launch_bounds__(256) void bucket_bin_kernel(
    const int* __restrict__ src, const int* __restrict__ dst, const int* __restrict__ attr,
    const int* __restrict__ bbase, int* __restrict__ bcursor, int* __restrict__ stag) {
  __shared__ int cnt[NBUK];
  __shared__ int gcur[NBUK];
  int tid = threadIdx.x;
  for (int i = tid; i < NBUK; i += 256) cnt[i] = 0;
  __syncthreads();
  int e0 = blockIdx.x * CHUNK;
  // pass 1: count
  for (int i = tid; i < CHUNK; i += 256) {
    int e = e0 + i;
    if (e < NE) atomicAdd(&cnt[dst[e] >> BSHIFT], 1);
  }
  __syncthreads();
  // reserve spans (one global atomic per non-empty bucket)
  for (int b = tid; b < NBUK; b += 256)
    gcur[b] = (cnt[b] > 0) ? (bbase[b] + atomicAdd(&bcursor[b], cnt[b])) : 0;
  __syncthreads();
  // pass 2: scatter straight to global
  for (int i = tid; i < CHUNK; i += 256) {
    int e = e0 + i;
    if (e < NE) {
      int d = dst[e];
      int b = d >> BSHIFT;
      int pos = atomicAdd(&gcur[b], 1);
      stag[pos] = src[e] | (attr[e] << 17) | ((d & (BNODES - 1)) << 19);
    }
  }
}

// per bucket: local hist(512) -> scan -> rowptr; scatter col within 32KB window.
// col entry format: src | attr<<20  (same as before)
__global__ __launch_bounds__(256) void bucket_csr_kernel(
    const int* __restrict__ bbase, const int* __restrict__ stag,
    int* __restrict__ rowptr, int* __restrict__ col) {
  __shared__ int hist[BNODES];
  __shared__ int wsum[4];
  int b = blockIdx.x, tid = threadIdx.x, lane = tid & 63, wave = tid >> 6;
  int base = bbase[b];
  int endb = (b == NBUK - 1) ? NE : bbase[b + 1];
  int n = endb - base;
  int nodes0 = b << BSHIFT;
  int nloc = NN - nodes0; if (nloc > BNODES) nloc = BNODES;
  for (int i = tid; i < BNODES; i += 256) hist[i] = 0;
  __syncthreads();
  for (int i = tid; i < n; i += 256)
    atomicAdd(&hist[(stag[base + i] >> 19) & (BNODES - 1)], 1);
  __syncthreads();
  // scan 512 with 256 threads: 2 elems/thread
  int a0 = hist[2 * tid], a1 = hist[2 * tid + 1];
  int pairsum = a0 + a1;
  int incl = wave_incl_scan(pairsum);
  if (lane == 63) wsum[wave] = incl;
  __syncthreads();
  int wbase = 0;
  for (int w = 0; w < wave; ++w) wbase += wsum[w];
  int excl = incl - pairsum + wbase;      // bucket-relative exclusive over pairs
  if (2 * tid < nloc)     rowptr[nodes0 + 2 * tid]     = base + excl;
  if (2 * tid + 1 < nloc) rowptr[nodes0 + 2 * tid + 1] = base + excl + a0;
  __syncthreads();
  hist[2 * tid] = excl;
  hist[2 * tid + 1] = excl + a0;
  __syncthreads();
  for (int i = tid; i < n; i += 256) {
    int p = stag[base + i];
    int dl = (p >> 19) & (BNODES - 1);
    int pos = atomicAdd(&hist[dl], 1);
    col[base + pos] = (p & 0x1FFFF) | (((p >> 17) & 3) << 20);
  }
}

// ae_tab[l*4+k] = e_tab[l][k] . (W_edges[l]^T att_edge[l])
__global__ __launch_bounds__(64) void prep_ae_kernel(const float* __restrict__ edge_embs,
                                                     const float* __restrict__ W_edges,
                                                     const float* __restrict__ att_edge,
                                                     float* __restrict__ ae_tab) {
  int t = blockIdx.x;          // 0..15
  int l = t >> 2, k = t & 3;
  int j = threadIdx.x;         // 0..63
  const float* We = W_edges + l * DD * DD;
  const float* aE = att_edge + l * DD;
  const float* et = edge_embs + (l * 4 + k) * DD;
  float tj = 0.f;
  #pragma unroll 8
  for (int d = 0; d < DD; ++d) tj = fmaf(We[d * DD + j], aE[d], tj);
  float acc = wave_reduce_sum(et[j] * tj);
  if (j == 0) ae_tab[t] = acc;
}

// g = h @ W^T (stored fp16) ; asrc = g . a_src ; adst = g . a_dst (from f32 acc)
// EMB=true (layer 0): h row comes from node_emb[x[v]] directly — no h round-trip.
template <bool EMB>
__global__ __launch_bounds__(256) void gemm_attn_kernel(
    const float* __restrict__ h, const int* __restrict__ x, const float* __restrict__ node_emb,
    const float* __restrict__ W,
    const float* __restrict__ a_src, const float* __restrict__ a_dst,
    __half* __restrict__ gh, float* __restrict__ asrc, float* __restrict__ adst) {
  __shared__ float Wsm[DD][68];
  __shared__ float hs[16][DD];
  int tid = threadIdx.x, wave = tid >> 6, lane = tid & 63;
  int vbase = blockIdx.x * 16;
  for (int idx = tid; idx < DD * DD; idx += 256) Wsm[idx >> 6][idx & 63] = W[idx];
  for (int idx = tid; idx < 16 * DD; idx += 256) {
    int row = idx >> 6, d = idx & 63;
    if (EMB) hs[row][d] = node_emb[x[vbase + row] * DD + d];
    else     hs[row][d] = h[(vbase + row) * DD + d];
  }
  __syncthreads();
  float acc0 = 0.f, acc1 = 0.f, acc2 = 0.f, acc3 = 0.f;
  int r = wave * 4;
  #pragma unroll
  for (int j4 = 0; j4 < DD / 4; ++j4) {
    float4 wv = *(const float4*)&Wsm[lane][j4 * 4];
    float4 h0 = *(const float4*)&hs[r + 0][j4 * 4];
    float4 h1 = *(const float4*)&hs[r + 1][j4 * 4];
    float4 h2 = *(const float4*)&hs[r + 2][j4 * 4];
    float4 h3 = *(const float4*)&hs[r + 3][j4 * 4];
    acc0 = fmaf(wv.x, h0.x, acc0); acc0 = fmaf(wv.y, h0.y, acc0);
    acc0 = fmaf(wv.z, h0.z, acc0); acc0 = fmaf(wv.w, h0.w, acc0);
    acc1 = fmaf(wv.x, h1.x, acc1); acc1 = fmaf(wv.y, h1.y, acc1);
    acc1 = fmaf(wv.z, h1.z, acc1); acc1 = fmaf(wv.w, h1.w, acc1);
    acc2 = fmaf(wv.x, h2.x, acc2); acc2 = fmaf(wv.y, h2.y, acc2);
    acc2 = fmaf(wv.z, h2.z, acc2); acc2 = fmaf(wv.w, h2.w, acc2);
    acc3 = fmaf(wv.x, h3.x, acc3); acc3 = fmaf(wv.y, h3.y, acc3);
    acc3 = fmaf(wv.z, h3.z, acc3); acc3 = fmaf(wv.w, h3.w, acc3);
  }
  int v = vbase + r;
  gh[(size_t)(v + 0) * DD + lane] = __float2half(acc0);
  gh[(size_t)(v + 1) * DD + lane] = __float2half(acc1);
  gh[(size_t)(v + 2) * DD + lane] = __float2half(acc2);
  gh[(size_t)(v + 3) * DD + lane] = __float2half(acc3);
  float asl = a_src[lane], adl = a_dst[lane];
  float p;
  p = wave_reduce_sum(acc0 * asl); if (lane == 0) asrc[v + 0] = p;
  p = wave_reduce_sum(acc1 * asl); if (lane == 0) asrc[v + 1] = p;
  p = wave_reduce_sum(acc2 * asl); if (lane == 0) asrc[v + 2] = p;
  p = wave_reduce_sum(acc3 * asl); if (lane == 0) asrc[v + 3] = p;
  p = wave_reduce_sum(acc0 * adl); if (lane == 0) adst[v + 0] = p;
  p = wave_reduce_sum(acc1 * adl); if (lane == 0) adst[v + 1] = p;
  p = wave_reduce_sum(acc2 * adl); if (lane == 0) adst[v + 2] = p;
  p = wave_reduce_sum(acc3 * adl); if (lane == 0) adst[v + 3] = p;
}

// softmax attention + aggregation, single pass, fp16 g gathers.
// (ex,s) pairs staged in LDS (wave-lockstep, barrier-free) instead of
// 32 ds_bpermute shfl-broadcasts per chunk: 1 store/lane + broadcast reads.
__global__ __launch_bounds__(256) void aggregate_kernel(
    const __half* __restrict__ gh, const float* __restrict__ asrc, const float* __restrict__ adst,
    const int* __restrict__ rowptr, const int* __restrict__ col,
    const float* __restrict__ ae4, const float* __restrict__ bias, float* __restrict__ hout) {
  __shared__ uint2 exs[256];
  int tid = threadIdx.x, wave = tid >> 6, lane = tid & 63;
  int sub = lane & 15;
  int gb = tid & 240;                 // group base index in exs (wave*64 + lane&48)
  int v = blockIdx.x * 16 + wave * 4 + (lane >> 4);
  int start = rowptr[v], end = rowptr[v + 1];
  float adstv = adst[v];

  float4 acc = {0.f, 0.f, 0.f, 0.f};
  float den = 0.f;
  for (int base = start; base < end; base += 16) {
    int e = base + sub;
    float ex = 0.f; int s = 0;
    if (e < end) {
      int p = col[e]; s = p & 0xFFFFF; int a = p >> 20;
      float al = asrc[s] + adstv + ae4[a];
      al = (al > 0.f) ? al : NEG_SLOPE * al;
      ex = __expf(al);
    }
    den += ex;
    exs[tid] = make_uint2(__float_as_uint(ex), (unsigned)s);
    #pragma unroll
    for (int j = 0; j < 16; ++j) {
      uint2 q = exs[gb + j];
      float exj = __uint_as_float(q.x);
      int sj = (int)q.y;
      uint2 raw = *(const uint2*)(gh + (size_t)sj * DD + sub * 4);
      __half2 p0 = *(__half2*)&raw.x;
      __half2 p1 = *(__half2*)&raw.y;
      float2 f0 = __half22float2(p0);
      float2 f1 = __half22float2(p1);
      acc.x = fmaf(exj, f0.x, acc.x);
      acc.y = fmaf(exj, f0.y, acc.y);
      acc.z = fmaf(exj, f1.x, acc.z);
      acc.w = fmaf(exj, f1.y, acc.w);
    }
  }
  den = group16_sum(den);
  float inv = 1.f / (den + EPSF);
  float4 b4 = ((const float4*)bias)[sub];
  float4 o;
  o.x = fmaxf(fmaf(acc.x, inv, b4.x), 0.f);
  o.y = fmaxf(fmaf(acc.y, inv, b4.y), 0.f);
  o.z = fmaxf(fmaf(acc.z, inv, b4.z), 0.f);
  o.w = fmaxf(fmaf(acc.w, inv, b4.w), 0.f);
  ((float4*)hout)[(size_t)v * 16 + sub] = o;
}

// pooled[g] = segment-sum of h (batch sorted); then MLP, all in one block.
__global__ __launch_bounds__(256) void pool_mlp_kernel(
    const float* __restrict__ h, const int* __restrict__ batch,
    const float* __restrict__ W1, const float* __restrict__ b1,
    const float* __restrict__ W2, const float* __restrict__ b2,
    float* __restrict__ out) {
  __shared__ int s_lo, s_hi;
  __shared__ float red[4][DD];
  __shared__ float sp[DD];
  __shared__ float sh[2 * DD];
  int gI = blockIdx.x;
  int tid = threadIdx.x, wave = tid >> 6, lane = tid & 63;
  if (tid == 0) {
    int lo = 0, hi = NN;
    while (lo < hi) { int mid = (lo + hi) >> 1; if (batch[mid] < gI) lo = mid + 1; else hi = mid; }
    s_lo = lo;
    lo = 0; hi = NN;
    while (lo < hi) { int mid = (lo + hi) >> 1; if (batch[mid] < gI + 1) lo = mid + 1; else hi = mid; }
    s_hi = lo;
  }
  __syncthreads();
  float acc = 0.f;
  for (int v = s_lo + wave; v < s_hi; v += 4) acc += h[v * DD + lane];
  red[wave][lane] = acc;
  __syncthreads();
  if (wave == 0) sp[lane] = red[0][lane] + red[1][lane] + red[2][lane] + red[3][lane];
  __syncthreads();
  if (tid < 2 * DD) {
    float a = b1[tid];
    for (int d = 0; d < DD; ++d) a += sp[d] * W1[tid * DD + d];
    sh[tid] = fmaxf(a, 0.f);
  }
  __syncthreads();
  if (tid < TT) {
    float o = b2[tid];
    for (int k = 0; k < 2 * DD; ++k) o += sh[k] * W2[tid * 2 * DD + k];
    out[gI * TT + tid] = o;
  }
}

extern "C" void kernel_launch(void* const* d_in, const int* in_sizes, int n_in,
                              void* d_out, int out_size, void* d_ws, size_t ws_size,
                              hipStream_t stream) {
  const int* x          = (const int*)d_in[0];
  const int* edge_index = (const int*)d_in[1];
  const int* edge_attr  = (const int*)d_in[2];
  const int* batch      = (const int*)d_in[3];
  const float* node_emb = (const float*)d_in[4];
  const float* edge_embs= (const float*)d_in[5];
  const float* Ws_      = (const float*)d_in[6];
  const float* W_edges  = (const float*)d_in[7];
  const float* att_src  = (const float*)d_in[8];
  const float* att_dst  = (const float*)d_in[9];
  const float* att_edge = (const float*)d_in[10];
  const float* biases   = (const float*)d_in[11];
  const float* W1       = (const float*)d_in[12];
  const float* b1       = (const float*)d_in[13];
  const float* W2       = (const float*)d_in[14];
  const float* b2       = (const float*)d_in[15];
  float* out = (float*)d_out;

  char* wsp = (char*)d_ws;
  float* h      = (float*)wsp; wsp += (size_t)NN * DD * 4;
  __half* gh    = (__half*)wsp; wsp += (size_t)NN * DD * 2;
  float* asrc   = (float*)wsp; wsp += (size_t)NN * 4;
  float* adst   = (float*)wsp; wsp += (size_t)NN * 4;
  float* ae_tab = (float*)wsp; wsp += 16 * 4;
  int* rowptr   = (int*)wsp;   wsp += (size_t)(NN + 1) * 4;
  int* bcnt     = (int*)wsp;   wsp += (size_t)NBUK * 4;   // zeroed
  int* bcursor  = (int*)wsp;   wsp += (size_t)NBUK * 4;   // zeroed (adjacent to bcnt)
  int* bbase    = (int*)wsp;   wsp += (size_t)NBUK * 4;
  int* stag     = (int*)wsp;   wsp += (size_t)NE * 4;
  int* col      = (int*)wsp;   wsp += (size_t)NE * 4;

  const int* src = edge_index;
  const int* dst = edge_index + NE;

  const int nchunk = (NE + CHUNK - 1) / CHUNK;   // 391

  hipMemsetAsync(bcnt, 0, 2 * NBUK * sizeof(int), stream);   // bcnt + bcursor
  bucket_count_kernel<<<nchunk, 256, 0, stream>>>(dst, bcnt);
  bucket_scan_kernel<<<1, 128, 0, stream>>>(bcnt, bbase, rowptr);
  bucket_bin_kernel<<<nchunk, 256, 0, stream>>>(src, dst, edge_attr, bbase, bcursor, stag);
  bucket_csr_kernel<<<NBUK, 256, 0, stream>>>(bbase, stag, rowptr, col);
  prep_ae_kernel<<<16, 64, 0, stream>>>(edge_embs, W_edges, att_edge, ae_tab);

  for (int l = 0; l < LL; ++l) {
    if (l == 0)
      gemm_attn_kernel<true><<<NN / 16, 256, 0, stream>>>(h, x, node_emb, Ws_,
                                                          att_src, att_dst, gh, asrc, adst);
    else
      gemm_attn_kernel<false><<<NN / 16, 256, 0, stream>>>(h, x, node_emb, Ws_ + l * DD * DD,
                                                           att_src + l * DD, att_dst + l * DD,
                                                           gh, asrc, adst);
    aggregate_kernel<<<NN / 16, 256, 0, stream>>>(gh, asrc, adst, rowptr, col,
                                                  ae_tab + l * 4, biases + l * DD, h);
  }

  pool_mlp_kernel<<<GG, 256, 0, stream>>>(h, batch, W1, b1, W2, b2, out);
}

// Round 16
// 370.135 us; speedup vs baseline: 2.3976x; 1.0030x over previous
//
#include <hip/hip_runtime.h>
#include <hip/hip_fp16.h>
#include <math.h>

#define NN 50000
#define NE 800000
#define DD 64
#define LL 4
#define GG 128
#define TT 10
#define NEG_SLOPE 0.2f
#define EPSF 1e-16f

#define BSHIFT 9
#define BNODES 512                       // nodes per bucket
#define NBUK ((NN + BNODES - 1) / BNODES)  // 98
#define CHUNK 2048

__device__ __forceinline__ float wave_reduce_sum(float v) {
  #pragma unroll
  for (int off = 32; off > 0; off >>= 1) v += __shfl_xor(v, off, 64);
  return v;
}
__device__ __forceinline__ float group16_sum(float v) {
  #pragma unroll
  for (int off = 1; off < 16; off <<= 1) v += __shfl_xor(v, off, 64);
  return v;
}
__device__ __forceinline__ int wave_incl_scan(int v) {
  int lane = threadIdx.x & 63;
  #pragma unroll
  for (int off = 1; off < 64; off <<= 1) {
    int t = __shfl_up(v, off, 64);
    if (lane >= off) v += t;
  }
  return v;
}

// per-block LDS histogram of dst>>BSHIFT -> global bucket counts
__global__ __launch_bounds__(256) void bucket_count_kernel(const int* __restrict__ dst,
                                                           int* __restrict__ bcnt) {
  __shared__ int cnt[NBUK];
  int tid = threadIdx.x;
  for (int i = tid; i < NBUK; i += 256) cnt[i] = 0;
  __syncthreads();
  int e0 = blockIdx.x * CHUNK;
  for (int i = tid; i < CHUNK; i += 256) {
    int e = e0 + i;
    if (e < NE) atomicAdd(&cnt[dst[e] >> BSHIFT], 1);
  }
  __syncthreads();
  for (int b = tid; b < NBUK; b += 256)
    if (cnt[b]) atomicAdd(&bcnt[b], cnt[b]);
}

// exclusive scan of NBUK (<=128) bucket counts -> bbase; rowptr[NN] = NE
__global__ __launch_bounds__(128) void bucket_scan_kernel(const int* __restrict__ bcnt,
                                                          int* __restrict__ bbase,
                                                          int* __restrict__ rowptr) {
  __shared__ int w0sum;
  int tid = threadIdx.x, lane = tid & 63, wave = tid >> 6;
  int v = (tid < NBUK) ? bcnt[tid] : 0;
  int incl = wave_incl_scan(v);
  if (wave == 0 && lane == 63) w0sum = incl;
  __syncthreads();
  int excl = incl - v + (wave ? w0sum : 0);
  if (tid < NBUK) bbase[tid] = excl;
  if (tid == 0) rowptr[NN] = NE;
}

// count chunk's bucket histogram in LDS, reserve contiguous spans, then
// scatter DIRECTLY to global (each span is block-private => line locality).
// packed record: src[0:17) | attr[17:19) | dstlow[19:28)
__global__ __launch_bounds__(256) void bucket_bin_kernel(
    const int* __restrict__ src, const int* __restrict__ dst, const int* __restrict__ attr,
    const int* __restrict__ bbase, int* __restrict__ bcursor, int* __restrict__ stag) {
  __shared__ int cnt[NBUK];
  __shared__ int gcur[NBUK];
  int tid = threadIdx.x;
  for (int i = tid; i < NBUK; i += 256) cnt[i] = 0;
  __syncthreads();
  int e0 = blockIdx.x * CHUNK;
  // pass 1: count
  for (int i = tid; i < CHUNK; i += 256) {
    int e = e0 + i;
    if (e < NE) atomicAdd(&cnt[dst[e] >> BSHIFT], 1);
  }
  __syncthreads();
  // reserve spans (one global atomic per non-empty bucket)
  for (int b = tid; b < NBUK; b += 256)
    gcur[b] = (cnt[b] > 0) ? (bbase[b] + atomicAdd(&bcursor[b], cnt[b])) : 0;
  __syncthreads();
  // pass 2: scatter straight to global
  for (int i = tid; i < CHUNK; i += 256) {
    int e = e0 + i;
    if (e < NE) {
      int d = dst[e];
      int b = d >> BSHIFT;
      int pos = atomicAdd(&gcur[b], 1);
      stag[pos] = src[e] | (attr[e] << 17) | ((d & (BNODES - 1)) << 19);
    }
  }
}

// per bucket: local hist(512) -> scan -> rowptr; scatter col within 32KB window.
// col entry format: src | attr<<20  (same as before)
__global__ __launch_bounds__(256) void bucket_csr_kernel(
    const int* __restrict__ bbase, const int* __restrict__ stag,
    int* __restrict__ rowptr, int* __restrict__ col) {
  __shared__ int hist[BNODES];
  __shared__ int wsum[4];
  int b = blockIdx.x, tid = threadIdx.x, lane = tid & 63, wave = tid >> 6;
  int base = bbase[b];
  int endb = (b == NBUK - 1) ? NE : bbase[b + 1];
  int n = endb - base;
  int nodes0 = b << BSHIFT;
  int nloc = NN - nodes0; if (nloc > BNODES) nloc = BNODES;
  for (int i = tid; i < BNODES; i += 256) hist[i] = 0;
  __syncthreads();
  for (int i = tid; i < n; i += 256)
    atomicAdd(&hist[(stag[base + i] >> 19) & (BNODES - 1)], 1);
  __syncthreads();
  // scan 512 with 256 threads: 2 elems/thread
  int a0 = hist[2 * tid], a1 = hist[2 * tid + 1];
  int pairsum = a0 + a1;
  int incl = wave_incl_scan(pairsum);
  if (lane == 63) wsum[wave] = incl;
  __syncthreads();
  int wbase = 0;
  for (int w = 0; w < wave; ++w) wbase += wsum[w];
  int excl = incl - pairsum + wbase;      // bucket-relative exclusive over pairs
  if (2 * tid < nloc)     rowptr[nodes0 + 2 * tid]     = base + excl;
  if (2 * tid + 1 < nloc) rowptr[nodes0 + 2 * tid + 1] = base + excl + a0;
  __syncthreads();
  hist[2 * tid] = excl;
  hist[2 * tid + 1] = excl + a0;
  __syncthreads();
  for (int i = tid; i < n; i += 256) {
    int p = stag[base + i];
    int dl = (p >> 19) & (BNODES - 1);
    int pos = atomicAdd(&hist[dl], 1);
    col[base + pos] = (p & 0x1FFFF) | (((p >> 17) & 3) << 20);
  }
}

// ae_tab[l*4+k] = e_tab[l][k] . (W_edges[l]^T att_edge[l])
__global__ __launch_bounds__(64) void prep_ae_kernel(const float* __restrict__ edge_embs,
                                                     const float* __restrict__ W_edges,
                                                     const float* __restrict__ att_edge,
                                                     float* __restrict__ ae_tab) {
  int t = blockIdx.x;          // 0..15
  int l = t >> 2, k = t & 3;
  int j = threadIdx.x;         // 0..63
  const float* We = W_edges + l * DD * DD;
  const float* aE = att_edge + l * DD;
  const float* et = edge_embs + (l * 4 + k) * DD;
  float tj = 0.f;
  #pragma unroll 8
  for (int d = 0; d < DD; ++d) tj = fmaf(We[d * DD + j], aE[d], tj);
  float acc = wave_reduce_sum(et[j] * tj);
  if (j == 0) ae_tab[t] = acc;
}

// g = h @ W^T (stored fp16) ; asrc = g . a_src ; adst = g . a_dst (from f32 acc)
// EMB=true (layer 0): h row comes from node_emb[x[v]] directly.
// h is stored fp16 (halved traffic); converted to f32 in LDS.
template <bool EMB>
__global__ __launch_bounds__(256) void gemm_attn_kernel(
    const __half* __restrict__ hh, const int* __restrict__ x, const float* __restrict__ node_emb,
    const float* __restrict__ W,
    const float* __restrict__ a_src, const float* __restrict__ a_dst,
    __half* __restrict__ gh, float* __restrict__ asrc, float* __restrict__ adst) {
  __shared__ float Wsm[DD][68];
  __shared__ float hs[16][DD];
  int tid = threadIdx.x, wave = tid >> 6, lane = tid & 63;
  int vbase = blockIdx.x * 16;
  for (int idx = tid; idx < DD * DD; idx += 256) Wsm[idx >> 6][idx & 63] = W[idx];
  for (int idx = tid; idx < 16 * DD; idx += 256) {
    int row = idx >> 6, d = idx & 63;
    if (EMB) hs[row][d] = node_emb[x[vbase + row] * DD + d];
    else     hs[row][d] = __half2float(hh[(size_t)(vbase + row) * DD + d]);
  }
  __syncthreads();
  float acc0 = 0.f, acc1 = 0.f, acc2 = 0.f, acc3 = 0.f;
  int r = wave * 4;
  #pragma unroll
  for (int j4 = 0; j4 < DD / 4; ++j4) {
    float4 wv = *(const float4*)&Wsm[lane][j4 * 4];
    float4 h0 = *(const float4*)&hs[r + 0][j4 * 4];
    float4 h1 = *(const float4*)&hs[r + 1][j4 * 4];
    float4 h2 = *(const float4*)&hs[r + 2][j4 * 4];
    float4 h3 = *(const float4*)&hs[r + 3][j4 * 4];
    acc0 = fmaf(wv.x, h0.x, acc0); acc0 = fmaf(wv.y, h0.y, acc0);
    acc0 = fmaf(wv.z, h0.z, acc0); acc0 = fmaf(wv.w, h0.w, acc0);
    acc1 = fmaf(wv.x, h1.x, acc1); acc1 = fmaf(wv.y, h1.y, acc1);
    acc1 = fmaf(wv.z, h1.z, acc1); acc1 = fmaf(wv.w, h1.w, acc1);
    acc2 = fmaf(wv.x, h2.x, acc2); acc2 = fmaf(wv.y, h2.y, acc2);
    acc2 = fmaf(wv.z, h2.z, acc2); acc2 = fmaf(wv.w, h2.w, acc2);
    acc3 = fmaf(wv.x, h3.x, acc3); acc3 = fmaf(wv.y, h3.y, acc3);
    acc3 = fmaf(wv.z, h3.z, acc3); acc3 = fmaf(wv.w, h3.w, acc3);
  }
  int v = vbase + r;
  gh[(size_t)(v + 0) * DD + lane] = __float2half(acc0);
  gh[(size_t)(v + 1) * DD + lane] = __float2half(acc1);
  gh[(size_t)(v + 2) * DD + lane] = __float2half(acc2);
  gh[(size_t)(v + 3) * DD + lane] = __float2half(acc3);
  float asl = a_src[lane], adl = a_dst[lane];
  float p;
  p = wave_reduce_sum(acc0 * asl); if (lane == 0) asrc[v + 0] = p;
  p = wave_reduce_sum(acc1 * asl); if (lane == 0) asrc[v + 1] = p;
  p = wave_reduce_sum(acc2 * asl); if (lane == 0) asrc[v + 2] = p;
  p = wave_reduce_sum(acc3 * asl); if (lane == 0) asrc[v + 3] = p;
  p = wave_reduce_sum(acc0 * adl); if (lane == 0) adst[v + 0] = p;
  p = wave_reduce_sum(acc1 * adl); if (lane == 0) adst[v + 1] = p;
  p = wave_reduce_sum(acc2 * adl); if (lane == 0) adst[v + 2] = p;
  p = wave_reduce_sum(acc3 * adl); if (lane == 0) adst[v + 3] = p;
}

// softmax attention + aggregation, single pass, fp16 g gathers, fp16 h out.
__global__ __launch_bounds__(256) void aggregate_kernel(
    const __half* __restrict__ gh, const float* __restrict__ asrc, const float* __restrict__ adst,
    const int* __restrict__ rowptr, const int* __restrict__ col,
    const float* __restrict__ ae4, const float* __restrict__ bias, __half* __restrict__ hout) {
  __shared__ uint2 exs[256];
  int tid = threadIdx.x, wave = tid >> 6, lane = tid & 63;
  int sub = lane & 15;
  int gb = tid & 240;                 // group base index in exs (wave*64 + lane&48)
  int v = blockIdx.x * 16 + wave * 4 + (lane >> 4);
  int start = rowptr[v], end = rowptr[v + 1];
  float adstv = adst[v];

  float4 acc = {0.f, 0.f, 0.f, 0.f};
  float den = 0.f;
  for (int base = start; base < end; base += 16) {
    int e = base + sub;
    float ex = 0.f; int s = 0;
    if (e < end) {
      int p = col[e]; s = p & 0xFFFFF; int a = p >> 20;
      float al = asrc[s] + adstv + ae4[a];
      al = (al > 0.f) ? al : NEG_SLOPE * al;
      ex = __expf(al);
    }
    den += ex;
    exs[tid] = make_uint2(__float_as_uint(ex), (unsigned)s);
    #pragma unroll
    for (int j = 0; j < 16; ++j) {
      uint2 q = exs[gb + j];
      float exj = __uint_as_float(q.x);
      int sj = (int)q.y;
      uint2 raw = *(const uint2*)(gh + (size_t)sj * DD + sub * 4);
      __half2 p0 = *(__half2*)&raw.x;
      __half2 p1 = *(__half2*)&raw.y;
      float2 f0 = __half22float2(p0);
      float2 f1 = __half22float2(p1);
      acc.x = fmaf(exj, f0.x, acc.x);
      acc.y = fmaf(exj, f0.y, acc.y);
      acc.z = fmaf(exj, f1.x, acc.z);
      acc.w = fmaf(exj, f1.y, acc.w);
    }
  }
  den = group16_sum(den);
  float inv = 1.f / (den + EPSF);
  float4 b4 = ((const float4*)bias)[sub];
  float ox = fmaxf(fmaf(acc.x, inv, b4.x), 0.f);
  float oy = fmaxf(fmaf(acc.y, inv, b4.y), 0.f);
  float oz = fmaxf(fmaf(acc.z, inv, b4.z), 0.f);
  float ow = fmaxf(fmaf(acc.w, inv, b4.w), 0.f);
  __half2 o01 = __floats2half2_rn(ox, oy);
  __half2 o23 = __floats2half2_rn(oz, ow);
  uint2 packed = make_uint2(*(unsigned*)&o01, *(unsigned*)&o23);
  *(uint2*)(hout + (size_t)v * DD + sub * 4) = packed;
}

// pooled[g] = segment-sum of fp16 h (batch sorted); then MLP, all in one block.
__global__ __launch_bounds__(256) void pool_mlp_kernel(
    const __half* __restrict__ hh, const int* __restrict__ batch,
    const float* __restrict__ W1, const float* __restrict__ b1,
    const float* __restrict__ W2, const float* __restrict__ b2,
    float* __restrict__ out) {
  __shared__ int s_lo, s_hi;
  __shared__ float red[4][DD];
  __shared__ float sp[DD];
  __shared__ float sh[2 * DD];
  int gI = blockIdx.x;
  int tid = threadIdx.x, wave = tid >> 6, lane = tid & 63;
  if (tid == 0) {
    int lo = 0, hi = NN;
    while (lo < hi) { int mid = (lo + hi) >> 1; if (batch[mid] < gI) lo = mid + 1; else hi = mid; }
    s_lo = lo;
    lo = 0; hi = NN;
    while (lo < hi) { int mid = (lo + hi) >> 1; if (batch[mid] < gI + 1) lo = mid + 1; else hi = mid; }
    s_hi = lo;
  }
  __syncthreads();
  float acc = 0.f;
  for (int v = s_lo + wave; v < s_hi; v += 4) acc += __half2float(hh[(size_t)v * DD + lane]);
  red[wave][lane] = acc;
  __syncthreads();
  if (wave == 0) sp[lane] = red[0][lane] + red[1][lane] + red[2][lane] + red[3][lane];
  __syncthreads();
  if (tid < 2 * DD) {
    float a = b1[tid];
    for (int d = 0; d < DD; ++d) a += sp[d] * W1[tid * DD + d];
    sh[tid] = fmaxf(a, 0.f);
  }
  __syncthreads();
  if (tid < TT) {
    float o = b2[tid];
    for (int k = 0; k < 2 * DD; ++k) o += sh[k] * W2[tid * 2 * DD + k];
    out[gI * TT + tid] = o;
  }
}

extern "C" void kernel_launch(void* const* d_in, const int* in_sizes, int n_in,
                              void* d_out, int out_size, void* d_ws, size_t ws_size,
                              hipStream_t stream) {
  const int* x          = (const int*)d_in[0];
  const int* edge_index = (const int*)d_in[1];
  const int* edge_attr  = (const int*)d_in[2];
  const int* batch      = (const int*)d_in[3];
  const float* node_emb = (const float*)d_in[4];
  const float* edge_embs= (const float*)d_in[5];
  const float* Ws_      = (const float*)d_in[6];
  const float* W_edges  = (const float*)d_in[7];
  const float* att_src  = (const float*)d_in[8];
  const float* att_dst  = (const float*)d_in[9];
  const float* att_edge = (const float*)d_in[10];
  const float* biases   = (const float*)d_in[11];
  const float* W1       = (const float*)d_in[12];
  const float* b1       = (const float*)d_in[13];
  const float* W2       = (const float*)d_in[14];
  const float* b2       = (const float*)d_in[15];
  float* out = (float*)d_out;

  char* wsp = (char*)d_ws;
  __half* h     = (__half*)wsp; wsp += (size_t)NN * DD * 2;
  __half* gh    = (__half*)wsp; wsp += (size_t)NN * DD * 2;
  float* asrc   = (float*)wsp; wsp += (size_t)NN * 4;
  float* adst   = (float*)wsp; wsp += (size_t)NN * 4;
  float* ae_tab = (float*)wsp; wsp += 16 * 4;
  int* rowptr   = (int*)wsp;   wsp += (size_t)(NN + 1) * 4;
  int* bcnt     = (int*)wsp;   wsp += (size_t)NBUK * 4;   // zeroed
  int* bcursor  = (int*)wsp;   wsp += (size_t)NBUK * 4;   // zeroed (adjacent to bcnt)
  int* bbase    = (int*)wsp;   wsp += (size_t)NBUK * 4;
  int* stag     = (int*)wsp;   wsp += (size_t)NE * 4;
  int* col      = (int*)wsp;   wsp += (size_t)NE * 4;

  const int* src = edge_index;
  const int* dst = edge_index + NE;

  const int nchunk = (NE + CHUNK - 1) / CHUNK;   // 391

  hipMemsetAsync(bcnt, 0, 2 * NBUK * sizeof(int), stream);   // bcnt + bcursor
  bucket_count_kernel<<<nchunk, 256, 0, stream>>>(dst, bcnt);
  bucket_scan_kernel<<<1, 128, 0, stream>>>(bcnt, bbase, rowptr);
  bucket_bin_kernel<<<nchunk, 256, 0, stream>>>(src, dst, edge_attr, bbase, bcursor, stag);
  bucket_csr_kernel<<<NBUK, 256, 0, stream>>>(bbase, stag, rowptr, col);
  prep_ae_kernel<<<16, 64, 0, stream>>>(edge_embs, W_edges, att_edge, ae_tab);

  for (int l = 0; l < LL; ++l) {
    if (l == 0)
      gemm_attn_kernel<true><<<NN / 16, 256, 0, stream>>>(h, x, node_emb, Ws_,
                                                          att_src, att_dst, gh, asrc, adst);
    else
      gemm_attn_kernel<false><<<NN / 16, 256, 0, stream>>>(h, x, node_emb, Ws_ + l * DD * DD,
                                                           att_src + l * DD, att_dst + l * DD,
                                                           gh, asrc, adst);
    aggregate_kernel<<<NN / 16, 256, 0, stream>>>(gh, asrc, adst, rowptr, col,
                                                  ae_tab + l * 4, biases + l * DD, h);
  }

  pool_mlp_kernel<<<GG, 256, 0, stream>>>(h, batch, W1, b1, W2, b2, out);
}

// Round 17
// 362.233 us; speedup vs baseline: 2.4499x; 1.0218x over previous
//
#include <hip/hip_runtime.h>
#include <hip/hip_fp16.h>
#include <math.h>

#define NN 50000
#define NE 800000
#define DD 64
#define LL 4
#define GG 128
#define TT 10
#define NEG_SLOPE 0.2f
#define EPSF 1e-16f

#define BSHIFT 9
#define BNODES 512                       // nodes per bucket
#define NBUK ((NN + BNODES - 1) / BNODES)  // 98
#define CHUNK 2048

__device__ __forceinline__ float wave_reduce_sum(float v) {
  #pragma unroll
  for (int off = 32; off > 0; off >>= 1) v += __shfl_xor(v, off, 64);
  return v;
}
__device__ __forceinline__ float group8_sum(float v) {
  #pragma unroll
  for (int off = 1; off < 8; off <<= 1) v += __shfl_xor(v, off, 64);
  return v;
}
__device__ __forceinline__ int wave_incl_scan(int v) {
  int lane = threadIdx.x & 63;
  #pragma unroll
  for (int off = 1; off < 64; off <<= 1) {
    int t = __shfl_up(v, off, 64);
    if (lane >= off) v += t;
  }
  return v;
}

// per-block LDS histogram of dst>>BSHIFT -> global bucket counts
__global__ __launch_bounds__(256) void bucket_count_kernel(const int* __restrict__ dst,
                                                           int* __restrict__ bcnt) {
  __shared__ int cnt[NBUK];
  int tid = threadIdx.x;
  for (int i = tid; i < NBUK; i += 256) cnt[i] = 0;
  __syncthreads();
  int e0 = blockIdx.x * CHUNK;
  for (int i = tid; i < CHUNK; i += 256) {
    int e = e0 + i;
    if (e < NE) atomicAdd(&cnt[dst[e] >> BSHIFT], 1);
  }
  __syncthreads();
  for (int b = tid; b < NBUK; b += 256)
    if (cnt[b]) atomicAdd(&bcnt[b], cnt[b]);
}

// exclusive scan of NBUK (<=128) bucket counts -> bbase; rowptr[NN] = NE
__global__ __launch_bounds__(128) void bucket_scan_kernel(const int* __restrict__ bcnt,
                                                          int* __restrict__ bbase,
                                                          int* __restrict__ rowptr) {
  __shared__ int w0sum;
  int tid = threadIdx.x, lane = tid & 63, wave = tid >> 6;
  int v = (tid < NBUK) ? bcnt[tid] : 0;
  int incl = wave_incl_scan(v);
  if (wave == 0 && lane == 63) w0sum = incl;
  __syncthreads();
  int excl = incl - v + (wave ? w0sum : 0);
  if (tid < NBUK) bbase[tid] = excl;
  if (tid == 0) rowptr[NN] = NE;
}

// count chunk's bucket histogram in LDS, reserve contiguous spans, then
// scatter DIRECTLY to global (each span is block-private => line locality).
// packed record: src[0:17) | attr[17:19) | dstlow[19:28)
__global__ __launch_bounds__(256) void bucket_bin_kernel(
    const int* __restrict__ src, const int* __restrict__ dst, const int* __restrict__ attr,
    const int* __restrict__ bbase, int* __restrict__ bcursor, int* __restrict__ stag) {
  __shared__ int cnt[NBUK];
  __shared__ int gcur[NBUK];
  int tid = threadIdx.x;
  for (int i = tid; i < NBUK; i += 256) cnt[i] = 0;
  __syncthreads();
  int e0 = blockIdx.x * CHUNK;
  // pass 1: count
  for (int i = tid; i < CHUNK; i += 256) {
    int e = e0 + i;
    if (e < NE) atomicAdd(&cnt[dst[e] >> BSHIFT], 1);
  }
  __syncthreads();
  // reserve spans (one global atomic per non-empty bucket)
  for (int b = tid; b < NBUK; b += 256)
    gcur[b] = (cnt[b] > 0) ? (bbase[b] + atomicAdd(&bcursor[b], cnt[b])) : 0;
  __syncthreads();
  // pass 2: scatter straight to global
  for (int i = tid; i < CHUNK; i += 256) {
    int e = e0 + i;
    if (e < NE) {
      int d = dst[e];
      int b = d >> BSHIFT;
      int pos = atomicAdd(&gcur[b], 1);
      stag[pos] = src[e] | (attr[e] << 17) | ((d & (BNODES - 1)) << 19);
    }
  }
}

// per bucket: local hist(512) -> scan -> rowptr; scatter col within 32KB window.
// col entry format: src | attr<<20  (same as before)
__global__ __launch_bounds__(256) void bucket_csr_kernel(
    const int* __restrict__ bbase, const int* __restrict__ stag,
    int* __restrict__ rowptr, int* __restrict__ col) {
  __shared__ int hist[BNODES];
  __shared__ int wsum[4];
  int b = blockIdx.x, tid = threadIdx.x, lane = tid & 63, wave = tid >> 6;
  int base = bbase[b];
  int endb = (b == NBUK - 1) ? NE : bbase[b + 1];
  int n = endb - base;
  int nodes0 = b << BSHIFT;
  int nloc = NN - nodes0; if (nloc > BNODES) nloc = BNODES;
  for (int i = tid; i < BNODES; i += 256) hist[i] = 0;
  __syncthreads();
  for (int i = tid; i < n; i += 256)
    atomicAdd(&hist[(stag[base + i] >> 19) & (BNODES - 1)], 1);
  __syncthreads();
  // scan 512 with 256 threads: 2 elems/thread
  int a0 = hist[2 * tid], a1 = hist[2 * tid + 1];
  int pairsum = a0 + a1;
  int incl = wave_incl_scan(pairsum);
  if (lane == 63) wsum[wave] = incl;
  __syncthreads();
  int wbase = 0;
  for (int w = 0; w < wave; ++w) wbase += wsum[w];
  int excl = incl - pairsum + wbase;      // bucket-relative exclusive over pairs
  if (2 * tid < nloc)     rowptr[nodes0 + 2 * tid]     = base + excl;
  if (2 * tid + 1 < nloc) rowptr[nodes0 + 2 * tid + 1] = base + excl + a0;
  __syncthreads();
  hist[2 * tid] = excl;
  hist[2 * tid + 1] = excl + a0;
  __syncthreads();
  for (int i = tid; i < n; i += 256) {
    int p = stag[base + i];
    int dl = (p >> 19) & (BNODES - 1);
    int pos = atomicAdd(&hist[dl], 1);
    col[base + pos] = (p & 0x1FFFF) | (((p >> 17) & 3) << 20);
  }
}

// ae_tab[l*4+k] = e_tab[l][k] . (W_edges[l]^T att_edge[l])
__global__ __launch_bounds__(64) void prep_ae_kernel(const float* __restrict__ edge_embs,
                                                     const float* __restrict__ W_edges,
                                                     const float* __restrict__ att_edge,
                                                     float* __restrict__ ae_tab) {
  int t = blockIdx.x;          // 0..15
  int l = t >> 2, k = t & 3;
  int j = threadIdx.x;         // 0..63
  const float* We = W_edges + l * DD * DD;
  const float* aE = att_edge + l * DD;
  const float* et = edge_embs + (l * 4 + k) * DD;
  float tj = 0.f;
  #pragma unroll 8
  for (int d = 0; d < DD; ++d) tj = fmaf(We[d * DD + j], aE[d], tj);
  float acc = wave_reduce_sum(et[j] * tj);
  if (j == 0) ae_tab[t] = acc;
}

// g = h @ W^T (stored fp16) ; asrc = g . a_src ; adst = g . a_dst (from f32 acc)
// EMB=true (layer 0): h row comes from node_emb[x[v]] directly.
template <bool EMB>
__global__ __launch_bounds__(256) void gemm_attn_kernel(
    const __half* __restrict__ hh, const int* __restrict__ x, const float* __restrict__ node_emb,
    const float* __restrict__ W,
    const float* __restrict__ a_src, const float* __restrict__ a_dst,
    __half* __restrict__ gh, float* __restrict__ asrc, float* __restrict__ adst) {
  __shared__ float Wsm[DD][68];
  __shared__ float hs[16][DD];
  int tid = threadIdx.x, wave = tid >> 6, lane = tid & 63;
  int vbase = blockIdx.x * 16;
  for (int idx = tid; idx < DD * DD; idx += 256) Wsm[idx >> 6][idx & 63] = W[idx];
  for (int idx = tid; idx < 16 * DD; idx += 256) {
    int row = idx >> 6, d = idx & 63;
    if (EMB) hs[row][d] = node_emb[x[vbase + row] * DD + d];
    else     hs[row][d] = __half2float(hh[(size_t)(vbase + row) * DD + d]);
  }
  __syncthreads();
  float acc0 = 0.f, acc1 = 0.f, acc2 = 0.f, acc3 = 0.f;
  int r = wave * 4;
  #pragma unroll
  for (int j4 = 0; j4 < DD / 4; ++j4) {
    float4 wv = *(const float4*)&Wsm[lane][j4 * 4];
    float4 h0 = *(const float4*)&hs[r + 0][j4 * 4];
    float4 h1 = *(const float4*)&hs[r + 1][j4 * 4];
    float4 h2 = *(const float4*)&hs[r + 2][j4 * 4];
    float4 h3 = *(const float4*)&hs[r + 3][j4 * 4];
    acc0 = fmaf(wv.x, h0.x, acc0); acc0 = fmaf(wv.y, h0.y, acc0);
    acc0 = fmaf(wv.z, h0.z, acc0); acc0 = fmaf(wv.w, h0.w, acc0);
    acc1 = fmaf(wv.x, h1.x, acc1); acc1 = fmaf(wv.y, h1.y, acc1);
    acc1 = fmaf(wv.z, h1.z, acc1); acc1 = fmaf(wv.w, h1.w, acc1);
    acc2 = fmaf(wv.x, h2.x, acc2); acc2 = fmaf(wv.y, h2.y, acc2);
    acc2 = fmaf(wv.z, h2.z, acc2); acc2 = fmaf(wv.w, h2.w, acc2);
    acc3 = fmaf(wv.x, h3.x, acc3); acc3 = fmaf(wv.y, h3.y, acc3);
    acc3 = fmaf(wv.z, h3.z, acc3); acc3 = fmaf(wv.w, h3.w, acc3);
  }
  int v = vbase + r;
  gh[(size_t)(v + 0) * DD + lane] = __float2half(acc0);
  gh[(size_t)(v + 1) * DD + lane] = __float2half(acc1);
  gh[(size_t)(v + 2) * DD + lane] = __float2half(acc2);
  gh[(size_t)(v + 3) * DD + lane] = __float2half(acc3);
  float asl = a_src[lane], adl = a_dst[lane];
  float p;
  p = wave_reduce_sum(acc0 * asl); if (lane == 0) asrc[v + 0] = p;
  p = wave_reduce_sum(acc1 * asl); if (lane == 0) asrc[v + 1] = p;
  p = wave_reduce_sum(acc2 * asl); if (lane == 0) asrc[v + 2] = p;
  p = wave_reduce_sum(acc3 * asl); if (lane == 0) asrc[v + 3] = p;
  p = wave_reduce_sum(acc0 * adl); if (lane == 0) adst[v + 0] = p;
  p = wave_reduce_sum(acc1 * adl); if (lane == 0) adst[v + 1] = p;
  p = wave_reduce_sum(acc2 * adl); if (lane == 0) adst[v + 2] = p;
  p = wave_reduce_sum(acc3 * adl); if (lane == 0) adst[v + 3] = p;
}

// softmax attention + aggregation, single pass.
// 8 lanes per node, 16B (uint4) fp16 gathers: 8 loads/edge instead of 16.
// exs staging padded (idx = tid + tid>>3) so cross-group broadcast reads are
// bank-conflict-free. 8 nodes/wave, 32 nodes/block.
__global__ __launch_bounds__(256) void aggregate_kernel(
    const __half* __restrict__ gh, const float* __restrict__ asrc, const float* __restrict__ adst,
    const int* __restrict__ rowptr, const int* __restrict__ col,
    const float* __restrict__ ae4, const float* __restrict__ bias, __half* __restrict__ hout) {
  __shared__ uint2 exs[288];          // 256 + 32 pad
  int tid = threadIdx.x, lane = tid & 63;
  int sub = lane & 7;                 // feature slice owner (8 halves)
  int gb = tid & ~7;                  // group base (unpadded)
  int gbp = gb + (gb >> 3);           // padded group base
  int widx = tid + (tid >> 3);        // padded write index
  int v = blockIdx.x * 32 + (tid >> 3);
  if (v >= NN) return;                // no __syncthreads below: safe early-exit
  int start = rowptr[v], end = rowptr[v + 1];
  float adstv = adst[v];

  float acc0 = 0.f, acc1 = 0.f, acc2 = 0.f, acc3 = 0.f;
  float acc4 = 0.f, acc5 = 0.f, acc6 = 0.f, acc7 = 0.f;
  float den = 0.f;
  for (int base = start; base < end; base += 8) {
    int e = base + sub;
    float ex = 0.f; int s = 0;
    if (e < end) {
      int p = col[e]; s = p & 0xFFFFF; int a = p >> 20;
      float al = asrc[s] + adstv + ae4[a];
      al = (al > 0.f) ? al : NEG_SLOPE * al;
      ex = __expf(al);
    }
    den += ex;
    exs[widx] = make_uint2(__float_as_uint(ex), (unsigned)s);
    #pragma unroll
    for (int j = 0; j < 8; ++j) {
      uint2 q = exs[gbp + j];
      float exj = __uint_as_float(q.x);
      int sj = (int)q.y;
      uint4 raw = *(const uint4*)(gh + (size_t)sj * DD + sub * 8);
      __half2 p0 = *(__half2*)&raw.x;
      __half2 p1 = *(__half2*)&raw.y;
      __half2 p2 = *(__half2*)&raw.z;
      __half2 p3 = *(__half2*)&raw.w;
      float2 f0 = __half22float2(p0);
      float2 f1 = __half22float2(p1);
      float2 f2 = __half22float2(p2);
      float2 f3 = __half22float2(p3);
      acc0 = fmaf(exj, f0.x, acc0); acc1 = fmaf(exj, f0.y, acc1);
      acc2 = fmaf(exj, f1.x, acc2); acc3 = fmaf(exj, f1.y, acc3);
      acc4 = fmaf(exj, f2.x, acc4); acc5 = fmaf(exj, f2.y, acc5);
      acc6 = fmaf(exj, f3.x, acc6); acc7 = fmaf(exj, f3.y, acc7);
    }
  }
  den = group8_sum(den);
  float inv = 1.f / (den + EPSF);
  const float4* b4p = (const float4*)bias;
  float4 ba = b4p[sub * 2], bb = b4p[sub * 2 + 1];
  __half2 o0 = __floats2half2_rn(fmaxf(fmaf(acc0, inv, ba.x), 0.f),
                                 fmaxf(fmaf(acc1, inv, ba.y), 0.f));
  __half2 o1 = __floats2half2_rn(fmaxf(fmaf(acc2, inv, ba.z), 0.f),
                                 fmaxf(fmaf(acc3, inv, ba.w), 0.f));
  __half2 o2 = __floats2half2_rn(fmaxf(fmaf(acc4, inv, bb.x), 0.f),
                                 fmaxf(fmaf(acc5, inv, bb.y), 0.f));
  __half2 o3 = __floats2half2_rn(fmaxf(fmaf(acc6, inv, bb.z), 0.f),
                                 fmaxf(fmaf(acc7, inv, bb.w), 0.f));
  uint4 packed = make_uint4(*(unsigned*)&o0, *(unsigned*)&o1,
                            *(unsigned*)&o2, *(unsigned*)&o3);
  *(uint4*)(hout + (size_t)v * DD + sub * 8) = packed;
}

// pooled[g] = segment-sum of fp16 h (batch sorted); then MLP, all in one block.
__global__ __launch_bounds__(256) void pool_mlp_kernel(
    const __half* __restrict__ hh, const int* __restrict__ batch,
    const float* __restrict__ W1, const float* __restrict__ b1,
    const float* __restrict__ W2, const float* __restrict__ b2,
    float* __restrict__ out) {
  __shared__ int s_lo, s_hi;
  __shared__ float red[4][DD];
  __shared__ float sp[DD];
  __shared__ float sh[2 * DD];
  int gI = blockIdx.x;
  int tid = threadIdx.x, wave = tid >> 6, lane = tid & 63;
  if (tid == 0) {
    int lo = 0, hi = NN;
    while (lo < hi) { int mid = (lo + hi) >> 1; if (batch[mid] < gI) lo = mid + 1; else hi = mid; }
    s_lo = lo;
    lo = 0; hi = NN;
    while (lo < hi) { int mid = (lo + hi) >> 1; if (batch[mid] < gI + 1) lo = mid + 1; else hi = mid; }
    s_hi = lo;
  }
  __syncthreads();
  float acc = 0.f;
  for (int v = s_lo + wave; v < s_hi; v += 4) acc += __half2float(hh[(size_t)v * DD + lane]);
  red[wave][lane] = acc;
  __syncthreads();
  if (wave == 0) sp[lane] = red[0][lane] + red[1][lane] + red[2][lane] + red[3][lane];
  __syncthreads();
  if (tid < 2 * DD) {
    float a = b1[tid];
    for (int d = 0; d < DD; ++d) a += sp[d] * W1[tid * DD + d];
    sh[tid] = fmaxf(a, 0.f);
  }
  __syncthreads();
  if (tid < TT) {
    float o = b2[tid];
    for (int k = 0; k < 2 * DD; ++k) o += sh[k] * W2[tid * 2 * DD + k];
    out[gI * TT + tid] = o;
  }
}

extern "C" void kernel_launch(void* const* d_in, const int* in_sizes, int n_in,
                              void* d_out, int out_size, void* d_ws, size_t ws_size,
                              hipStream_t stream) {
  const int* x          = (const int*)d_in[0];
  const int* edge_index = (const int*)d_in[1];
  const int* edge_attr  = (const int*)d_in[2];
  const int* batch      = (const int*)d_in[3];
  const float* node_emb = (const float*)d_in[4];
  const float* edge_embs= (const float*)d_in[5];
  const float* Ws_      = (const float*)d_in[6];
  const float* W_edges  = (const float*)d_in[7];
  const float* att_src  = (const float*)d_in[8];
  const float* att_dst  = (const float*)d_in[9];
  const float* att_edge = (const float*)d_in[10];
  const float* biases   = (const float*)d_in[11];
  const float* W1       = (const float*)d_in[12];
  const float* b1       = (const float*)d_in[13];
  const float* W2       = (const float*)d_in[14];
  const float* b2       = (const float*)d_in[15];
  float* out = (float*)d_out;

  char* wsp = (char*)d_ws;
  __half* h     = (__half*)wsp; wsp += (size_t)NN * DD * 2;
  __half* gh    = (__half*)wsp; wsp += (size_t)NN * DD * 2;
  float* asrc   = (float*)wsp; wsp += (size_t)NN * 4;
  float* adst   = (float*)wsp; wsp += (size_t)NN * 4;
  float* ae_tab = (float*)wsp; wsp += 16 * 4;
  int* rowptr   = (int*)wsp;   wsp += (size_t)(NN + 1) * 4;
  int* bcnt     = (int*)wsp;   wsp += (size_t)NBUK * 4;   // zeroed
  int* bcursor  = (int*)wsp;   wsp += (size_t)NBUK * 4;   // zeroed (adjacent to bcnt)
  int* bbase    = (int*)wsp;   wsp += (size_t)NBUK * 4;
  int* stag     = (int*)wsp;   wsp += (size_t)NE * 4;
  int* col      = (int*)wsp;   wsp += (size_t)NE * 4;

  const int* src = edge_index;
  const int* dst = edge_index + NE;

  const int nchunk = (NE + CHUNK - 1) / CHUNK;   // 391

  hipMemsetAsync(bcnt, 0, 2 * NBUK * sizeof(int), stream);   // bcnt + bcursor
  bucket_count_kernel<<<nchunk, 256, 0, stream>>>(dst, bcnt);
  bucket_scan_kernel<<<1, 128, 0, stream>>>(bcnt, bbase, rowptr);
  bucket_bin_kernel<<<nchunk, 256, 0, stream>>>(src, dst, edge_attr, bbase, bcursor, stag);
  bucket_csr_kernel<<<NBUK, 256, 0, stream>>>(bbase, stag, rowptr, col);
  prep_ae_kernel<<<16, 64, 0, stream>>>(edge_embs, W_edges, att_edge, ae_tab);

  const int agg_grid = (NN + 31) / 32;   // 1563

  for (int l = 0; l < LL; ++l) {
    if (l == 0)
      gemm_attn_kernel<true><<<NN / 16, 256, 0, stream>>>(h, x, node_emb, Ws_,
                                                          att_src, att_dst, gh, asrc, adst);
    else
      gemm_attn_kernel<false><<<NN / 16, 256, 0, stream>>>(h, x, node_emb, Ws_ + l * DD * DD,
                                                           att_src + l * DD, att_dst + l * DD,
                                                           gh, asrc, adst);
    aggregate_kernel<<<agg_grid, 256, 0, stream>>>(gh, asrc, adst, rowptr, col,
                                                   ae_tab + l * 4, biases + l * DD, h);
  }

  pool_mlp_kernel<<<GG, 256, 0, stream>>>(h, batch, W1, b1, W2, b2, out);
}